// Round 5
// baseline (999.302 us; speedup 1.0000x reference)
//
#include <hip/hip_runtime.h>
#include <hip/hip_bf16.h>
#include <math.h>

#define F 128

typedef __attribute__((ext_vector_type(8))) unsigned short ushort8v;

__device__ __forceinline__ float bfu(unsigned short u) {
  return __uint_as_float(((unsigned)u) << 16);
}

// ------- row-normalize: xn = x/max(||x||,eps) (fp32 + bf16 copies) ----------
__global__ void k_normalize(const float* __restrict__ x, float* __restrict__ xn,
                            __hip_bfloat16* __restrict__ xnb, int N) {
  int wid = (blockIdx.x * blockDim.x + threadIdx.x) >> 6;  // one wave per node
  int lane = threadIdx.x & 63;
  if (wid >= N) return;
  const float2* src = (const float2*)(x + (size_t)wid * F);
  float2 v = src[lane];
  float ss = v.x * v.x + v.y * v.y;
#pragma unroll
  for (int m = 32; m >= 1; m >>= 1) ss += __shfl_xor(ss, m);
  float inv = 1.0f / fmaxf(sqrtf(ss), 1e-12f);
  float2 o; o.x = v.x * inv; o.y = v.y * inv;
  ((float2*)(xn + (size_t)wid * F))[lane] = o;
  __hip_bfloat162 ob;
  ob.x = __float2bfloat16(o.x); ob.y = __float2bfloat16(o.y);
  ((__hip_bfloat162*)(xnb + (size_t)wid * F))[lane] = ob;
}

// ---------------- CSR build: fused histograms, scan, scatter ----------------
__global__ void k_hist2(const int* __restrict__ row, const int* __restrict__ col,
                        int* __restrict__ cntr, int* __restrict__ cntc, int E) {
  int e = blockIdx.x * blockDim.x + threadIdx.x;
  if (e < E) { atomicAdd(cntr + row[e], 1); atomicAdd(cntc + col[e], 1); }
}

__global__ void k_scan1(const int* __restrict__ cnt, int* __restrict__ partial,
                        int* __restrict__ bsum, int N) {
  __shared__ int sm[256];
  int t = threadIdx.x;
  int i = blockIdx.x * 256 + t;
  int val = (i < N) ? cnt[i] : 0;
  sm[t] = val;
  __syncthreads();
  for (int off = 1; off < 256; off <<= 1) {
    int v = (t >= off) ? sm[t - off] : 0;
    __syncthreads();
    sm[t] += v;
    __syncthreads();
  }
  if (i < N) partial[i] = sm[t] - val;  // exclusive
  if (t == 255) bsum[blockIdx.x] = sm[255];
}

__global__ void k_scan2(const int* __restrict__ bsum, int* __restrict__ boffs, int nb) {
  __shared__ int sm[256];
  int t = threadIdx.x;
  int val = (t < nb) ? bsum[t] : 0;
  sm[t] = val;
  __syncthreads();
  for (int off = 1; off < 256; off <<= 1) {
    int v = (t >= off) ? sm[t - off] : 0;
    __syncthreads();
    sm[t] += v;
    __syncthreads();
  }
  if (t < nb) boffs[t] = sm[t] - val;  // exclusive
}

__global__ void k_scan3(const int* __restrict__ partial, const int* __restrict__ boffs,
                        int* __restrict__ offs, int N, int E) {
  int i = blockIdx.x * 256 + threadIdx.x;
  if (i < N) offs[i] = partial[i] + boffs[i >> 8];
  if (i == 0) offs[N] = E;
}

__global__ void k_scatter(const int* __restrict__ idx, const int* __restrict__ offs,
                          int* __restrict__ cursor, int* __restrict__ perm,
                          int* __restrict__ pos_of_e, int E) {
  int e = blockIdx.x * blockDim.x + threadIdx.x;
  if (e >= E) return;
  int c = idx[e];
  int pos = offs[c] + atomicAdd(cursor + c, 1);
  perm[pos] = e;
  pos_of_e[e] = pos;
}

// ---- static index maps (built once) ----
__global__ void k_static(const int* __restrict__ row, const int* __restrict__ col,
                         const int* __restrict__ perm_r, const int* __restrict__ perm_c,
                         const int* __restrict__ rpos,
                         int* __restrict__ colof_r, int* __restrict__ rowof_c,
                         int* __restrict__ colof_c, int* __restrict__ c2r, int E) {
  int p = blockIdx.x * blockDim.x + threadIdx.x;
  if (p >= E) return;
  colof_r[p] = col[perm_r[p]];
  int e = perm_c[p];
  rowof_c[p] = row[e];
  colof_c[p] = col[e];
  c2r[p] = rpos[e];
}

// ------- fused per-row sims + weights. One WAVE per row; lane owns an edge:
//         16 independent 16B gathers per lane (deep vmcnt pipeline), no
//         per-edge shuffles — one wave-reduce per row.
__global__ __launch_bounds__(256) void k_simw(
    const float* __restrict__ xn, const __hip_bfloat16* __restrict__ xnb,
    const int* __restrict__ colof_r, const int* __restrict__ offs_r,
    float* __restrict__ adjr, float* __restrict__ wgr, float* __restrict__ colw,
    const float* __restrict__ gate, int layer, int N) {
  int w = threadIdx.x >> 6;   // wave 0..3, one row each
  int l = threadIdx.x & 63;
  int r = blockIdx.x * 4 + w;
  __shared__ float xrf[4][128];   // fp32 self row (a-side stays fp32)
  __shared__ float sims[4][320];  // ne < 320 (Poisson(16)+self)
  bool active = (r < N);
  if (active)
    ((float2*)xrf[w])[l] = ((const float2*)(xn + (size_t)r * F))[l];
  __syncthreads();
  if (!active) return;
  int p0 = offs_r[r], p1 = offs_r[r + 1];
  int ne = p1 - p0;
  float vsum = 0.f; int cn = 0;
  for (int i = l; i < ne; i += 64) {
    int c = colof_r[p0 + i];
    const ushort8v* bp = (const ushort8v*)(xnb + (size_t)c * F);
    float s0 = 0.f, s1 = 0.f;
#pragma unroll
    for (int k = 0; k < 16; ++k) {
      ushort8v bv = bp[k];                              // 16 independent gathers
      float4 a0 = ((const float4*)xrf[w])[2 * k];       // LDS broadcast
      float4 a1 = ((const float4*)xrf[w])[2 * k + 1];
      s0 += a0.x * bfu(bv[0]) + a0.y * bfu(bv[1]) + a0.z * bfu(bv[2]) + a0.w * bfu(bv[3]);
      s1 += a1.x * bfu(bv[4]) + a1.y * bfu(bv[5]) + a1.z * bfu(bv[6]) + a1.w * bfu(bv[7]);
    }
    float s = s0 + s1;
    bool self = (r == c);
    // bf16 dot error < 0.002; only the guard band can flip the threshold
    if (!self && fabsf(s - 0.1f) < 0.02f) {
      const float4* bq = (const float4*)(xn + (size_t)c * F);
      float t0 = 0.f, t1 = 0.f;
#pragma unroll
      for (int k = 0; k < 32; ++k) {
        float4 b4 = bq[k];
        float4 a4 = ((const float4*)xrf[w])[k];
        t0 += a4.x * b4.x + a4.y * b4.y;
        t1 += a4.z * b4.z + a4.w * b4.w;
      }
      s = t0 + t1;
    }
    if (s < 0.1f || self) s = 0.f;
    sims[w][i] = s;                 // same-lane read later; no cross-lane dep
    vsum += s;
    cn += (s > 0.f) ? 1 : 0;
  }
#pragma unroll
  for (int m = 32; m >= 1; m >>= 1) {
    vsum += __shfl_xor(vsum, m);
    cn += __shfl_xor(cn, m);
  }
  float rs = vsum;
  float lam = 1.0f / (float)(cn + 1);
  float gg = (layer > 0) ? gate[layer - 1] : 0.f;
  for (int i = l; i < ne; i += 64) {
    int c = colof_r[p0 + i];        // L1-hot reread
    float s = sims[w][i];
    float sn = (rs > 0.f) ? s / rs : 0.f;
    float wv = (r == c) ? lam : sn;
    wv = expf(wv);                  // thresholded edges get exp(0)=1
    float wc;
    if (layer == 0) { adjr[p0 + i] = wv; wc = wv; }
    else { wc = gg * adjr[p0 + i] + (1.f - gg) * wv; }
    wgr[p0 + i] = wc;               // sequential write
    atomicAdd(colw + c, wc);        // 200KB table, L2-resident
  }
}

// pack (row, dinv[r]*w*dinv[c]) sequentially in col-CSR order.
__global__ void k_prep(const int* __restrict__ rowof_c, const int* __restrict__ colof_c,
                       const int* __restrict__ c2r, const float* __restrict__ wgr,
                       const float* __restrict__ colw, int2* __restrict__ packed, int E) {
  int pc = blockIdx.x * blockDim.x + threadIdx.x;
  if (pc >= E) return;
  int r = rowof_c[pc];
  float dr = colw[r];
  float dc = colw[colof_c[pc]];
  float dir_ = (dr > 0.f) ? rsqrtf(dr) : 0.f;
  float dic_ = (dc > 0.f) ? rsqrtf(dc) : 0.f;
  float nrm = dir_ * wgr[c2r[pc]] * dic_;
  int2 rec; rec.x = r; rec.y = __float_as_int(nrm);
  packed[pc] = rec;
}

// ------ GEMM: out_bf16[M,128] = A[M,128] @ W[128,128], register-tiled -------
__global__ __launch_bounds__(256) void k_gemm128(const float* __restrict__ A,
                                                 const float* __restrict__ W,
                                                 __hip_bfloat16* __restrict__ out, int M) {
  __shared__ float As[128][36];
  int t = threadIdx.x;
  int n0 = blockIdx.x * 32;
  for (int i = t; i < 32 * 128; i += 256) {
    int nn = i >> 7, kk = i & 127;
    int gn = n0 + nn;
    As[kk][nn] = (gn < M) ? A[(size_t)gn * 128 + kk] : 0.f;
  }
  __syncthreads();
  int nb = (t >> 6) * 8;
  int j2 = (t & 63) * 2;
  float acc[8][2] = {};
  for (int k = 0; k < 128; ++k) {
    float4 a01 = *(const float4*)&As[k][nb];
    float4 a23 = *(const float4*)&As[k][nb + 4];
    float2 wv = *(const float2*)&W[k * 128 + j2];
    acc[0][0] += a01.x * wv.x; acc[0][1] += a01.x * wv.y;
    acc[1][0] += a01.y * wv.x; acc[1][1] += a01.y * wv.y;
    acc[2][0] += a01.z * wv.x; acc[2][1] += a01.z * wv.y;
    acc[3][0] += a01.w * wv.x; acc[3][1] += a01.w * wv.y;
    acc[4][0] += a23.x * wv.x; acc[4][1] += a23.x * wv.y;
    acc[5][0] += a23.y * wv.x; acc[5][1] += a23.y * wv.y;
    acc[6][0] += a23.z * wv.x; acc[6][1] += a23.z * wv.y;
    acc[7][0] += a23.w * wv.x; acc[7][1] += a23.w * wv.y;
  }
  __hip_bfloat162* o2 = (__hip_bfloat162*)out;
#pragma unroll
  for (int i = 0; i < 8; ++i) {
    int gn = n0 + nb + i;
    if (gn < M) {
      __hip_bfloat162 o;
      o.x = __float2bfloat16(acc[i][0]); o.y = __float2bfloat16(acc[i][1]);
      o2[(size_t)gn * 64 + (j2 >> 1)] = o;
    }
  }
}

// ------ GEMM: out_bf16[M,40] = A[M,128] @ W[128,40], register-tiled ---------
__global__ __launch_bounds__(320) void k_gemm40(const float* __restrict__ A,
                                                const float* __restrict__ W,
                                                __hip_bfloat16* __restrict__ out,
                                                int M, int C) {
  __shared__ float As[128][68];
  int t = threadIdx.x;
  int n0 = blockIdx.x * 64;
  for (int i = t; i < 64 * 128; i += 320) {
    int nn = i >> 7, kk = i & 127;
    int gn = n0 + nn;
    As[kk][nn] = (gn < M) ? A[(size_t)gn * 128 + kk] : 0.f;
  }
  __syncthreads();
  int gq = t / 40;
  int jc = t - gq * 40;
  int nb = gq * 8;
  float acc[8] = {};
  for (int k = 0; k < 128; ++k) {
    float4 a01 = *(const float4*)&As[k][nb];
    float4 a23 = *(const float4*)&As[k][nb + 4];
    float wv = W[k * C + jc];
    acc[0] += a01.x * wv; acc[1] += a01.y * wv; acc[2] += a01.z * wv; acc[3] += a01.w * wv;
    acc[4] += a23.x * wv; acc[5] += a23.y * wv; acc[6] += a23.z * wv; acc[7] += a23.w * wv;
  }
#pragma unroll
  for (int i = 0; i < 8; ++i) {
    int gn = n0 + nb + i;
    if (gn < M) out[(size_t)gn * C + jc] = __float2bfloat16(acc[i]);
  }
}

// ---- aggregation + bias + relu + fused normalize; wave per node, unroll x4 -
__global__ __launch_bounds__(256) void k_agg_norm(
    const __hip_bfloat162* __restrict__ hWb, const int2* __restrict__ packed,
    const int* __restrict__ offs_c, const float* __restrict__ bias,
    float* __restrict__ out, float* __restrict__ xn, __hip_bfloat16* __restrict__ xnb,
    int N) {
  int w = threadIdx.x >> 6;
  int t = threadIdx.x & 63;
  int c = blockIdx.x * 4 + w;
  if (c >= N) return;
  int p0 = offs_c[c], p1 = offs_c[c + 1];
  float acc0 = bias[2 * t], acc1 = bias[2 * t + 1];
  int p = p0;
  for (; p + 4 <= p1; p += 4) {   // 4 gathers in flight
    int2 r0 = packed[p], r1 = packed[p + 1], r2 = packed[p + 2], r3 = packed[p + 3];
    __hip_bfloat162 h0 = hWb[(size_t)r0.x * 64 + t];
    __hip_bfloat162 h1 = hWb[(size_t)r1.x * 64 + t];
    __hip_bfloat162 h2 = hWb[(size_t)r2.x * 64 + t];
    __hip_bfloat162 h3 = hWb[(size_t)r3.x * 64 + t];
    float w0 = __int_as_float(r0.y), w1 = __int_as_float(r1.y);
    float w2 = __int_as_float(r2.y), w3 = __int_as_float(r3.y);
    acc0 += w0 * __bfloat162float(h0.x) + w1 * __bfloat162float(h1.x)
          + w2 * __bfloat162float(h2.x) + w3 * __bfloat162float(h3.x);
    acc1 += w0 * __bfloat162float(h0.y) + w1 * __bfloat162float(h1.y)
          + w2 * __bfloat162float(h2.y) + w3 * __bfloat162float(h3.y);
  }
  for (; p < p1; ++p) {
    int2 ra = packed[p];
    __hip_bfloat162 ha = hWb[(size_t)ra.x * 64 + t];
    float wa = __int_as_float(ra.y);
    acc0 += wa * __bfloat162float(ha.x);
    acc1 += wa * __bfloat162float(ha.y);
  }
  acc0 = fmaxf(acc0, 0.f); acc1 = fmaxf(acc1, 0.f);
  float2 o; o.x = acc0; o.y = acc1;
  ((float2*)out)[(size_t)c * 64 + t] = o;
  float ss = acc0 * acc0 + acc1 * acc1;
#pragma unroll
  for (int m = 32; m >= 1; m >>= 1) ss += __shfl_xor(ss, m);
  float inv = 1.0f / fmaxf(sqrtf(ss), 1e-12f);
  float2 on; on.x = acc0 * inv; on.y = acc1 * inv;
  ((float2*)xn)[(size_t)c * 64 + t] = on;
  __hip_bfloat162 ob;
  ob.x = __float2bfloat16(on.x); ob.y = __float2bfloat16(on.y);
  ((__hip_bfloat162*)xnb)[(size_t)c * 64 + t] = ob;
}

// ------- final aggregation + bias + log_softmax; wave per node, unroll x4 ---
__global__ __launch_bounds__(256) void k_agg40_lsm(
    const __hip_bfloat16* __restrict__ hW, const int2* __restrict__ packed,
    const int* __restrict__ offs_c, const float* __restrict__ bias,
    float* __restrict__ out, int C, int N) {
  int w = threadIdx.x >> 6;
  int j = threadIdx.x & 63;
  int c = blockIdx.x * 4 + w;
  if (c >= N) return;
  int p0 = offs_c[c], p1 = offs_c[c + 1];
  bool act = j < C;
  int jj = act ? j : 0;
  float acc = act ? bias[jj] : 0.f;
  int p = p0;
  for (; p + 4 <= p1; p += 4) {
    int2 r0 = packed[p], r1 = packed[p + 1], r2 = packed[p + 2], r3 = packed[p + 3];
    float h0 = __bfloat162float(hW[(size_t)r0.x * C + jj]);
    float h1 = __bfloat162float(hW[(size_t)r1.x * C + jj]);
    float h2 = __bfloat162float(hW[(size_t)r2.x * C + jj]);
    float h3 = __bfloat162float(hW[(size_t)r3.x * C + jj]);
    acc += __int_as_float(r0.y) * h0 + __int_as_float(r1.y) * h1
         + __int_as_float(r2.y) * h2 + __int_as_float(r3.y) * h3;
  }
  for (; p < p1; ++p) {
    int2 ra = packed[p];
    acc += __int_as_float(ra.y) * __bfloat162float(hW[(size_t)ra.x * C + jj]);
  }
  if (!act) acc = 0.f;
  float v = act ? acc : -3.0e38f;
#pragma unroll
  for (int m = 32; m >= 1; m >>= 1) v = fmaxf(v, __shfl_xor(v, m));
  float ex = act ? expf(acc - v) : 0.f;
#pragma unroll
  for (int m = 32; m >= 1; m >>= 1) ex += __shfl_xor(ex, m);
  if (act) out[(size_t)c * C + j] = acc - v - logf(ex);
}

extern "C" void kernel_launch(void* const* d_in, const int* in_sizes, int n_in,
                              void* d_out, int out_size, void* d_ws, size_t ws_size,
                              hipStream_t stream) {
  const float* x    = (const float*)d_in[0];
  const float* gate = (const float*)d_in[1];
  const float* W0   = (const float*)d_in[2];
  const float* b0   = (const float*)d_in[3];
  const float* W1   = (const float*)d_in[4];
  const float* b1   = (const float*)d_in[5];
  const float* W2   = (const float*)d_in[6];
  const float* b2   = (const float*)d_in[7];
  const int* eidx   = (const int*)d_in[8];
  int N = in_sizes[0] / 128;
  int E = in_sizes[8] / 2;
  int C = in_sizes[7];  // 40
  const int* row = eidx;
  const int* col = eidx + E;

  char* ws = (char*)d_ws;
  size_t off = 0;
  auto alloc = [&](size_t bytes) {
    char* p = ws + off;
    off += (bytes + 255) & ~(size_t)255;
    return p;
  };
  float* xn     = (float*)alloc((size_t)N * 128 * 4);
  __hip_bfloat16* xnb = (__hip_bfloat16*)alloc((size_t)N * 128 * 2);
  float* bufC   = (float*)alloc((size_t)N * 128 * 4);
  __hip_bfloat16* hWb = (__hip_bfloat16*)alloc((size_t)N * 128 * 2);
  float* adjr   = (float*)alloc((size_t)E * 4);
  float* wgr    = (float*)alloc((size_t)E * 4);
  int*   cpos   = (int*)alloc((size_t)E * 4);
  int*   rpos   = (int*)alloc((size_t)E * 4);
  int*   perm_c = (int*)alloc((size_t)E * 4);
  int*   perm_r = (int*)alloc((size_t)E * 4);
  int2*  packed = (int2*)alloc((size_t)E * 8);
  int*   colof_r= (int*)alloc((size_t)E * 4);
  int*   rowof_c= (int*)alloc((size_t)E * 4);
  int*   colof_c= (int*)alloc((size_t)E * 4);
  int*   c2r    = (int*)alloc((size_t)E * 4);
  int*   offs_c = (int*)alloc((size_t)(N + 1) * 4);
  int*   offs_r = (int*)alloc((size_t)(N + 1) * 4);
  int*   cnt    = (int*)alloc((size_t)N * 4 * 4);
  int*   cur_c  = cnt + N;
  int*   cnt_r  = cnt + 2 * N;
  int*   cur_r  = cnt + 3 * N;
  int*   partial= (int*)alloc((size_t)N * 4);
  int*   bsum   = (int*)alloc(1024);
  int*   boffs  = (int*)alloc(1024);
  float* colw   = (float*)alloc((size_t)N * 4);

  int nb = (N + 255) / 256;
  int eb = (E + 255) / 256;
  int nw4 = (N + 3) / 4;

  // ---- build col-CSR + row-CSR + static index maps (one-time per call) ----
  hipMemsetAsync(cnt, 0, (size_t)N * 4 * 4, stream);
  k_hist2<<<eb, 256, 0, stream>>>(row, col, cnt_r, cnt, E);
  k_scan1<<<nb, 256, 0, stream>>>(cnt, partial, bsum, N);
  k_scan2<<<1, 256, 0, stream>>>(bsum, boffs, nb);
  k_scan3<<<nb, 256, 0, stream>>>(partial, boffs, offs_c, N, E);
  k_scatter<<<eb, 256, 0, stream>>>(col, offs_c, cur_c, perm_c, cpos, E);
  k_scan1<<<nb, 256, 0, stream>>>(cnt_r, partial, bsum, N);
  k_scan2<<<1, 256, 0, stream>>>(bsum, boffs, nb);
  k_scan3<<<nb, 256, 0, stream>>>(partial, boffs, offs_r, N, E);
  k_scatter<<<eb, 256, 0, stream>>>(row, offs_r, cur_r, perm_r, rpos, E);
  k_static<<<eb, 256, 0, stream>>>(row, col, perm_r, perm_c, rpos,
                                   colof_r, rowof_c, colof_c, c2r, E);

  for (int layer = 0; layer < 3; ++layer) {
    hipMemsetAsync(colw, 0, (size_t)N * 4, stream);
    if (layer == 0) k_normalize<<<(N + 3) / 4, 256, 0, stream>>>(x, xn, xnb, N);
    k_simw<<<nw4, 256, 0, stream>>>(xn, xnb, colof_r, offs_r, adjr, wgr, colw,
                                    gate, layer, N);
    k_prep<<<eb, 256, 0, stream>>>(rowof_c, colof_c, c2r, wgr, colw, packed, E);
    const float* hin = (layer == 0) ? x : bufC;
    if (layer < 2) {
      const float* W = (layer == 0) ? W0 : W1;
      const float* b = (layer == 0) ? b0 : b1;
      k_gemm128<<<(N + 31) / 32, 256, 0, stream>>>(hin, W, hWb, N);
      k_agg_norm<<<nw4, 256, 0, stream>>>((const __hip_bfloat162*)hWb, packed, offs_c,
                                          b, bufC, xn, xnb, N);
    } else {
      k_gemm40<<<(N + 63) / 64, 320, 0, stream>>>(hin, W2, hWb, N, C);
      k_agg40_lsm<<<nw4, 256, 0, stream>>>(hWb, packed, offs_c, b2, (float*)d_out, C, N);
    }
  }
}

// Round 6
// 767.457 us; speedup vs baseline: 1.3021x; 1.3021x over previous
//
#include <hip/hip_runtime.h>
#include <hip/hip_bf16.h>
#include <math.h>

#define F 128

typedef __attribute__((ext_vector_type(8))) unsigned short ushort8v;

__device__ __forceinline__ float bfu(unsigned short u) {
  return __uint_as_float(((unsigned)u) << 16);
}

// ------- row-normalize: xn = x/max(||x||,eps) (fp32 + bf16 copies) ----------
__global__ void k_normalize(const float* __restrict__ x, float* __restrict__ xn,
                            __hip_bfloat16* __restrict__ xnb, int N) {
  int wid = (blockIdx.x * blockDim.x + threadIdx.x) >> 6;  // one wave per node
  int lane = threadIdx.x & 63;
  if (wid >= N) return;
  const float2* src = (const float2*)(x + (size_t)wid * F);
  float2 v = src[lane];
  float ss = v.x * v.x + v.y * v.y;
#pragma unroll
  for (int m = 32; m >= 1; m >>= 1) ss += __shfl_xor(ss, m);
  float inv = 1.0f / fmaxf(sqrtf(ss), 1e-12f);
  float2 o; o.x = v.x * inv; o.y = v.y * inv;
  ((float2*)(xn + (size_t)wid * F))[lane] = o;
  __hip_bfloat162 ob;
  ob.x = __float2bfloat16(o.x); ob.y = __float2bfloat16(o.y);
  ((__hip_bfloat162*)(xnb + (size_t)wid * F))[lane] = ob;
}

// ---------------- CSR build: fused histograms, scan, scatter ----------------
__global__ void k_hist2(const int* __restrict__ row, const int* __restrict__ col,
                        int* __restrict__ cntr, int* __restrict__ cntc, int E) {
  int e = blockIdx.x * blockDim.x + threadIdx.x;
  if (e < E) { atomicAdd(cntr + row[e], 1); atomicAdd(cntc + col[e], 1); }
}

__global__ void k_scan1(const int* __restrict__ cnt, int* __restrict__ partial,
                        int* __restrict__ bsum, int N) {
  __shared__ int sm[256];
  int t = threadIdx.x;
  int i = blockIdx.x * 256 + t;
  int val = (i < N) ? cnt[i] : 0;
  sm[t] = val;
  __syncthreads();
  for (int off = 1; off < 256; off <<= 1) {
    int v = (t >= off) ? sm[t - off] : 0;
    __syncthreads();
    sm[t] += v;
    __syncthreads();
  }
  if (i < N) partial[i] = sm[t] - val;  // exclusive
  if (t == 255) bsum[blockIdx.x] = sm[255];
}

__global__ void k_scan2(const int* __restrict__ bsum, int* __restrict__ boffs, int nb) {
  __shared__ int sm[256];
  int t = threadIdx.x;
  int val = (t < nb) ? bsum[t] : 0;
  sm[t] = val;
  __syncthreads();
  for (int off = 1; off < 256; off <<= 1) {
    int v = (t >= off) ? sm[t - off] : 0;
    __syncthreads();
    sm[t] += v;
    __syncthreads();
  }
  if (t < nb) boffs[t] = sm[t] - val;  // exclusive
}

__global__ void k_scan3(const int* __restrict__ partial, const int* __restrict__ boffs,
                        int* __restrict__ offs, int N, int E) {
  int i = blockIdx.x * 256 + threadIdx.x;
  if (i < N) offs[i] = partial[i] + boffs[i >> 8];
  if (i == 0) offs[N] = E;
}

__global__ void k_scatter(const int* __restrict__ idx, const int* __restrict__ offs,
                          int* __restrict__ cursor, int* __restrict__ perm,
                          int* __restrict__ pos_of_e, int E) {
  int e = blockIdx.x * blockDim.x + threadIdx.x;
  if (e >= E) return;
  int c = idx[e];
  int pos = offs[c] + atomicAdd(cursor + c, 1);
  perm[pos] = e;
  pos_of_e[e] = pos;
}

// ---- static index maps (built once) ----
__global__ void k_static(const int* __restrict__ row, const int* __restrict__ col,
                         const int* __restrict__ perm_r, const int* __restrict__ perm_c,
                         const int* __restrict__ rpos,
                         int* __restrict__ colof_r, int* __restrict__ rowof_c,
                         int* __restrict__ colof_c, int* __restrict__ c2r, int E) {
  int p = blockIdx.x * blockDim.x + threadIdx.x;
  if (p >= E) return;
  colof_r[p] = col[perm_r[p]];
  int e = perm_c[p];
  rowof_c[p] = row[e];
  colof_c[p] = col[e];
  c2r[p] = rpos[e];
}

// ------- fused per-row: bf16 cosine sims (fp32 recompute in guard band) +
//         threshold + rowsum/deg + weight (+gating) + colw atomic.
//         16-lane group per edge (R4 design: 20 VGPR, ~72% occupancy).
__global__ __launch_bounds__(128) void k_simw(
    const float* __restrict__ xn, const __hip_bfloat16* __restrict__ xnb,
    const int* __restrict__ colof_r, const int* __restrict__ offs_r,
    float* __restrict__ adjr, float* __restrict__ wgr, float* __restrict__ colw,
    const float* __restrict__ gate, int layer) {
  int r = blockIdx.x;
  int t = threadIdx.x;
  int p0 = offs_r[r], p1 = offs_r[r + 1];
  int ne = p1 - p0;                      // ~17 (Poisson(16) + self loop), <320
  __shared__ float xr[128];
  __shared__ float sims[320];
  __shared__ int scol[320];
  __shared__ float redv[2];
  __shared__ int redc[2];
  xr[t] = xn[(size_t)r * F + t];
  __syncthreads();
  int g = t >> 4, l = t & 15;
  float4 a0 = *(const float4*)(xr + l * 8);
  float4 a1 = *(const float4*)(xr + l * 8 + 4);
  for (int i = g; i < ne; i += 8) {
    int c = colof_r[p0 + i];             // broadcast within group
    ushort8v bv = *(const ushort8v*)(xnb + (size_t)c * F + l * 8);  // 16B gather
    float s = a0.x * bfu(bv[0]) + a0.y * bfu(bv[1]) + a0.z * bfu(bv[2]) + a0.w * bfu(bv[3])
            + a1.x * bfu(bv[4]) + a1.y * bfu(bv[5]) + a1.z * bfu(bv[6]) + a1.w * bfu(bv[7]);
#pragma unroll
    for (int m = 8; m >= 1; m >>= 1) s += __shfl_xor(s, m);
    bool self = (r == c);
    // bf16 worst-case dot error <= 2^-9 < 0.002; only the guard band can flip
    if (!self && fabsf(s - 0.1f) < 0.02f) {
      const float4* bp = (const float4*)(xn + (size_t)c * F);
      float4 b0 = bp[l * 2], b1 = bp[l * 2 + 1];
      float s2 = a0.x * b0.x + a0.y * b0.y + a0.z * b0.z + a0.w * b0.w
               + a1.x * b1.x + a1.y * b1.y + a1.z * b1.z + a1.w * b1.w;
#pragma unroll
      for (int m = 8; m >= 1; m >>= 1) s2 += __shfl_xor(s2, m);
      s = s2;
    }
    if (l == 0) {
      if (s < 0.1f || self) s = 0.0f;
      sims[i] = s;
      scol[i] = c;
    }
  }
  __syncthreads();
  // block reduce rowsum and deg (count of surviving sims)
  float v = 0.f; int cn = 0;
  for (int i = t; i < ne; i += 128) {
    float s = sims[i];
    v += s;
    cn += (s > 0.f) ? 1 : 0;
  }
#pragma unroll
  for (int m = 32; m >= 1; m >>= 1) { v += __shfl_xor(v, m); cn += __shfl_xor(cn, m); }
  if ((t & 63) == 0) { redv[t >> 6] = v; redc[t >> 6] = cn; }
  __syncthreads();
  float rs = redv[0] + redv[1];
  int deg = redc[0] + redc[1];
  float lam = 1.0f / (float)(deg + 1);
  float gg = (layer > 0) ? gate[layer - 1] : 0.f;
  for (int i = t; i < ne; i += 128) {
    int c = scol[i];
    float s = sims[i];
    float sn = (rs > 0.f) ? s / rs : 0.f;
    float w = (r == c) ? lam : sn;
    w = expf(w);                          // thresholded edges get exp(0)=1
    float wc;
    if (layer == 0) { adjr[p0 + i] = w; wc = w; }
    else { wc = gg * adjr[p0 + i] + (1.f - gg) * w; }
    wgr[p0 + i] = wc;                     // sequential write (no RMW scatter)
    atomicAdd(colw + c, wc);              // 200KB table, L2-resident
  }
}

// pack (row, dinv[r]*w*dinv[c]) sequentially in col-CSR order.
__global__ void k_prep(const int* __restrict__ rowof_c, const int* __restrict__ colof_c,
                       const int* __restrict__ c2r, const float* __restrict__ wgr,
                       const float* __restrict__ colw, int2* __restrict__ packed, int E) {
  int pc = blockIdx.x * blockDim.x + threadIdx.x;
  if (pc >= E) return;
  int r = rowof_c[pc];
  float dr = colw[r];
  float dc = colw[colof_c[pc]];
  float dir_ = (dr > 0.f) ? rsqrtf(dr) : 0.f;
  float dic_ = (dc > 0.f) ? rsqrtf(dc) : 0.f;
  float nrm = dir_ * wgr[c2r[pc]] * dic_;
  int2 rec; rec.x = r; rec.y = __float_as_int(nrm);
  packed[pc] = rec;
}

// ------ GEMM: out_bf16[M,128] = A[M,128] @ W[128,128], register-tiled -------
__global__ __launch_bounds__(256) void k_gemm128(const float* __restrict__ A,
                                                 const float* __restrict__ W,
                                                 __hip_bfloat16* __restrict__ out, int M) {
  __shared__ float As[128][36];
  int t = threadIdx.x;
  int n0 = blockIdx.x * 32;
  for (int i = t; i < 32 * 128; i += 256) {
    int nn = i >> 7, kk = i & 127;
    int gn = n0 + nn;
    As[kk][nn] = (gn < M) ? A[(size_t)gn * 128 + kk] : 0.f;
  }
  __syncthreads();
  int nb = (t >> 6) * 8;
  int j2 = (t & 63) * 2;
  float acc[8][2] = {};
  for (int k = 0; k < 128; ++k) {
    float4 a01 = *(const float4*)&As[k][nb];
    float4 a23 = *(const float4*)&As[k][nb + 4];
    float2 wv = *(const float2*)&W[k * 128 + j2];
    acc[0][0] += a01.x * wv.x; acc[0][1] += a01.x * wv.y;
    acc[1][0] += a01.y * wv.x; acc[1][1] += a01.y * wv.y;
    acc[2][0] += a01.z * wv.x; acc[2][1] += a01.z * wv.y;
    acc[3][0] += a01.w * wv.x; acc[3][1] += a01.w * wv.y;
    acc[4][0] += a23.x * wv.x; acc[4][1] += a23.x * wv.y;
    acc[5][0] += a23.y * wv.x; acc[5][1] += a23.y * wv.y;
    acc[6][0] += a23.z * wv.x; acc[6][1] += a23.z * wv.y;
    acc[7][0] += a23.w * wv.x; acc[7][1] += a23.w * wv.y;
  }
  __hip_bfloat162* o2 = (__hip_bfloat162*)out;
#pragma unroll
  for (int i = 0; i < 8; ++i) {
    int gn = n0 + nb + i;
    if (gn < M) {
      __hip_bfloat162 o;
      o.x = __float2bfloat16(acc[i][0]); o.y = __float2bfloat16(acc[i][1]);
      o2[(size_t)gn * 64 + (j2 >> 1)] = o;
    }
  }
}

// ------ GEMM: out_bf16[M,40] = A[M,128] @ W[128,40], register-tiled ---------
__global__ __launch_bounds__(320) void k_gemm40(const float* __restrict__ A,
                                                const float* __restrict__ W,
                                                __hip_bfloat16* __restrict__ out,
                                                int M, int C) {
  __shared__ float As[128][68];
  int t = threadIdx.x;
  int n0 = blockIdx.x * 64;
  for (int i = t; i < 64 * 128; i += 320) {
    int nn = i >> 7, kk = i & 127;
    int gn = n0 + nn;
    As[kk][nn] = (gn < M) ? A[(size_t)gn * 128 + kk] : 0.f;
  }
  __syncthreads();
  int gq = t / 40;
  int jc = t - gq * 40;
  int nb = gq * 8;
  float acc[8] = {};
  for (int k = 0; k < 128; ++k) {
    float4 a01 = *(const float4*)&As[k][nb];
    float4 a23 = *(const float4*)&As[k][nb + 4];
    float wv = W[k * C + jc];
    acc[0] += a01.x * wv; acc[1] += a01.y * wv; acc[2] += a01.z * wv; acc[3] += a01.w * wv;
    acc[4] += a23.x * wv; acc[5] += a23.y * wv; acc[6] += a23.z * wv; acc[7] += a23.w * wv;
  }
#pragma unroll
  for (int i = 0; i < 8; ++i) {
    int gn = n0 + nb + i;
    if (gn < M) out[(size_t)gn * C + jc] = __float2bfloat16(acc[i]);
  }
}

// ---- aggregation + bias + relu + fused normalize; wave per node, unroll x4 -
__global__ __launch_bounds__(256) void k_agg_norm(
    const __hip_bfloat162* __restrict__ hWb, const int2* __restrict__ packed,
    const int* __restrict__ offs_c, const float* __restrict__ bias,
    float* __restrict__ out, float* __restrict__ xn, __hip_bfloat16* __restrict__ xnb,
    int N) {
  int w = threadIdx.x >> 6;
  int t = threadIdx.x & 63;
  int c = blockIdx.x * 4 + w;
  if (c >= N) return;
  int p0 = offs_c[c], p1 = offs_c[c + 1];
  float acc0 = bias[2 * t], acc1 = bias[2 * t + 1];
  int p = p0;
  for (; p + 4 <= p1; p += 4) {   // 4 gathers in flight
    int2 r0 = packed[p], r1 = packed[p + 1], r2 = packed[p + 2], r3 = packed[p + 3];
    __hip_bfloat162 h0 = hWb[(size_t)r0.x * 64 + t];
    __hip_bfloat162 h1 = hWb[(size_t)r1.x * 64 + t];
    __hip_bfloat162 h2 = hWb[(size_t)r2.x * 64 + t];
    __hip_bfloat162 h3 = hWb[(size_t)r3.x * 64 + t];
    float w0 = __int_as_float(r0.y), w1 = __int_as_float(r1.y);
    float w2 = __int_as_float(r2.y), w3 = __int_as_float(r3.y);
    acc0 += w0 * __bfloat162float(h0.x) + w1 * __bfloat162float(h1.x)
          + w2 * __bfloat162float(h2.x) + w3 * __bfloat162float(h3.x);
    acc1 += w0 * __bfloat162float(h0.y) + w1 * __bfloat162float(h1.y)
          + w2 * __bfloat162float(h2.y) + w3 * __bfloat162float(h3.y);
  }
  for (; p < p1; ++p) {
    int2 ra = packed[p];
    __hip_bfloat162 ha = hWb[(size_t)ra.x * 64 + t];
    float wa = __int_as_float(ra.y);
    acc0 += wa * __bfloat162float(ha.x);
    acc1 += wa * __bfloat162float(ha.y);
  }
  acc0 = fmaxf(acc0, 0.f); acc1 = fmaxf(acc1, 0.f);
  float2 o; o.x = acc0; o.y = acc1;
  ((float2*)out)[(size_t)c * 64 + t] = o;
  float ss = acc0 * acc0 + acc1 * acc1;
#pragma unroll
  for (int m = 32; m >= 1; m >>= 1) ss += __shfl_xor(ss, m);
  float inv = 1.0f / fmaxf(sqrtf(ss), 1e-12f);
  float2 on; on.x = acc0 * inv; on.y = acc1 * inv;
  ((float2*)xn)[(size_t)c * 64 + t] = on;
  __hip_bfloat162 ob;
  ob.x = __float2bfloat16(on.x); ob.y = __float2bfloat16(on.y);
  ((__hip_bfloat162*)xnb)[(size_t)c * 64 + t] = ob;
}

// ------- final aggregation + bias + log_softmax; wave per node, unroll x4 ---
__global__ __launch_bounds__(256) void k_agg40_lsm(
    const __hip_bfloat16* __restrict__ hW, const int2* __restrict__ packed,
    const int* __restrict__ offs_c, const float* __restrict__ bias,
    float* __restrict__ out, int C, int N) {
  int w = threadIdx.x >> 6;
  int j = threadIdx.x & 63;
  int c = blockIdx.x * 4 + w;
  if (c >= N) return;
  int p0 = offs_c[c], p1 = offs_c[c + 1];
  bool act = j < C;
  int jj = act ? j : 0;
  float acc = act ? bias[jj] : 0.f;
  int p = p0;
  for (; p + 4 <= p1; p += 4) {
    int2 r0 = packed[p], r1 = packed[p + 1], r2 = packed[p + 2], r3 = packed[p + 3];
    float h0 = __bfloat162float(hW[(size_t)r0.x * C + jj]);
    float h1 = __bfloat162float(hW[(size_t)r1.x * C + jj]);
    float h2 = __bfloat162float(hW[(size_t)r2.x * C + jj]);
    float h3 = __bfloat162float(hW[(size_t)r3.x * C + jj]);
    acc += __int_as_float(r0.y) * h0 + __int_as_float(r1.y) * h1
         + __int_as_float(r2.y) * h2 + __int_as_float(r3.y) * h3;
  }
  for (; p < p1; ++p) {
    int2 ra = packed[p];
    acc += __int_as_float(ra.y) * __bfloat162float(hW[(size_t)ra.x * C + jj]);
  }
  if (!act) acc = 0.f;
  float v = act ? acc : -3.0e38f;
#pragma unroll
  for (int m = 32; m >= 1; m >>= 1) v = fmaxf(v, __shfl_xor(v, m));
  float ex = act ? expf(acc - v) : 0.f;
#pragma unroll
  for (int m = 32; m >= 1; m >>= 1) ex += __shfl_xor(ex, m);
  if (act) out[(size_t)c * C + j] = acc - v - logf(ex);
}

extern "C" void kernel_launch(void* const* d_in, const int* in_sizes, int n_in,
                              void* d_out, int out_size, void* d_ws, size_t ws_size,
                              hipStream_t stream) {
  const float* x    = (const float*)d_in[0];
  const float* gate = (const float*)d_in[1];
  const float* W0   = (const float*)d_in[2];
  const float* b0   = (const float*)d_in[3];
  const float* W1   = (const float*)d_in[4];
  const float* b1   = (const float*)d_in[5];
  const float* W2   = (const float*)d_in[6];
  const float* b2   = (const float*)d_in[7];
  const int* eidx   = (const int*)d_in[8];
  int N = in_sizes[0] / 128;
  int E = in_sizes[8] / 2;
  int C = in_sizes[7];  // 40
  const int* row = eidx;
  const int* col = eidx + E;

  char* ws = (char*)d_ws;
  size_t off = 0;
  auto alloc = [&](size_t bytes) {
    char* p = ws + off;
    off += (bytes + 255) & ~(size_t)255;
    return p;
  };
  float* xn     = (float*)alloc((size_t)N * 128 * 4);
  __hip_bfloat16* xnb = (__hip_bfloat16*)alloc((size_t)N * 128 * 2);
  float* bufC   = (float*)alloc((size_t)N * 128 * 4);
  __hip_bfloat16* hWb = (__hip_bfloat16*)alloc((size_t)N * 128 * 2);
  float* adjr   = (float*)alloc((size_t)E * 4);
  float* wgr    = (float*)alloc((size_t)E * 4);
  int*   cpos   = (int*)alloc((size_t)E * 4);
  int*   rpos   = (int*)alloc((size_t)E * 4);
  int*   perm_c = (int*)alloc((size_t)E * 4);
  int*   perm_r = (int*)alloc((size_t)E * 4);
  int2*  packed = (int2*)alloc((size_t)E * 8);
  int*   colof_r= (int*)alloc((size_t)E * 4);
  int*   rowof_c= (int*)alloc((size_t)E * 4);
  int*   colof_c= (int*)alloc((size_t)E * 4);
  int*   c2r    = (int*)alloc((size_t)E * 4);
  int*   offs_c = (int*)alloc((size_t)(N + 1) * 4);
  int*   offs_r = (int*)alloc((size_t)(N + 1) * 4);
  int*   cnt    = (int*)alloc((size_t)N * 4 * 4);
  int*   cur_c  = cnt + N;
  int*   cnt_r  = cnt + 2 * N;
  int*   cur_r  = cnt + 3 * N;
  int*   partial= (int*)alloc((size_t)N * 4);
  int*   bsum   = (int*)alloc(1024);
  int*   boffs  = (int*)alloc(1024);
  float* colw   = (float*)alloc((size_t)N * 4);

  int nb = (N + 255) / 256;
  int eb = (E + 255) / 256;
  int nw4 = (N + 3) / 4;

  // ---- build col-CSR + row-CSR + static index maps (one-time per call) ----
  hipMemsetAsync(cnt, 0, (size_t)N * 4 * 4, stream);
  k_hist2<<<eb, 256, 0, stream>>>(row, col, cnt_r, cnt, E);
  k_scan1<<<nb, 256, 0, stream>>>(cnt, partial, bsum, N);
  k_scan2<<<1, 256, 0, stream>>>(bsum, boffs, nb);
  k_scan3<<<nb, 256, 0, stream>>>(partial, boffs, offs_c, N, E);
  k_scatter<<<eb, 256, 0, stream>>>(col, offs_c, cur_c, perm_c, cpos, E);
  k_scan1<<<nb, 256, 0, stream>>>(cnt_r, partial, bsum, N);
  k_scan2<<<1, 256, 0, stream>>>(bsum, boffs, nb);
  k_scan3<<<nb, 256, 0, stream>>>(partial, boffs, offs_r, N, E);
  k_scatter<<<eb, 256, 0, stream>>>(row, offs_r, cur_r, perm_r, rpos, E);
  k_static<<<eb, 256, 0, stream>>>(row, col, perm_r, perm_c, rpos,
                                   colof_r, rowof_c, colof_c, c2r, E);

  for (int layer = 0; layer < 3; ++layer) {
    hipMemsetAsync(colw, 0, (size_t)N * 4, stream);
    if (layer == 0) k_normalize<<<(N + 3) / 4, 256, 0, stream>>>(x, xn, xnb, N);
    k_simw<<<N, 128, 0, stream>>>(xn, xnb, colof_r, offs_r, adjr, wgr, colw, gate, layer);
    k_prep<<<eb, 256, 0, stream>>>(rowof_c, colof_c, c2r, wgr, colw, packed, E);
    const float* hin = (layer == 0) ? x : bufC;
    if (layer < 2) {
      const float* W = (layer == 0) ? W0 : W1;
      const float* b = (layer == 0) ? b0 : b1;
      k_gemm128<<<(N + 31) / 32, 256, 0, stream>>>(hin, W, hWb, N);
      k_agg_norm<<<nw4, 256, 0, stream>>>((const __hip_bfloat162*)hWb, packed, offs_c,
                                          b, bufC, xn, xnb, N);
    } else {
      k_gemm40<<<(N + 63) / 64, 320, 0, stream>>>(hin, W2, hWb, N, C);
      k_agg40_lsm<<<nw4, 256, 0, stream>>>(hWb, packed, offs_c, b2, (float*)d_out, C, N);
    }
  }
}

// Round 7
// 714.629 us; speedup vs baseline: 1.3984x; 1.0739x over previous
//
#include <hip/hip_runtime.h>
#include <hip/hip_bf16.h>
#include <math.h>

#define F 128

typedef __attribute__((ext_vector_type(8))) unsigned short ushort8v;

__device__ __forceinline__ float bfu(unsigned short u) {
  return __uint_as_float(((unsigned)u) << 16);
}

// ------- row-normalize: xn = x/max(||x||,eps) (fp32 + bf16 copies) ----------
__global__ void k_normalize(const float* __restrict__ x, float* __restrict__ xn,
                            __hip_bfloat16* __restrict__ xnb, int N) {
  int wid = (blockIdx.x * blockDim.x + threadIdx.x) >> 6;  // one wave per node
  int lane = threadIdx.x & 63;
  if (wid >= N) return;
  const float2* src = (const float2*)(x + (size_t)wid * F);
  float2 v = src[lane];
  float ss = v.x * v.x + v.y * v.y;
#pragma unroll
  for (int m = 32; m >= 1; m >>= 1) ss += __shfl_xor(ss, m);
  float inv = 1.0f / fmaxf(sqrtf(ss), 1e-12f);
  float2 o; o.x = v.x * inv; o.y = v.y * inv;
  ((float2*)(xn + (size_t)wid * F))[lane] = o;
  __hip_bfloat162 ob;
  ob.x = __float2bfloat16(o.x); ob.y = __float2bfloat16(o.y);
  ((__hip_bfloat162*)(xnb + (size_t)wid * F))[lane] = ob;
}

// ---------------- CSR build ----------------
// cntBoth layout: [0,N) col counts, [N,2N) row counts (scanned as one array)
__global__ void k_hist2(const int* __restrict__ row, const int* __restrict__ col,
                        int* __restrict__ cntBoth, int N, int E) {
  int e = blockIdx.x * blockDim.x + threadIdx.x;
  if (e < E) { atomicAdd(cntBoth + col[e], 1); atomicAdd(cntBoth + N + row[e], 1); }
}

__global__ void k_scan1(const int* __restrict__ cnt, int* __restrict__ partial,
                        int* __restrict__ bsum, int M) {
  __shared__ int sm[256];
  int t = threadIdx.x;
  int i = blockIdx.x * 256 + t;
  int val = (i < M) ? cnt[i] : 0;
  sm[t] = val;
  __syncthreads();
  for (int off = 1; off < 256; off <<= 1) {
    int v = (t >= off) ? sm[t - off] : 0;
    __syncthreads();
    sm[t] += v;
    __syncthreads();
  }
  if (i < M) partial[i] = sm[t] - val;  // exclusive
  if (t == 255) bsum[blockIdx.x] = sm[255];
}

// looped single-block scan of up to 512*... block sums (handles nb > 256)
__global__ void k_scan2(const int* __restrict__ bsum, int* __restrict__ boffs, int nb) {
  __shared__ int sm[256];
  int t = threadIdx.x;
  int carry = 0;
  for (int base = 0; base < nb; base += 256) {
    int idx = base + t;
    int val = (idx < nb) ? bsum[idx] : 0;
    sm[t] = val;
    __syncthreads();
    for (int off = 1; off < 256; off <<= 1) {
      int v = (t >= off) ? sm[t - off] : 0;
      __syncthreads();
      sm[t] += v;
      __syncthreads();
    }
    if (idx < nb) boffs[idx] = sm[t] - val + carry;
    carry += sm[255];
    __syncthreads();
  }
}

// writes offs_c[0..N] and offs_r[0..N] from the combined exclusive scan
__global__ void k_scan3(const int* __restrict__ partial, const int* __restrict__ boffs,
                        int* __restrict__ offs_c, int* __restrict__ offs_r,
                        int N, int E) {
  int i = blockIdx.x * 256 + threadIdx.x;
  if (i < 2 * N) {
    int v = partial[i] + boffs[i >> 8];
    if (i < N) offs_c[i] = v;
    else offs_r[i - N] = v - E;  // second half includes total E of first half
  }
  if (i == 0) { offs_c[N] = E; offs_r[N] = E; }
}

__global__ void k_scatter_row(const int* __restrict__ row, const int* __restrict__ offs_r,
                              int* __restrict__ cur_r, int* __restrict__ perm_r, int E) {
  int e = blockIdx.x * blockDim.x + threadIdx.x;
  if (e >= E) return;
  int r = row[e];
  int pos = offs_r[r] + atomicAdd(cur_r + r, 1);
  perm_r[pos] = e;
}

// Fill col lists iterating in row-CSR order -> each col list ~row-ascending
// (approximate sort = L2 locality heuristic for agg; order is perf-only).
// Also emits colof_r (simw) and pstat[pc] = (row, rowCSR-slot) for fused agg.
__global__ void k_scatter_col(const int* __restrict__ perm_r, const int* __restrict__ row,
                              const int* __restrict__ col, const int* __restrict__ offs_c,
                              int* __restrict__ cur_c, int* __restrict__ colof_r,
                              int2* __restrict__ pstat, int E) {
  int rp = blockIdx.x * blockDim.x + threadIdx.x;
  if (rp >= E) return;
  int e = perm_r[rp];
  int c = col[e];
  colof_r[rp] = c;
  int pos = offs_c[c] + atomicAdd(cur_c + c, 1);
  int2 rec; rec.x = row[e]; rec.y = rp;
  pstat[pos] = rec;
}

// ------- fused per-row: bf16 cosine sims (fp32 recompute in guard band) +
//         threshold + rowsum/deg + weight (+gating) + colw atomic.
//         16-lane group per edge (20 VGPR, ~72% occupancy — R4/R6 design).
__global__ __launch_bounds__(128) void k_simw(
    const float* __restrict__ xn, const __hip_bfloat16* __restrict__ xnb,
    const int* __restrict__ colof_r, const int* __restrict__ offs_r,
    float* __restrict__ adjr, float* __restrict__ wgr, float* __restrict__ colw,
    const float* __restrict__ gate, int layer) {
  int r = blockIdx.x;
  int t = threadIdx.x;
  int p0 = offs_r[r], p1 = offs_r[r + 1];
  int ne = p1 - p0;                      // ~17 (Poisson(16) + self loop), <320
  __shared__ float xr[128];
  __shared__ float sims[320];
  __shared__ int scol[320];
  __shared__ float redv[2];
  __shared__ int redc[2];
  xr[t] = xn[(size_t)r * F + t];
  __syncthreads();
  int g = t >> 4, l = t & 15;
  float4 a0 = *(const float4*)(xr + l * 8);
  float4 a1 = *(const float4*)(xr + l * 8 + 4);
  for (int i = g; i < ne; i += 8) {
    int c = colof_r[p0 + i];             // broadcast within group
    ushort8v bv = *(const ushort8v*)(xnb + (size_t)c * F + l * 8);  // 16B gather
    float s = a0.x * bfu(bv[0]) + a0.y * bfu(bv[1]) + a0.z * bfu(bv[2]) + a0.w * bfu(bv[3])
            + a1.x * bfu(bv[4]) + a1.y * bfu(bv[5]) + a1.z * bfu(bv[6]) + a1.w * bfu(bv[7]);
#pragma unroll
    for (int m = 8; m >= 1; m >>= 1) s += __shfl_xor(s, m);
    bool self = (r == c);
    // bf16 worst-case dot error <= 2^-9 < 0.002; only the guard band can flip
    if (!self && fabsf(s - 0.1f) < 0.02f) {
      const float4* bp = (const float4*)(xn + (size_t)c * F);
      float4 b0 = bp[l * 2], b1 = bp[l * 2 + 1];
      float s2 = a0.x * b0.x + a0.y * b0.y + a0.z * b0.z + a0.w * b0.w
               + a1.x * b1.x + a1.y * b1.y + a1.z * b1.z + a1.w * b1.w;
#pragma unroll
      for (int m = 8; m >= 1; m >>= 1) s2 += __shfl_xor(s2, m);
      s = s2;
    }
    if (l == 0) {
      if (s < 0.1f || self) s = 0.0f;
      sims[i] = s;
      scol[i] = c;
    }
  }
  __syncthreads();
  float v = 0.f; int cn = 0;
  for (int i = t; i < ne; i += 128) {
    float s = sims[i];
    v += s;
    cn += (s > 0.f) ? 1 : 0;
  }
#pragma unroll
  for (int m = 32; m >= 1; m >>= 1) { v += __shfl_xor(v, m); cn += __shfl_xor(cn, m); }
  if ((t & 63) == 0) { redv[t >> 6] = v; redc[t >> 6] = cn; }
  __syncthreads();
  float rs = redv[0] + redv[1];
  int deg = redc[0] + redc[1];
  float lam = 1.0f / (float)(deg + 1);
  float gg = (layer > 0) ? gate[layer - 1] : 0.f;
  for (int i = t; i < ne; i += 128) {
    int c = scol[i];
    float s = sims[i];
    float sn = (rs > 0.f) ? s / rs : 0.f;
    float w = (r == c) ? lam : sn;
    w = expf(w);                          // thresholded edges get exp(0)=1
    float wc;
    if (layer == 0) { adjr[p0 + i] = w; wc = w; }
    else { wc = gg * adjr[p0 + i] + (1.f - gg) * w; }
    wgr[p0 + i] = wc;                     // sequential write (no RMW scatter)
    atomicAdd(colw + c, wc);              // 200KB table, L2-resident
  }
}

// ------ GEMM: out_bf16[M,128] = A[M,128] @ W[128,128], register-tiled -------
__global__ __launch_bounds__(256) void k_gemm128(const float* __restrict__ A,
                                                 const float* __restrict__ W,
                                                 __hip_bfloat16* __restrict__ out, int M) {
  __shared__ float As[128][36];
  int t = threadIdx.x;
  int n0 = blockIdx.x * 32;
  for (int i = t; i < 32 * 128; i += 256) {
    int nn = i >> 7, kk = i & 127;
    int gn = n0 + nn;
    As[kk][nn] = (gn < M) ? A[(size_t)gn * 128 + kk] : 0.f;
  }
  __syncthreads();
  int nb = (t >> 6) * 8;
  int j2 = (t & 63) * 2;
  float acc[8][2] = {};
  for (int k = 0; k < 128; ++k) {
    float4 a01 = *(const float4*)&As[k][nb];
    float4 a23 = *(const float4*)&As[k][nb + 4];
    float2 wv = *(const float2*)&W[k * 128 + j2];
    acc[0][0] += a01.x * wv.x; acc[0][1] += a01.x * wv.y;
    acc[1][0] += a01.y * wv.x; acc[1][1] += a01.y * wv.y;
    acc[2][0] += a01.z * wv.x; acc[2][1] += a01.z * wv.y;
    acc[3][0] += a01.w * wv.x; acc[3][1] += a01.w * wv.y;
    acc[4][0] += a23.x * wv.x; acc[4][1] += a23.x * wv.y;
    acc[5][0] += a23.y * wv.x; acc[5][1] += a23.y * wv.y;
    acc[6][0] += a23.z * wv.x; acc[6][1] += a23.z * wv.y;
    acc[7][0] += a23.w * wv.x; acc[7][1] += a23.w * wv.y;
  }
  __hip_bfloat162* o2 = (__hip_bfloat162*)out;
#pragma unroll
  for (int i = 0; i < 8; ++i) {
    int gn = n0 + nb + i;
    if (gn < M) {
      __hip_bfloat162 o;
      o.x = __float2bfloat16(acc[i][0]); o.y = __float2bfloat16(acc[i][1]);
      o2[(size_t)gn * 64 + (j2 >> 1)] = o;
    }
  }
}

// ------ GEMM: out_bf16[M,40] = A[M,128] @ W[128,40], register-tiled ---------
__global__ __launch_bounds__(320) void k_gemm40(const float* __restrict__ A,
                                                const float* __restrict__ W,
                                                __hip_bfloat16* __restrict__ out,
                                                int M, int C) {
  __shared__ float As[128][68];
  int t = threadIdx.x;
  int n0 = blockIdx.x * 64;
  for (int i = t; i < 64 * 128; i += 320) {
    int nn = i >> 7, kk = i & 127;
    int gn = n0 + nn;
    As[kk][nn] = (gn < M) ? A[(size_t)gn * 128 + kk] : 0.f;
  }
  __syncthreads();
  int gq = t / 40;
  int jc = t - gq * 40;
  int nb = gq * 8;
  float acc[8] = {};
  for (int k = 0; k < 128; ++k) {
    float4 a01 = *(const float4*)&As[k][nb];
    float4 a23 = *(const float4*)&As[k][nb + 4];
    float wv = W[k * C + jc];
    acc[0] += a01.x * wv; acc[1] += a01.y * wv; acc[2] += a01.z * wv; acc[3] += a01.w * wv;
    acc[4] += a23.x * wv; acc[5] += a23.y * wv; acc[6] += a23.z * wv; acc[7] += a23.w * wv;
  }
#pragma unroll
  for (int i = 0; i < 8; ++i) {
    int gn = n0 + nb + i;
    if (gn < M) out[(size_t)gn * C + jc] = __float2bfloat16(acc[i]);
  }
}

// ---- fused: per-edge norm (was k_prep) + aggregation + bias + relu +
//      row-normalize of result. Wave per node, unroll x4. ----
__global__ __launch_bounds__(256) void k_agg_norm(
    const __hip_bfloat162* __restrict__ hWb, const int2* __restrict__ pstat,
    const float* __restrict__ wgr, const float* __restrict__ colw,
    const int* __restrict__ offs_c, const float* __restrict__ bias,
    float* __restrict__ out, float* __restrict__ xn, __hip_bfloat16* __restrict__ xnb,
    int N) {
  int w = threadIdx.x >> 6;
  int t = threadIdx.x & 63;
  int c = blockIdx.x * 4 + w;
  if (c >= N) return;
  int p0 = offs_c[c], p1 = offs_c[c + 1];
  float dcv = colw[c];
  float dic = (dcv > 0.f) ? rsqrtf(dcv) : 0.f;
  float acc0 = bias[2 * t], acc1 = bias[2 * t + 1];
  int p = p0;
  for (; p + 4 <= p1; p += 4) {   // 4 row-gathers in flight
    int2 s0 = pstat[p], s1 = pstat[p + 1], s2 = pstat[p + 2], s3 = pstat[p + 3];
    float w0 = wgr[s0.y], w1 = wgr[s1.y], w2 = wgr[s2.y], w3 = wgr[s3.y];
    float d0 = colw[s0.x], d1 = colw[s1.x], d2 = colw[s2.x], d3 = colw[s3.x];
    __hip_bfloat162 h0 = hWb[(size_t)s0.x * 64 + t];
    __hip_bfloat162 h1 = hWb[(size_t)s1.x * 64 + t];
    __hip_bfloat162 h2 = hWb[(size_t)s2.x * 64 + t];
    __hip_bfloat162 h3 = hWb[(size_t)s3.x * 64 + t];
    float n0 = ((d0 > 0.f) ? rsqrtf(d0) : 0.f) * w0 * dic;
    float n1 = ((d1 > 0.f) ? rsqrtf(d1) : 0.f) * w1 * dic;
    float n2 = ((d2 > 0.f) ? rsqrtf(d2) : 0.f) * w2 * dic;
    float n3 = ((d3 > 0.f) ? rsqrtf(d3) : 0.f) * w3 * dic;
    acc0 += n0 * __bfloat162float(h0.x) + n1 * __bfloat162float(h1.x)
          + n2 * __bfloat162float(h2.x) + n3 * __bfloat162float(h3.x);
    acc1 += n0 * __bfloat162float(h0.y) + n1 * __bfloat162float(h1.y)
          + n2 * __bfloat162float(h2.y) + n3 * __bfloat162float(h3.y);
  }
  for (; p < p1; ++p) {
    int2 s0 = pstat[p];
    float w0 = wgr[s0.y];
    float d0 = colw[s0.x];
    __hip_bfloat162 h0 = hWb[(size_t)s0.x * 64 + t];
    float n0 = ((d0 > 0.f) ? rsqrtf(d0) : 0.f) * w0 * dic;
    acc0 += n0 * __bfloat162float(h0.x);
    acc1 += n0 * __bfloat162float(h0.y);
  }
  acc0 = fmaxf(acc0, 0.f); acc1 = fmaxf(acc1, 0.f);
  float2 o; o.x = acc0; o.y = acc1;
  ((float2*)out)[(size_t)c * 64 + t] = o;
  float ss = acc0 * acc0 + acc1 * acc1;
#pragma unroll
  for (int m = 32; m >= 1; m >>= 1) ss += __shfl_xor(ss, m);
  float inv = 1.0f / fmaxf(sqrtf(ss), 1e-12f);
  float2 on; on.x = acc0 * inv; on.y = acc1 * inv;
  ((float2*)xn)[(size_t)c * 64 + t] = on;
  __hip_bfloat162 ob;
  ob.x = __float2bfloat16(on.x); ob.y = __float2bfloat16(on.y);
  ((__hip_bfloat162*)xnb)[(size_t)c * 64 + t] = ob;
}

// ------- fused final aggregation + bias + log_softmax; wave per node --------
__global__ __launch_bounds__(256) void k_agg40_lsm(
    const __hip_bfloat16* __restrict__ hW, const int2* __restrict__ pstat,
    const float* __restrict__ wgr, const float* __restrict__ colw,
    const int* __restrict__ offs_c, const float* __restrict__ bias,
    float* __restrict__ out, int C, int N) {
  int w = threadIdx.x >> 6;
  int j = threadIdx.x & 63;
  int c = blockIdx.x * 4 + w;
  if (c >= N) return;
  int p0 = offs_c[c], p1 = offs_c[c + 1];
  float dcv = colw[c];
  float dic = (dcv > 0.f) ? rsqrtf(dcv) : 0.f;
  bool act = j < C;
  int jj = act ? j : 0;
  float acc = act ? bias[jj] : 0.f;
  int p = p0;
  for (; p + 4 <= p1; p += 4) {
    int2 s0 = pstat[p], s1 = pstat[p + 1], s2 = pstat[p + 2], s3 = pstat[p + 3];
    float w0 = wgr[s0.y], w1 = wgr[s1.y], w2 = wgr[s2.y], w3 = wgr[s3.y];
    float d0 = colw[s0.x], d1 = colw[s1.x], d2 = colw[s2.x], d3 = colw[s3.x];
    float h0 = __bfloat162float(hW[(size_t)s0.x * C + jj]);
    float h1 = __bfloat162float(hW[(size_t)s1.x * C + jj]);
    float h2 = __bfloat162float(hW[(size_t)s2.x * C + jj]);
    float h3 = __bfloat162float(hW[(size_t)s3.x * C + jj]);
    acc += ((d0 > 0.f) ? rsqrtf(d0) : 0.f) * w0 * dic * h0
         + ((d1 > 0.f) ? rsqrtf(d1) : 0.f) * w1 * dic * h1
         + ((d2 > 0.f) ? rsqrtf(d2) : 0.f) * w2 * dic * h2
         + ((d3 > 0.f) ? rsqrtf(d3) : 0.f) * w3 * dic * h3;
  }
  for (; p < p1; ++p) {
    int2 s0 = pstat[p];
    float w0 = wgr[s0.y];
    float d0 = colw[s0.x];
    acc += ((d0 > 0.f) ? rsqrtf(d0) : 0.f) * w0 * dic
         * __bfloat162float(hW[(size_t)s0.x * C + jj]);
  }
  if (!act) acc = 0.f;
  float v = act ? acc : -3.0e38f;
#pragma unroll
  for (int m = 32; m >= 1; m >>= 1) v = fmaxf(v, __shfl_xor(v, m));
  float ex = act ? expf(acc - v) : 0.f;
#pragma unroll
  for (int m = 32; m >= 1; m >>= 1) ex += __shfl_xor(ex, m);
  if (act) out[(size_t)c * C + j] = acc - v - logf(ex);
}

extern "C" void kernel_launch(void* const* d_in, const int* in_sizes, int n_in,
                              void* d_out, int out_size, void* d_ws, size_t ws_size,
                              hipStream_t stream) {
  const float* x    = (const float*)d_in[0];
  const float* gate = (const float*)d_in[1];
  const float* W0   = (const float*)d_in[2];
  const float* b0   = (const float*)d_in[3];
  const float* W1   = (const float*)d_in[4];
  const float* b1   = (const float*)d_in[5];
  const float* W2   = (const float*)d_in[6];
  const float* b2   = (const float*)d_in[7];
  const int* eidx   = (const int*)d_in[8];
  int N = in_sizes[0] / 128;
  int E = in_sizes[8] / 2;
  int C = in_sizes[7];  // 40
  const int* row = eidx;
  const int* col = eidx + E;

  char* ws = (char*)d_ws;
  size_t off = 0;
  auto alloc = [&](size_t bytes) {
    char* p = ws + off;
    off += (bytes + 255) & ~(size_t)255;
    return p;
  };
  float* xn     = (float*)alloc((size_t)N * 128 * 4);
  __hip_bfloat16* xnb = (__hip_bfloat16*)alloc((size_t)N * 128 * 2);
  float* bufC   = (float*)alloc((size_t)N * 128 * 4);
  __hip_bfloat16* hWb = (__hip_bfloat16*)alloc((size_t)N * 128 * 2);
  float* adjr   = (float*)alloc((size_t)E * 4);    // layer-0 weights, row-CSR order
  float* wgr    = (float*)alloc((size_t)E * 4);    // gated weight, row-CSR order
  int*   perm_r = (int*)alloc((size_t)E * 4);
  int2*  pstat  = (int2*)alloc((size_t)E * 8);     // (row, rowCSR-slot) per col slot
  int*   colof_r= (int*)alloc((size_t)E * 4);
  int*   offs_c = (int*)alloc((size_t)(N + 1) * 4);
  int*   offs_r = (int*)alloc((size_t)(N + 1) * 4);
  int*   cntB   = (int*)alloc((size_t)N * 4 * 4);  // cnt[2N] + cur[2N]
  int*   curB   = cntB + 2 * N;
  int*   partial= (int*)alloc((size_t)N * 4 * 2);  // 2N
  int*   bsum   = (int*)alloc(2048);
  int*   boffs  = (int*)alloc(2048);
  float* colw   = (float*)alloc((size_t)N * 4);

  int eb  = (E + 255) / 256;
  int nb2 = (2 * N + 255) / 256;
  int nw4 = (N + 3) / 4;

  // ---- build row-CSR, then row-sorted col-CSR + static maps (7 dispatches) -
  hipMemsetAsync(cntB, 0, (size_t)N * 4 * 4, stream);
  k_hist2<<<eb, 256, 0, stream>>>(row, col, cntB, N, E);
  k_scan1<<<nb2, 256, 0, stream>>>(cntB, partial, bsum, 2 * N);
  k_scan2<<<1, 256, 0, stream>>>(bsum, boffs, nb2);
  k_scan3<<<nb2, 256, 0, stream>>>(partial, boffs, offs_c, offs_r, N, E);
  k_scatter_row<<<eb, 256, 0, stream>>>(row, offs_r, curB + N, perm_r, E);
  k_scatter_col<<<eb, 256, 0, stream>>>(perm_r, row, col, offs_c, curB,
                                        colof_r, pstat, E);

  for (int layer = 0; layer < 3; ++layer) {
    hipMemsetAsync(colw, 0, (size_t)N * 4, stream);
    if (layer == 0) k_normalize<<<(N + 3) / 4, 256, 0, stream>>>(x, xn, xnb, N);
    k_simw<<<N, 128, 0, stream>>>(xn, xnb, colof_r, offs_r, adjr, wgr, colw, gate, layer);
    const float* hin = (layer == 0) ? x : bufC;
    if (layer < 2) {
      const float* W = (layer == 0) ? W0 : W1;
      const float* b = (layer == 0) ? b0 : b1;
      k_gemm128<<<(N + 31) / 32, 256, 0, stream>>>(hin, W, hWb, N);
      k_agg_norm<<<nw4, 256, 0, stream>>>((const __hip_bfloat162*)hWb, pstat, wgr, colw,
                                          offs_c, b, bufC, xn, xnb, N);
    } else {
      k_gemm40<<<(N + 63) / 64, 320, 0, stream>>>(hin, W2, hWb, N, C);
      k_agg40_lsm<<<nw4, 256, 0, stream>>>(hWb, pstat, wgr, colw, offs_c, b2,
                                           (float*)d_out, C, N);
    }
  }
}

// Round 8
// 700.019 us; speedup vs baseline: 1.4275x; 1.0209x over previous
//
#include <hip/hip_runtime.h>
#include <hip/hip_bf16.h>
#include <math.h>

#define F 128

typedef __attribute__((ext_vector_type(8))) short bf16x8;
typedef __attribute__((ext_vector_type(4))) float f32x4;

// ------- row-normalize: xn = x/max(||x||,eps) (fp32 + bf16 copies) ----------
__global__ void k_normalize(const float* __restrict__ x, float* __restrict__ xn,
                            __hip_bfloat16* __restrict__ xnb, int N) {
  int wid = (blockIdx.x * blockDim.x + threadIdx.x) >> 6;  // one wave per node
  int lane = threadIdx.x & 63;
  if (wid >= N) return;
  const float2* src = (const float2*)(x + (size_t)wid * F);
  float2 v = src[lane];
  float ss = v.x * v.x + v.y * v.y;
#pragma unroll
  for (int m = 32; m >= 1; m >>= 1) ss += __shfl_xor(ss, m);
  float inv = 1.0f / fmaxf(sqrtf(ss), 1e-12f);
  float2 o; o.x = v.x * inv; o.y = v.y * inv;
  ((float2*)(xn + (size_t)wid * F))[lane] = o;
  __hip_bfloat162 ob;
  ob.x = __float2bfloat16(o.x); ob.y = __float2bfloat16(o.y);
  ((__hip_bfloat162*)(xnb + (size_t)wid * F))[lane] = ob;
}

// ---------------- CSR build ----------------
// cntBoth layout: [0,N) col counts, [N,2N) row counts (scanned as one array)
__global__ void k_hist2(const int* __restrict__ row, const int* __restrict__ col,
                        int* __restrict__ cntBoth, int N, int E) {
  int e = blockIdx.x * blockDim.x + threadIdx.x;
  if (e < E) { atomicAdd(cntBoth + col[e], 1); atomicAdd(cntBoth + N + row[e], 1); }
}

__global__ void k_scan1(const int* __restrict__ cnt, int* __restrict__ partial,
                        int* __restrict__ bsum, int M) {
  __shared__ int sm[256];
  int t = threadIdx.x;
  int i = blockIdx.x * 256 + t;
  int val = (i < M) ? cnt[i] : 0;
  sm[t] = val;
  __syncthreads();
  for (int off = 1; off < 256; off <<= 1) {
    int v = (t >= off) ? sm[t - off] : 0;
    __syncthreads();
    sm[t] += v;
    __syncthreads();
  }
  if (i < M) partial[i] = sm[t] - val;  // exclusive
  if (t == 255) bsum[blockIdx.x] = sm[255];
}

// looped single-block scan (handles nb > 256)
__global__ void k_scan2(const int* __restrict__ bsum, int* __restrict__ boffs, int nb) {
  __shared__ int sm[256];
  int t = threadIdx.x;
  int carry = 0;
  for (int base = 0; base < nb; base += 256) {
    int idx = base + t;
    int val = (idx < nb) ? bsum[idx] : 0;
    sm[t] = val;
    __syncthreads();
    for (int off = 1; off < 256; off <<= 1) {
      int v = (t >= off) ? sm[t - off] : 0;
      __syncthreads();
      sm[t] += v;
      __syncthreads();
    }
    if (idx < nb) boffs[idx] = sm[t] - val + carry;
    carry += sm[255];
    __syncthreads();
  }
}

__global__ void k_scan3(const int* __restrict__ partial, const int* __restrict__ boffs,
                        int* __restrict__ offs_c, int* __restrict__ offs_r,
                        int N, int E) {
  int i = blockIdx.x * 256 + threadIdx.x;
  if (i < 2 * N) {
    int v = partial[i] + boffs[i >> 8];
    if (i < N) offs_c[i] = v;
    else offs_r[i - N] = v - E;  // second half includes total E of first half
  }
  if (i == 0) { offs_c[N] = E; offs_r[N] = E; }
}

__global__ void k_scatter_row(const int* __restrict__ row, const int* __restrict__ offs_r,
                              int* __restrict__ cur_r, int* __restrict__ perm_r, int E) {
  int e = blockIdx.x * blockDim.x + threadIdx.x;
  if (e >= E) return;
  int r = row[e];
  int pos = offs_r[r] + atomicAdd(cur_r + r, 1);
  perm_r[pos] = e;
}

// Fill col lists iterating in row-CSR order -> each col list ~row-ascending
// (L2 locality for agg). Emits colof_r and pstat[pc] = (row, rowCSR-slot).
__global__ void k_scatter_col(const int* __restrict__ perm_r, const int* __restrict__ row,
                              const int* __restrict__ col, const int* __restrict__ offs_c,
                              int* __restrict__ cur_c, int* __restrict__ colof_r,
                              int2* __restrict__ pstat, int E) {
  int rp = blockIdx.x * blockDim.x + threadIdx.x;
  if (rp >= E) return;
  int e = perm_r[rp];
  int c = col[e];
  colof_r[rp] = c;
  int pos = offs_c[c] + atomicAdd(cur_c + c, 1);
  int2 rec; rec.x = row[e]; rec.y = rp;
  pstat[pos] = rec;
}

// ------- fused per-row sims + weights, MFMA edition. One wave per row.
//   sims(row) = A @ b: A = neighbor rows (bf16, 16 per MFMA tile),
//   B = self row replicated across all 16 columns -> every D column equals
//   the sims vector. Layouts per learn_hip m118/m120/m122:
//   A[m=lane&15][k=quad*8+j], B[k=quad*8+j][n], D: col=lane&15, row=quad*4+reg.
//   Guard band +-0.03 (bf16 A+B dot err <= 0.0043) -> fp32 wave recompute.
__global__ __launch_bounds__(256) void k_simw(
    const float* __restrict__ xn, const __hip_bfloat16* __restrict__ xnb,
    const int* __restrict__ colof_r, const int* __restrict__ offs_r,
    float* __restrict__ adjr, float* __restrict__ wgr, float* __restrict__ colw,
    const float* __restrict__ gate, int layer, int N) {
  int w = threadIdx.x >> 6;   // wave 0..3, one row each
  int l = threadIdx.x & 63;
  int r = blockIdx.x * 4 + w;
  __shared__ float sims[4][320];
  __shared__ int scol[4][320];
  if (r >= N) return;
  int p0 = offs_r[r], p1 = offs_r[r + 1];
  int ne = p1 - p0;                     // ~17 (Poisson(16) + self loop), <320
  int quad = l >> 4;
  int m = l & 15;
  int qoff = quad * 8;
  const __hip_bfloat16* xr = xnb + (size_t)r * F;
  bf16x8 b0 = *(const bf16x8*)(xr + 0 * 32 + qoff);   // 16-lane broadcast loads
  bf16x8 b1 = *(const bf16x8*)(xr + 1 * 32 + qoff);
  bf16x8 b2 = *(const bf16x8*)(xr + 2 * 32 + qoff);
  bf16x8 b3 = *(const bf16x8*)(xr + 3 * 32 + qoff);
  for (int tb = 0; tb < ne; tb += 16) {
    int ii = tb + m; if (ii > ne - 1) ii = ne - 1;     // clamp (extra rows ignored)
    int cm = colof_r[p0 + ii];
    if (quad == 0 && tb + m < ne) scol[w][tb + m] = cm;
    const __hip_bfloat16* xc = xnb + (size_t)cm * F;
    bf16x8 a0 = *(const bf16x8*)(xc + 0 * 32 + qoff);  // 4 independent 16B gathers
    bf16x8 a1 = *(const bf16x8*)(xc + 1 * 32 + qoff);
    bf16x8 a2 = *(const bf16x8*)(xc + 2 * 32 + qoff);
    bf16x8 a3 = *(const bf16x8*)(xc + 3 * 32 + qoff);
    f32x4 acc = {0.f, 0.f, 0.f, 0.f};
    acc = __builtin_amdgcn_mfma_f32_16x16x32_bf16(a0, b0, acc, 0, 0, 0);
    acc = __builtin_amdgcn_mfma_f32_16x16x32_bf16(a1, b1, acc, 0, 0, 0);
    acc = __builtin_amdgcn_mfma_f32_16x16x32_bf16(a2, b2, acc, 0, 0, 0);
    acc = __builtin_amdgcn_mfma_f32_16x16x32_bf16(a3, b3, acc, 0, 0, 0);
    if (m == 0) {                       // lanes 0,16,32,48 hold rows quad*4+reg
#pragma unroll
      for (int reg = 0; reg < 4; ++reg) {
        int i = tb + quad * 4 + reg;
        if (i < ne) sims[w][i] = acc[reg];
      }
    }
  }
  // pass 2: guard-band fp32 recompute + threshold + rowsum/deg (one wave)
  float vsum = 0.f; int cn = 0;
  for (int base = 0; base < ne; base += 64) {
    int i = base + l;
    bool have = i < ne;
    float s = have ? sims[w][i] : 0.f;
    int c = have ? scol[w][i] : r;
    bool self = (c == r);
    bool flag = have && !self && fabsf(s - 0.1f) < 0.03f;
    unsigned long long mask = __ballot(flag);
    while (mask) {                      // ~1 flagged edge/row: wave-coop fp32 dot
      int src = __ffsll(mask) - 1;
      mask &= mask - 1;
      int cc = __shfl(c, src);
      float2 ar = ((const float2*)(xn + (size_t)r * F))[l];
      float2 bc = ((const float2*)(xn + (size_t)cc * F))[l];
      float d = ar.x * bc.x + ar.y * bc.y;
#pragma unroll
      for (int mm = 32; mm >= 1; mm >>= 1) d += __shfl_xor(d, mm);
      if (l == src) s = d;
    }
    if (self || s < 0.1f) s = 0.f;
    if (have) sims[w][i] = s;
    vsum += s;
    cn += (s > 0.f) ? 1 : 0;
  }
#pragma unroll
  for (int mm = 32; mm >= 1; mm >>= 1) {
    vsum += __shfl_xor(vsum, mm);
    cn += __shfl_xor(cn, mm);
  }
  float rs = vsum;
  float lam = 1.0f / (float)(cn + 1);
  float gg = (layer > 0) ? gate[layer - 1] : 0.f;
  for (int i = l; i < ne; i += 64) {
    int c = scol[w][i];
    float s = sims[w][i];
    float sn = (rs > 0.f) ? s / rs : 0.f;
    float wv = (c == r) ? lam : sn;
    wv = expf(wv);                      // thresholded edges get exp(0)=1
    float wc;
    if (layer == 0) { adjr[p0 + i] = wv; wc = wv; }
    else { wc = gg * adjr[p0 + i] + (1.f - gg) * wv; }
    wgr[p0 + i] = wc;                   // sequential write
    atomicAdd(colw + c, wc);            // 200KB table, L2-resident
  }
}

// ------ GEMM: out_bf16[M,128] = A[M,128] @ W[128,128], register-tiled -------
__global__ __launch_bounds__(256) void k_gemm128(const float* __restrict__ A,
                                                 const float* __restrict__ W,
                                                 __hip_bfloat16* __restrict__ out, int M) {
  __shared__ float As[128][36];
  int t = threadIdx.x;
  int n0 = blockIdx.x * 32;
  for (int i = t; i < 32 * 128; i += 256) {
    int nn = i >> 7, kk = i & 127;
    int gn = n0 + nn;
    As[kk][nn] = (gn < M) ? A[(size_t)gn * 128 + kk] : 0.f;
  }
  __syncthreads();
  int nb = (t >> 6) * 8;
  int j2 = (t & 63) * 2;
  float acc[8][2] = {};
  for (int k = 0; k < 128; ++k) {
    float4 a01 = *(const float4*)&As[k][nb];
    float4 a23 = *(const float4*)&As[k][nb + 4];
    float2 wv = *(const float2*)&W[k * 128 + j2];
    acc[0][0] += a01.x * wv.x; acc[0][1] += a01.x * wv.y;
    acc[1][0] += a01.y * wv.x; acc[1][1] += a01.y * wv.y;
    acc[2][0] += a01.z * wv.x; acc[2][1] += a01.z * wv.y;
    acc[3][0] += a01.w * wv.x; acc[3][1] += a01.w * wv.y;
    acc[4][0] += a23.x * wv.x; acc[4][1] += a23.x * wv.y;
    acc[5][0] += a23.y * wv.x; acc[5][1] += a23.y * wv.y;
    acc[6][0] += a23.z * wv.x; acc[6][1] += a23.z * wv.y;
    acc[7][0] += a23.w * wv.x; acc[7][1] += a23.w * wv.y;
  }
  __hip_bfloat162* o2 = (__hip_bfloat162*)out;
#pragma unroll
  for (int i = 0; i < 8; ++i) {
    int gn = n0 + nb + i;
    if (gn < M) {
      __hip_bfloat162 o;
      o.x = __float2bfloat16(acc[i][0]); o.y = __float2bfloat16(acc[i][1]);
      o2[(size_t)gn * 64 + (j2 >> 1)] = o;
    }
  }
}

// ------ GEMM: out_bf16[M,40] = A[M,128] @ W[128,40], register-tiled ---------
__global__ __launch_bounds__(320) void k_gemm40(const float* __restrict__ A,
                                                const float* __restrict__ W,
                                                __hip_bfloat16* __restrict__ out,
                                                int M, int C) {
  __shared__ float As[128][68];
  int t = threadIdx.x;
  int n0 = blockIdx.x * 64;
  for (int i = t; i < 64 * 128; i += 320) {
    int nn = i >> 7, kk = i & 127;
    int gn = n0 + nn;
    As[kk][nn] = (gn < M) ? A[(size_t)gn * 128 + kk] : 0.f;
  }
  __syncthreads();
  int gq = t / 40;
  int jc = t - gq * 40;
  int nb = gq * 8;
  float acc[8] = {};
  for (int k = 0; k < 128; ++k) {
    float4 a01 = *(const float4*)&As[k][nb];
    float4 a23 = *(const float4*)&As[k][nb + 4];
    float wv = W[k * C + jc];
    acc[0] += a01.x * wv; acc[1] += a01.y * wv; acc[2] += a01.z * wv; acc[3] += a01.w * wv;
    acc[4] += a23.x * wv; acc[5] += a23.y * wv; acc[6] += a23.z * wv; acc[7] += a23.w * wv;
  }
#pragma unroll
  for (int i = 0; i < 8; ++i) {
    int gn = n0 + nb + i;
    if (gn < M) out[(size_t)gn * C + jc] = __float2bfloat16(acc[i]);
  }
}

// ---- fused: per-edge norm + aggregation + bias + relu + row-normalize ------
__global__ __launch_bounds__(256) void k_agg_norm(
    const __hip_bfloat162* __restrict__ hWb, const int2* __restrict__ pstat,
    const float* __restrict__ wgr, const float* __restrict__ colw,
    const int* __restrict__ offs_c, const float* __restrict__ bias,
    float* __restrict__ out, float* __restrict__ xn, __hip_bfloat16* __restrict__ xnb,
    int N) {
  int w = threadIdx.x >> 6;
  int t = threadIdx.x & 63;
  int c = blockIdx.x * 4 + w;
  if (c >= N) return;
  int p0 = offs_c[c], p1 = offs_c[c + 1];
  float dcv = colw[c];
  float dic = (dcv > 0.f) ? rsqrtf(dcv) : 0.f;
  float acc0 = bias[2 * t], acc1 = bias[2 * t + 1];
  int p = p0;
  for (; p + 4 <= p1; p += 4) {   // 4 row-gathers in flight
    int2 s0 = pstat[p], s1 = pstat[p + 1], s2 = pstat[p + 2], s3 = pstat[p + 3];
    float w0 = wgr[s0.y], w1 = wgr[s1.y], w2 = wgr[s2.y], w3 = wgr[s3.y];
    float d0 = colw[s0.x], d1 = colw[s1.x], d2 = colw[s2.x], d3 = colw[s3.x];
    __hip_bfloat162 h0 = hWb[(size_t)s0.x * 64 + t];
    __hip_bfloat162 h1 = hWb[(size_t)s1.x * 64 + t];
    __hip_bfloat162 h2 = hWb[(size_t)s2.x * 64 + t];
    __hip_bfloat162 h3 = hWb[(size_t)s3.x * 64 + t];
    float n0 = ((d0 > 0.f) ? rsqrtf(d0) : 0.f) * w0 * dic;
    float n1 = ((d1 > 0.f) ? rsqrtf(d1) : 0.f) * w1 * dic;
    float n2 = ((d2 > 0.f) ? rsqrtf(d2) : 0.f) * w2 * dic;
    float n3 = ((d3 > 0.f) ? rsqrtf(d3) : 0.f) * w3 * dic;
    acc0 += n0 * __bfloat162float(h0.x) + n1 * __bfloat162float(h1.x)
          + n2 * __bfloat162float(h2.x) + n3 * __bfloat162float(h3.x);
    acc1 += n0 * __bfloat162float(h0.y) + n1 * __bfloat162float(h1.y)
          + n2 * __bfloat162float(h2.y) + n3 * __bfloat162float(h3.y);
  }
  for (; p < p1; ++p) {
    int2 s0 = pstat[p];
    float w0 = wgr[s0.y];
    float d0 = colw[s0.x];
    __hip_bfloat162 h0 = hWb[(size_t)s0.x * 64 + t];
    float n0 = ((d0 > 0.f) ? rsqrtf(d0) : 0.f) * w0 * dic;
    acc0 += n0 * __bfloat162float(h0.x);
    acc1 += n0 * __bfloat162float(h0.y);
  }
  acc0 = fmaxf(acc0, 0.f); acc1 = fmaxf(acc1, 0.f);
  float2 o; o.x = acc0; o.y = acc1;
  ((float2*)out)[(size_t)c * 64 + t] = o;
  float ss = acc0 * acc0 + acc1 * acc1;
#pragma unroll
  for (int m = 32; m >= 1; m >>= 1) ss += __shfl_xor(ss, m);
  float inv = 1.0f / fmaxf(sqrtf(ss), 1e-12f);
  float2 on; on.x = acc0 * inv; on.y = acc1 * inv;
  ((float2*)xn)[(size_t)c * 64 + t] = on;
  __hip_bfloat162 ob;
  ob.x = __float2bfloat16(on.x); ob.y = __float2bfloat16(on.y);
  ((__hip_bfloat162*)xnb)[(size_t)c * 64 + t] = ob;
}

// ------- fused final aggregation + bias + log_softmax; wave per node --------
__global__ __launch_bounds__(256) void k_agg40_lsm(
    const __hip_bfloat16* __restrict__ hW, const int2* __restrict__ pstat,
    const float* __restrict__ wgr, const float* __restrict__ colw,
    const int* __restrict__ offs_c, const float* __restrict__ bias,
    float* __restrict__ out, int C, int N) {
  int w = threadIdx.x >> 6;
  int j = threadIdx.x & 63;
  int c = blockIdx.x * 4 + w;
  if (c >= N) return;
  int p0 = offs_c[c], p1 = offs_c[c + 1];
  float dcv = colw[c];
  float dic = (dcv > 0.f) ? rsqrtf(dcv) : 0.f;
  bool act = j < C;
  int jj = act ? j : 0;
  float acc = act ? bias[jj] : 0.f;
  int p = p0;
  for (; p + 4 <= p1; p += 4) {
    int2 s0 = pstat[p], s1 = pstat[p + 1], s2 = pstat[p + 2], s3 = pstat[p + 3];
    float w0 = wgr[s0.y], w1 = wgr[s1.y], w2 = wgr[s2.y], w3 = wgr[s3.y];
    float d0 = colw[s0.x], d1 = colw[s1.x], d2 = colw[s2.x], d3 = colw[s3.x];
    float h0 = __bfloat162float(hW[(size_t)s0.x * C + jj]);
    float h1 = __bfloat162float(hW[(size_t)s1.x * C + jj]);
    float h2 = __bfloat162float(hW[(size_t)s2.x * C + jj]);
    float h3 = __bfloat162float(hW[(size_t)s3.x * C + jj]);
    acc += ((d0 > 0.f) ? rsqrtf(d0) : 0.f) * w0 * dic * h0
         + ((d1 > 0.f) ? rsqrtf(d1) : 0.f) * w1 * dic * h1
         + ((d2 > 0.f) ? rsqrtf(d2) : 0.f) * w2 * dic * h2
         + ((d3 > 0.f) ? rsqrtf(d3) : 0.f) * w3 * dic * h3;
  }
  for (; p < p1; ++p) {
    int2 s0 = pstat[p];
    float w0 = wgr[s0.y];
    float d0 = colw[s0.x];
    acc += ((d0 > 0.f) ? rsqrtf(d0) : 0.f) * w0 * dic
         * __bfloat162float(hW[(size_t)s0.x * C + jj]);
  }
  if (!act) acc = 0.f;
  float v = act ? acc : -3.0e38f;
#pragma unroll
  for (int m = 32; m >= 1; m >>= 1) v = fmaxf(v, __shfl_xor(v, m));
  float ex = act ? expf(acc - v) : 0.f;
#pragma unroll
  for (int m = 32; m >= 1; m >>= 1) ex += __shfl_xor(ex, m);
  if (act) out[(size_t)c * C + j] = acc - v - logf(ex);
}

extern "C" void kernel_launch(void* const* d_in, const int* in_sizes, int n_in,
                              void* d_out, int out_size, void* d_ws, size_t ws_size,
                              hipStream_t stream) {
  const float* x    = (const float*)d_in[0];
  const float* gate = (const float*)d_in[1];
  const float* W0   = (const float*)d_in[2];
  const float* b0   = (const float*)d_in[3];
  const float* W1   = (const float*)d_in[4];
  const float* b1   = (const float*)d_in[5];
  const float* W2   = (const float*)d_in[6];
  const float* b2   = (const float*)d_in[7];
  const int* eidx   = (const int*)d_in[8];
  int N = in_sizes[0] / 128;
  int E = in_sizes[8] / 2;
  int C = in_sizes[7];  // 40
  const int* row = eidx;
  const int* col = eidx + E;

  char* ws = (char*)d_ws;
  size_t off = 0;
  auto alloc = [&](size_t bytes) {
    char* p = ws + off;
    off += (bytes + 255) & ~(size_t)255;
    return p;
  };
  float* xn     = (float*)alloc((size_t)N * 128 * 4);
  __hip_bfloat16* xnb = (__hip_bfloat16*)alloc((size_t)N * 128 * 2);
  float* bufC   = (float*)alloc((size_t)N * 128 * 4);
  __hip_bfloat16* hWb = (__hip_bfloat16*)alloc((size_t)N * 128 * 2);
  float* adjr   = (float*)alloc((size_t)E * 4);    // layer-0 weights, row-CSR order
  float* wgr    = (float*)alloc((size_t)E * 4);    // gated weight, row-CSR order
  int*   perm_r = (int*)alloc((size_t)E * 4);
  int2*  pstat  = (int2*)alloc((size_t)E * 8);     // (row, rowCSR-slot) per col slot
  int*   colof_r= (int*)alloc((size_t)E * 4);
  int*   offs_c = (int*)alloc((size_t)(N + 1) * 4);
  int*   offs_r = (int*)alloc((size_t)(N + 1) * 4);
  int*   cntB   = (int*)alloc((size_t)N * 4 * 4);  // cnt[2N] + cur[2N]
  int*   curB   = cntB + 2 * N;
  int*   partial= (int*)alloc((size_t)N * 4 * 2);  // 2N
  int*   bsum   = (int*)alloc(2048);
  int*   boffs  = (int*)alloc(2048);
  float* colw   = (float*)alloc((size_t)N * 4);

  int eb  = (E + 255) / 256;
  int nb2 = (2 * N + 255) / 256;
  int nw4 = (N + 3) / 4;

  // ---- build row-CSR, then row-sorted col-CSR + static maps ----
  hipMemsetAsync(cntB, 0, (size_t)N * 4 * 4, stream);
  k_hist2<<<eb, 256, 0, stream>>>(row, col, cntB, N, E);
  k_scan1<<<nb2, 256, 0, stream>>>(cntB, partial, bsum, 2 * N);
  k_scan2<<<1, 256, 0, stream>>>(bsum, boffs, nb2);
  k_scan3<<<nb2, 256, 0, stream>>>(partial, boffs, offs_c, offs_r, N, E);
  k_scatter_row<<<eb, 256, 0, stream>>>(row, offs_r, curB + N, perm_r, E);
  k_scatter_col<<<eb, 256, 0, stream>>>(perm_r, row, col, offs_c, curB,
                                        colof_r, pstat, E);

  for (int layer = 0; layer < 3; ++layer) {
    hipMemsetAsync(colw, 0, (size_t)N * 4, stream);
    if (layer == 0) k_normalize<<<(N + 3) / 4, 256, 0, stream>>>(x, xn, xnb, N);
    k_simw<<<nw4, 256, 0, stream>>>(xn, xnb, colof_r, offs_r, adjr, wgr, colw,
                                    gate, layer, N);
    const float* hin = (layer == 0) ? x : bufC;
    if (layer < 2) {
      const float* W = (layer == 0) ? W0 : W1;
      const float* b = (layer == 0) ? b0 : b1;
      k_gemm128<<<(N + 31) / 32, 256, 0, stream>>>(hin, W, hWb, N);
      k_agg_norm<<<nw4, 256, 0, stream>>>((const __hip_bfloat162*)hWb, pstat, wgr, colw,
                                          offs_c, b, bufC, xn, xnb, N);
    } else {
      k_gemm40<<<(N + 63) / 64, 320, 0, stream>>>(hin, W2, hWb, N, C);
      k_agg40_lsm<<<nw4, 256, 0, stream>>>(hWb, pstat, wgr, colw, offs_c, b2,
                                           (float*)d_out, C, N);
    }
  }
}

// Round 9
// 681.003 us; speedup vs baseline: 1.4674x; 1.0279x over previous
//
#include <hip/hip_runtime.h>
#include <hip/hip_bf16.h>
#include <math.h>

#define F 128

typedef __attribute__((ext_vector_type(8))) short bf16x8;
typedef __attribute__((ext_vector_type(4))) float f32x4;

// ------- row-normalize: xn = x/max(||x||,eps) (fp32 + bf16 copies) ----------
__global__ void k_normalize(const float* __restrict__ x, float* __restrict__ xn,
                            __hip_bfloat16* __restrict__ xnb, int N) {
  int wid = (blockIdx.x * blockDim.x + threadIdx.x) >> 6;  // one wave per node
  int lane = threadIdx.x & 63;
  if (wid >= N) return;
  const float2* src = (const float2*)(x + (size_t)wid * F);
  float2 v = src[lane];
  float ss = v.x * v.x + v.y * v.y;
#pragma unroll
  for (int m = 32; m >= 1; m >>= 1) ss += __shfl_xor(ss, m);
  float inv = 1.0f / fmaxf(sqrtf(ss), 1e-12f);
  float2 o; o.x = v.x * inv; o.y = v.y * inv;
  ((float2*)(xn + (size_t)wid * F))[lane] = o;
  __hip_bfloat162 ob;
  ob.x = __float2bfloat16(o.x); ob.y = __float2bfloat16(o.y);
  ((__hip_bfloat162*)(xnb + (size_t)wid * F))[lane] = ob;
}

// ---------------- CSR build (XCD-sharded two-level) ----------------
// Shard s = blockIdx&7 ~ XCD id (dispatch round-robin heuristic; perf-only).
// cntR/cntC: [8][N] shard-private counters -> atomic lines stay XCD-local.
__global__ void k_rank(const int* __restrict__ row, const int* __restrict__ col,
                       int* __restrict__ cntR, int* __restrict__ cntC,
                       int* __restrict__ rankR, int N, int E) {
  int e = blockIdx.x * blockDim.x + threadIdx.x;
  if (e >= E) return;
  int s = blockIdx.x & 7;
  rankR[e] = atomicAdd(cntR + s * N + row[e], 1);
  atomicAdd(cntC + s * N + col[e], 1);
}

// tot[0..N) = col totals, tot[N..2N) = row totals (matches scan layout)
__global__ void k_tot(const int* __restrict__ cntR, const int* __restrict__ cntC,
                      int* __restrict__ tot, int N) {
  int i = blockIdx.x * 256 + threadIdx.x;
  if (i >= 2 * N) return;
  const int* src = (i < N) ? (cntC + i) : (cntR + (i - N));
  int ssum = 0;
#pragma unroll
  for (int s = 0; s < 8; ++s) ssum += src[s * N];
  tot[i] = ssum;
}

__global__ void k_scan1(const int* __restrict__ cnt, int* __restrict__ partial,
                        int* __restrict__ bsum, int M) {
  __shared__ int sm[256];
  int t = threadIdx.x;
  int i = blockIdx.x * 256 + t;
  int val = (i < M) ? cnt[i] : 0;
  sm[t] = val;
  __syncthreads();
  for (int off = 1; off < 256; off <<= 1) {
    int v = (t >= off) ? sm[t - off] : 0;
    __syncthreads();
    sm[t] += v;
    __syncthreads();
  }
  if (i < M) partial[i] = sm[t] - val;  // exclusive
  if (t == 255) bsum[blockIdx.x] = sm[255];
}

// looped single-block scan (handles nb > 256)
__global__ void k_scan2(const int* __restrict__ bsum, int* __restrict__ boffs, int nb) {
  __shared__ int sm[256];
  int t = threadIdx.x;
  int carry = 0;
  for (int base = 0; base < nb; base += 256) {
    int idx = base + t;
    int val = (idx < nb) ? bsum[idx] : 0;
    sm[t] = val;
    __syncthreads();
    for (int off = 1; off < 256; off <<= 1) {
      int v = (t >= off) ? sm[t - off] : 0;
      __syncthreads();
      sm[t] += v;
      __syncthreads();
    }
    if (idx < nb) boffs[idx] = sm[t] - val + carry;
    carry += sm[255];
    __syncthreads();
  }
}

__global__ void k_scan3(const int* __restrict__ partial, const int* __restrict__ boffs,
                        int* __restrict__ offs_c, int* __restrict__ offs_r,
                        int N, int E) {
  int i = blockIdx.x * 256 + threadIdx.x;
  if (i < 2 * N) {
    int v = partial[i] + boffs[i >> 8];
    if (i < N) offs_c[i] = v;
    else offs_r[i - N] = v - E;  // second half includes total E of first half
  }
  if (i == 0) { offs_c[N] = E; offs_r[N] = E; }
}

// base8[s][r] = offs_r[r] + sum_{s'<s} cntR[s'][r]
__global__ void k_base(const int* __restrict__ cntR, const int* __restrict__ offs_r,
                       int* __restrict__ base8, int N) {
  int r = blockIdx.x * 256 + threadIdx.x;
  if (r >= N) return;
  int run = offs_r[r];
#pragma unroll
  for (int s = 0; s < 8; ++s) { base8[s * N + r] = run; run += cntR[s * N + r]; }
}

// atomic-free row placement (grid/block must match k_rank so shard matches)
__global__ void k_place_row(const int* __restrict__ row, const int* __restrict__ rankR,
                            const int* __restrict__ base8, int* __restrict__ perm_r,
                            int N, int E) {
  int e = blockIdx.x * blockDim.x + threadIdx.x;
  if (e >= E) return;
  int s = blockIdx.x & 7;
  perm_r[base8[s * N + row[e]] + rankR[e]] = e;
}

// Fill col lists iterating in row-CSR order -> each col list ~row-ascending
// (L2 locality for agg). Emits colof_r and pstat[pc] = (row, rowCSR-slot).
__global__ void k_scatter_col(const int* __restrict__ perm_r, const int* __restrict__ row,
                              const int* __restrict__ col, const int* __restrict__ offs_c,
                              int* __restrict__ cur_c, int* __restrict__ colof_r,
                              int2* __restrict__ pstat, int E) {
  int rp = blockIdx.x * blockDim.x + threadIdx.x;
  if (rp >= E) return;
  int e = perm_r[rp];
  int c = col[e];
  colof_r[rp] = c;
  int pos = offs_c[c] + atomicAdd(cur_c + c, 1);
  int2 rec; rec.x = row[e]; rec.y = rp;
  pstat[pos] = rec;
}

// ------- fused per-row sims + weights, MFMA edition. One wave per row. ------
__global__ __launch_bounds__(256) void k_simw(
    const float* __restrict__ xn, const __hip_bfloat16* __restrict__ xnb,
    const int* __restrict__ colof_r, const int* __restrict__ offs_r,
    float* __restrict__ adjr, float* __restrict__ wgr, float* __restrict__ colw,
    const float* __restrict__ gate, int layer, int N) {
  int w = threadIdx.x >> 6;   // wave 0..3, one row each
  int l = threadIdx.x & 63;
  int r = blockIdx.x * 4 + w;
  __shared__ float sims[4][320];
  __shared__ int scol[4][320];
  if (r >= N) return;
  int p0 = offs_r[r], p1 = offs_r[r + 1];
  int ne = p1 - p0;                     // ~17 (Poisson(16) + self loop), <320
  int quad = l >> 4;
  int m = l & 15;
  int qoff = quad * 8;
  const __hip_bfloat16* xr = xnb + (size_t)r * F;
  bf16x8 b0 = *(const bf16x8*)(xr + 0 * 32 + qoff);   // 16-lane broadcast loads
  bf16x8 b1 = *(const bf16x8*)(xr + 1 * 32 + qoff);
  bf16x8 b2 = *(const bf16x8*)(xr + 2 * 32 + qoff);
  bf16x8 b3 = *(const bf16x8*)(xr + 3 * 32 + qoff);
  for (int tb = 0; tb < ne; tb += 16) {
    int ii = tb + m; if (ii > ne - 1) ii = ne - 1;     // clamp (extra rows ignored)
    int cm = colof_r[p0 + ii];
    if (quad == 0 && tb + m < ne) scol[w][tb + m] = cm;
    const __hip_bfloat16* xc = xnb + (size_t)cm * F;
    bf16x8 a0 = *(const bf16x8*)(xc + 0 * 32 + qoff);  // 4 independent 16B gathers
    bf16x8 a1 = *(const bf16x8*)(xc + 1 * 32 + qoff);
    bf16x8 a2 = *(const bf16x8*)(xc + 2 * 32 + qoff);
    bf16x8 a3 = *(const bf16x8*)(xc + 3 * 32 + qoff);
    f32x4 acc = {0.f, 0.f, 0.f, 0.f};
    acc = __builtin_amdgcn_mfma_f32_16x16x32_bf16(a0, b0, acc, 0, 0, 0);
    acc = __builtin_amdgcn_mfma_f32_16x16x32_bf16(a1, b1, acc, 0, 0, 0);
    acc = __builtin_amdgcn_mfma_f32_16x16x32_bf16(a2, b2, acc, 0, 0, 0);
    acc = __builtin_amdgcn_mfma_f32_16x16x32_bf16(a3, b3, acc, 0, 0, 0);
    if (m == 0) {                       // lanes 0,16,32,48 hold rows quad*4+reg
#pragma unroll
      for (int reg = 0; reg < 4; ++reg) {
        int i = tb + quad * 4 + reg;
        if (i < ne) sims[w][i] = acc[reg];
      }
    }
  }
  // pass 2: guard-band fp32 recompute + threshold + rowsum/deg (one wave)
  float vsum = 0.f; int cn = 0;
  for (int base = 0; base < ne; base += 64) {
    int i = base + l;
    bool have = i < ne;
    float s = have ? sims[w][i] : 0.f;
    int c = have ? scol[w][i] : r;
    bool self = (c == r);
    bool flag = have && !self && fabsf(s - 0.1f) < 0.03f;
    unsigned long long mask = __ballot(flag);
    while (mask) {                      // ~1 flagged edge/row: wave-coop fp32 dot
      int src = __ffsll(mask) - 1;
      mask &= mask - 1;
      int cc = __shfl(c, src);
      float2 ar = ((const float2*)(xn + (size_t)r * F))[l];
      float2 bc = ((const float2*)(xn + (size_t)cc * F))[l];
      float d = ar.x * bc.x + ar.y * bc.y;
#pragma unroll
      for (int mm = 32; mm >= 1; mm >>= 1) d += __shfl_xor(d, mm);
      if (l == src) s = d;
    }
    if (self || s < 0.1f) s = 0.f;
    if (have) sims[w][i] = s;
    vsum += s;
    cn += (s > 0.f) ? 1 : 0;
  }
#pragma unroll
  for (int mm = 32; mm >= 1; mm >>= 1) {
    vsum += __shfl_xor(vsum, mm);
    cn += __shfl_xor(cn, mm);
  }
  float rs = vsum;
  float lam = 1.0f / (float)(cn + 1);
  float gg = (layer > 0) ? gate[layer - 1] : 0.f;
  for (int i = l; i < ne; i += 64) {
    int c = scol[w][i];
    float s = sims[w][i];
    float sn = (rs > 0.f) ? s / rs : 0.f;
    float wv = (c == r) ? lam : sn;
    wv = expf(wv);                      // thresholded edges get exp(0)=1
    float wc;
    if (layer == 0) { adjr[p0 + i] = wv; wc = wv; }
    else { wc = gg * adjr[p0 + i] + (1.f - gg) * wv; }
    wgr[p0 + i] = wc;                   // sequential write
    atomicAdd(colw + c, wc);            // 200KB table, L2-resident
  }
}

// ------ GEMM: out_bf16[M,128] = A[M,128] @ W[128,128], register-tiled -------
__global__ __launch_bounds__(256) void k_gemm128(const float* __restrict__ A,
                                                 const float* __restrict__ W,
                                                 __hip_bfloat16* __restrict__ out, int M) {
  __shared__ float As[128][36];
  int t = threadIdx.x;
  int n0 = blockIdx.x * 32;
  for (int i = t; i < 32 * 128; i += 256) {
    int nn = i >> 7, kk = i & 127;
    int gn = n0 + nn;
    As[kk][nn] = (gn < M) ? A[(size_t)gn * 128 + kk] : 0.f;
  }
  __syncthreads();
  int nb = (t >> 6) * 8;
  int j2 = (t & 63) * 2;
  float acc[8][2] = {};
  for (int k = 0; k < 128; ++k) {
    float4 a01 = *(const float4*)&As[k][nb];
    float4 a23 = *(const float4*)&As[k][nb + 4];
    float2 wv = *(const float2*)&W[k * 128 + j2];
    acc[0][0] += a01.x * wv.x; acc[0][1] += a01.x * wv.y;
    acc[1][0] += a01.y * wv.x; acc[1][1] += a01.y * wv.y;
    acc[2][0] += a01.z * wv.x; acc[2][1] += a01.z * wv.y;
    acc[3][0] += a01.w * wv.x; acc[3][1] += a01.w * wv.y;
    acc[4][0] += a23.x * wv.x; acc[4][1] += a23.x * wv.y;
    acc[5][0] += a23.y * wv.x; acc[5][1] += a23.y * wv.y;
    acc[6][0] += a23.z * wv.x; acc[6][1] += a23.z * wv.y;
    acc[7][0] += a23.w * wv.x; acc[7][1] += a23.w * wv.y;
  }
  __hip_bfloat162* o2 = (__hip_bfloat162*)out;
#pragma unroll
  for (int i = 0; i < 8; ++i) {
    int gn = n0 + nb + i;
    if (gn < M) {
      __hip_bfloat162 o;
      o.x = __float2bfloat16(acc[i][0]); o.y = __float2bfloat16(acc[i][1]);
      o2[(size_t)gn * 64 + (j2 >> 1)] = o;
    }
  }
}

// ------ GEMM: out_bf16[M,40] = A[M,128] @ W[128,40], register-tiled ---------
__global__ __launch_bounds__(320) void k_gemm40(const float* __restrict__ A,
                                                const float* __restrict__ W,
                                                __hip_bfloat16* __restrict__ out,
                                                int M, int C) {
  __shared__ float As[128][68];
  int t = threadIdx.x;
  int n0 = blockIdx.x * 64;
  for (int i = t; i < 64 * 128; i += 320) {
    int nn = i >> 7, kk = i & 127;
    int gn = n0 + nn;
    As[kk][nn] = (gn < M) ? A[(size_t)gn * 128 + kk] : 0.f;
  }
  __syncthreads();
  int gq = t / 40;
  int jc = t - gq * 40;
  int nb = gq * 8;
  float acc[8] = {};
  for (int k = 0; k < 128; ++k) {
    float4 a01 = *(const float4*)&As[k][nb];
    float4 a23 = *(const float4*)&As[k][nb + 4];
    float wv = W[k * C + jc];
    acc[0] += a01.x * wv; acc[1] += a01.y * wv; acc[2] += a01.z * wv; acc[3] += a01.w * wv;
    acc[4] += a23.x * wv; acc[5] += a23.y * wv; acc[6] += a23.z * wv; acc[7] += a23.w * wv;
  }
#pragma unroll
  for (int i = 0; i < 8; ++i) {
    int gn = n0 + nb + i;
    if (gn < M) out[(size_t)gn * C + jc] = __float2bfloat16(acc[i]);
  }
}

// ---- fused: per-edge norm + aggregation + bias + relu + row-normalize ------
__global__ __launch_bounds__(256) void k_agg_norm(
    const __hip_bfloat162* __restrict__ hWb, const int2* __restrict__ pstat,
    const float* __restrict__ wgr, const float* __restrict__ colw,
    const int* __restrict__ offs_c, const float* __restrict__ bias,
    float* __restrict__ out, float* __restrict__ xn, __hip_bfloat16* __restrict__ xnb,
    int N) {
  int w = threadIdx.x >> 6;
  int t = threadIdx.x & 63;
  int c = blockIdx.x * 4 + w;
  if (c >= N) return;
  int p0 = offs_c[c], p1 = offs_c[c + 1];
  float dcv = colw[c];
  float dic = (dcv > 0.f) ? rsqrtf(dcv) : 0.f;
  float acc0 = bias[2 * t], acc1 = bias[2 * t + 1];
  int p = p0;
  for (; p + 4 <= p1; p += 4) {   // 4 row-gathers in flight
    int2 s0 = pstat[p], s1 = pstat[p + 1], s2 = pstat[p + 2], s3 = pstat[p + 3];
    float w0 = wgr[s0.y], w1 = wgr[s1.y], w2 = wgr[s2.y], w3 = wgr[s3.y];
    float d0 = colw[s0.x], d1 = colw[s1.x], d2 = colw[s2.x], d3 = colw[s3.x];
    __hip_bfloat162 h0 = hWb[(size_t)s0.x * 64 + t];
    __hip_bfloat162 h1 = hWb[(size_t)s1.x * 64 + t];
    __hip_bfloat162 h2 = hWb[(size_t)s2.x * 64 + t];
    __hip_bfloat162 h3 = hWb[(size_t)s3.x * 64 + t];
    float n0 = ((d0 > 0.f) ? rsqrtf(d0) : 0.f) * w0 * dic;
    float n1 = ((d1 > 0.f) ? rsqrtf(d1) : 0.f) * w1 * dic;
    float n2 = ((d2 > 0.f) ? rsqrtf(d2) : 0.f) * w2 * dic;
    float n3 = ((d3 > 0.f) ? rsqrtf(d3) : 0.f) * w3 * dic;
    acc0 += n0 * __bfloat162float(h0.x) + n1 * __bfloat162float(h1.x)
          + n2 * __bfloat162float(h2.x) + n3 * __bfloat162float(h3.x);
    acc1 += n0 * __bfloat162float(h0.y) + n1 * __bfloat162float(h1.y)
          + n2 * __bfloat162float(h2.y) + n3 * __bfloat162float(h3.y);
  }
  for (; p < p1; ++p) {
    int2 s0 = pstat[p];
    float w0 = wgr[s0.y];
    float d0 = colw[s0.x];
    __hip_bfloat162 h0 = hWb[(size_t)s0.x * 64 + t];
    float n0 = ((d0 > 0.f) ? rsqrtf(d0) : 0.f) * w0 * dic;
    acc0 += n0 * __bfloat162float(h0.x);
    acc1 += n0 * __bfloat162float(h0.y);
  }
  acc0 = fmaxf(acc0, 0.f); acc1 = fmaxf(acc1, 0.f);
  float2 o; o.x = acc0; o.y = acc1;
  ((float2*)out)[(size_t)c * 64 + t] = o;
  float ss = acc0 * acc0 + acc1 * acc1;
#pragma unroll
  for (int m = 32; m >= 1; m >>= 1) ss += __shfl_xor(ss, m);
  float inv = 1.0f / fmaxf(sqrtf(ss), 1e-12f);
  float2 on; on.x = acc0 * inv; on.y = acc1 * inv;
  ((float2*)xn)[(size_t)c * 64 + t] = on;
  __hip_bfloat162 ob;
  ob.x = __float2bfloat16(on.x); ob.y = __float2bfloat16(on.y);
  ((__hip_bfloat162*)xnb)[(size_t)c * 64 + t] = ob;
}

// ------- fused final aggregation + bias + log_softmax; wave per node --------
__global__ __launch_bounds__(256) void k_agg40_lsm(
    const __hip_bfloat16* __restrict__ hW, const int2* __restrict__ pstat,
    const float* __restrict__ wgr, const float* __restrict__ colw,
    const int* __restrict__ offs_c, const float* __restrict__ bias,
    float* __restrict__ out, int C, int N) {
  int w = threadIdx.x >> 6;
  int j = threadIdx.x & 63;
  int c = blockIdx.x * 4 + w;
  if (c >= N) return;
  int p0 = offs_c[c], p1 = offs_c[c + 1];
  float dcv = colw[c];
  float dic = (dcv > 0.f) ? rsqrtf(dcv) : 0.f;
  bool act = j < C;
  int jj = act ? j : 0;
  float acc = act ? bias[jj] : 0.f;
  int p = p0;
  for (; p + 4 <= p1; p += 4) {
    int2 s0 = pstat[p], s1 = pstat[p + 1], s2 = pstat[p + 2], s3 = pstat[p + 3];
    float w0 = wgr[s0.y], w1 = wgr[s1.y], w2 = wgr[s2.y], w3 = wgr[s3.y];
    float d0 = colw[s0.x], d1 = colw[s1.x], d2 = colw[s2.x], d3 = colw[s3.x];
    float h0 = __bfloat162float(hW[(size_t)s0.x * C + jj]);
    float h1 = __bfloat162float(hW[(size_t)s1.x * C + jj]);
    float h2 = __bfloat162float(hW[(size_t)s2.x * C + jj]);
    float h3 = __bfloat162float(hW[(size_t)s3.x * C + jj]);
    acc += ((d0 > 0.f) ? rsqrtf(d0) : 0.f) * w0 * dic * h0
         + ((d1 > 0.f) ? rsqrtf(d1) : 0.f) * w1 * dic * h1
         + ((d2 > 0.f) ? rsqrtf(d2) : 0.f) * w2 * dic * h2
         + ((d3 > 0.f) ? rsqrtf(d3) : 0.f) * w3 * dic * h3;
  }
  for (; p < p1; ++p) {
    int2 s0 = pstat[p];
    float w0 = wgr[s0.y];
    float d0 = colw[s0.x];
    acc += ((d0 > 0.f) ? rsqrtf(d0) : 0.f) * w0 * dic
         * __bfloat162float(hW[(size_t)s0.x * C + jj]);
  }
  if (!act) acc = 0.f;
  float v = act ? acc : -3.0e38f;
#pragma unroll
  for (int m = 32; m >= 1; m >>= 1) v = fmaxf(v, __shfl_xor(v, m));
  float ex = act ? expf(acc - v) : 0.f;
#pragma unroll
  for (int m = 32; m >= 1; m >>= 1) ex += __shfl_xor(ex, m);
  if (act) out[(size_t)c * C + j] = acc - v - logf(ex);
}

extern "C" void kernel_launch(void* const* d_in, const int* in_sizes, int n_in,
                              void* d_out, int out_size, void* d_ws, size_t ws_size,
                              hipStream_t stream) {
  const float* x    = (const float*)d_in[0];
  const float* gate = (const float*)d_in[1];
  const float* W0   = (const float*)d_in[2];
  const float* b0   = (const float*)d_in[3];
  const float* W1   = (const float*)d_in[4];
  const float* b1   = (const float*)d_in[5];
  const float* W2   = (const float*)d_in[6];
  const float* b2   = (const float*)d_in[7];
  const int* eidx   = (const int*)d_in[8];
  int N = in_sizes[0] / 128;
  int E = in_sizes[8] / 2;
  int C = in_sizes[7];  // 40
  const int* row = eidx;
  const int* col = eidx + E;

  char* ws = (char*)d_ws;
  size_t off = 0;
  auto alloc = [&](size_t bytes) {
    char* p = ws + off;
    off += (bytes + 255) & ~(size_t)255;
    return p;
  };
  float* xn     = (float*)alloc((size_t)N * 128 * 4);
  __hip_bfloat16* xnb = (__hip_bfloat16*)alloc((size_t)N * 128 * 2);
  float* bufC   = (float*)alloc((size_t)N * 128 * 4);
  __hip_bfloat16* hWb = (__hip_bfloat16*)alloc((size_t)N * 128 * 2);
  float* adjr   = (float*)alloc((size_t)E * 4);    // layer-0 weights, row-CSR order
  float* wgr    = (float*)alloc((size_t)E * 4);    // gated weight, row-CSR order
  int*   perm_r = (int*)alloc((size_t)E * 4);
  int2*  pstat  = (int2*)alloc((size_t)E * 8);     // (row, rowCSR-slot) per col slot
  int*   colof_r= (int*)alloc((size_t)E * 4);      // also doubles as rankR (lifetimes disjoint)
  int*   rankR  = colof_r;
  int*   offs_c = (int*)alloc((size_t)(N + 1) * 4);
  int*   offs_r = (int*)alloc((size_t)(N + 1) * 4);
  int*   cntR   = (int*)alloc((size_t)N * 4 * 8);  // [8][N] sharded row counts
  int*   cntC   = (int*)alloc((size_t)N * 4 * 8);  // [8][N] sharded col counts; [0][:] reused as cursor
  int*   base8  = (int*)alloc((size_t)N * 4 * 8);
  int*   tot    = (int*)alloc((size_t)N * 4 * 2);  // 2N totals (col then row)
  int*   partial= (int*)alloc((size_t)N * 4 * 2);
  int*   bsum   = (int*)alloc(2048);
  int*   boffs  = (int*)alloc(2048);
  float* colw   = (float*)alloc((size_t)N * 4);

  int eb  = (E + 255) / 256;
  int nb1 = (N + 255) / 256;
  int nb2 = (2 * N + 255) / 256;
  int nw4 = (N + 3) / 4;

  // ---- CSR build: sharded rank -> totals -> scan -> base -> place ----
  hipMemsetAsync(cntR, 0, (size_t)N * 4 * 16, stream);  // cntR + cntC
  k_rank<<<eb, 256, 0, stream>>>(row, col, cntR, cntC, rankR, N, E);
  k_tot<<<nb2, 256, 0, stream>>>(cntR, cntC, tot, N);
  k_scan1<<<nb2, 256, 0, stream>>>(tot, partial, bsum, 2 * N);
  k_scan2<<<1, 256, 0, stream>>>(bsum, boffs, nb2);
  k_scan3<<<nb2, 256, 0, stream>>>(partial, boffs, offs_c, offs_r, N, E);
  k_base<<<nb1, 256, 0, stream>>>(cntR, offs_r, base8, N);
  k_place_row<<<eb, 256, 0, stream>>>(row, rankR, base8, perm_r, N, E);
  hipMemsetAsync(cntC, 0, (size_t)N * 4, stream);       // reuse as col cursor
  k_scatter_col<<<eb, 256, 0, stream>>>(perm_r, row, col, offs_c, cntC,
                                        colof_r, pstat, E);

  for (int layer = 0; layer < 3; ++layer) {
    hipMemsetAsync(colw, 0, (size_t)N * 4, stream);
    if (layer == 0) k_normalize<<<(N + 3) / 4, 256, 0, stream>>>(x, xn, xnb, N);
    k_simw<<<nw4, 256, 0, stream>>>(xn, xnb, colof_r, offs_r, adjr, wgr, colw,
                                    gate, layer, N);
    const float* hin = (layer == 0) ? x : bufC;
    if (layer < 2) {
      const float* W = (layer == 0) ? W0 : W1;
      const float* b = (layer == 0) ? b0 : b1;
      k_gemm128<<<(N + 31) / 32, 256, 0, stream>>>(hin, W, hWb, N);
      k_agg_norm<<<nw4, 256, 0, stream>>>((const __hip_bfloat162*)hWb, pstat, wgr, colw,
                                          offs_c, b, bufC, xn, xnb, N);
    } else {
      k_gemm40<<<(N + 63) / 64, 320, 0, stream>>>(hin, W2, hWb, N, C);
      k_agg40_lsm<<<nw4, 256, 0, stream>>>(hWb, pstat, wgr, colw, offs_c, b2,
                                           (float*)d_out, C, N);
    }
  }
}

// Round 10
// 628.731 us; speedup vs baseline: 1.5894x; 1.0831x over previous
//
#include <hip/hip_runtime.h>
#include <hip/hip_bf16.h>
#include <math.h>

#define F 128

typedef __attribute__((ext_vector_type(8))) short bf16x8;
typedef __attribute__((ext_vector_type(4))) float f32x4;

// ------- row-normalize: xn = x/max(||x||,eps) (fp32 + bf16 copies) ----------
__global__ void k_normalize(const float* __restrict__ x, float* __restrict__ xn,
                            __hip_bfloat16* __restrict__ xnb, int N) {
  int wid = (blockIdx.x * blockDim.x + threadIdx.x) >> 6;  // one wave per node
  int lane = threadIdx.x & 63;
  if (wid >= N) return;
  const float2* src = (const float2*)(x + (size_t)wid * F);
  float2 v = src[lane];
  float ss = v.x * v.x + v.y * v.y;
#pragma unroll
  for (int m = 32; m >= 1; m >>= 1) ss += __shfl_xor(ss, m);
  float inv = 1.0f / fmaxf(sqrtf(ss), 1e-12f);
  float2 o; o.x = v.x * inv; o.y = v.y * inv;
  ((float2*)(xn + (size_t)wid * F))[lane] = o;
  __hip_bfloat162 ob;
  ob.x = __float2bfloat16(o.x); ob.y = __float2bfloat16(o.y);
  ((__hip_bfloat162*)(xnb + (size_t)wid * F))[lane] = ob;
}

// ============ CSR build: atomic-free two-level LDS counting sort ============
// bucket = node >> 8 (<=256 buckets for N<=65536); 2048-edge chunks.
// ghist layout [256][nchunk] bucket-major -> its exclusive scan directly gives
// per-(bucket,chunk) write bases AND bucket starts.

// per-chunk LDS histogram; optionally key via perm; optionally emit key stream
__global__ __launch_bounds__(256) void k_lhist(
    const int* __restrict__ keys, const int* __restrict__ perm,
    int* __restrict__ ghist, int* __restrict__ keyout, int nchunk, int E) {
  __shared__ int lh[256];
  int t = threadIdx.x, chunk = blockIdx.x;
  lh[t] = 0;
  __syncthreads();
  int base = chunk * 2048;
#pragma unroll
  for (int k = 0; k < 8; ++k) {
    int i = base + k * 256 + t;
    if (i < E) {
      int key = perm ? keys[perm[i]] : keys[i];
      if (keyout) keyout[i] = key;
      atomicAdd(&lh[key >> 8], 1);
    }
  }
  __syncthreads();
  ghist[t * nchunk + chunk] = lh[t];
}

__global__ void k_scan1(const int* __restrict__ cnt, int* __restrict__ partial,
                        int* __restrict__ bsum, int M) {
  __shared__ int sm[256];
  int t = threadIdx.x;
  int i = blockIdx.x * 256 + t;
  int val = (i < M) ? cnt[i] : 0;
  sm[t] = val;
  __syncthreads();
  for (int off = 1; off < 256; off <<= 1) {
    int v = (t >= off) ? sm[t - off] : 0;
    __syncthreads();
    sm[t] += v;
    __syncthreads();
  }
  if (i < M) partial[i] = sm[t] - val;  // exclusive
  if (t == 255) bsum[blockIdx.x] = sm[255];
}

// looped single-block scan (handles nb > 256)
__global__ void k_scan2(const int* __restrict__ bsum, int* __restrict__ boffs, int nb) {
  __shared__ int sm[256];
  int t = threadIdx.x;
  int carry = 0;
  for (int base = 0; base < nb; base += 256) {
    int idx = base + t;
    int val = (idx < nb) ? bsum[idx] : 0;
    sm[t] = val;
    __syncthreads();
    for (int off = 1; off < 256; off <<= 1) {
      int v = (t >= off) ? sm[t - off] : 0;
      __syncthreads();
      sm[t] += v;
      __syncthreads();
    }
    if (idx < nb) boffs[idx] = sm[t] - val + carry;
    carry += sm[255];
    __syncthreads();
  }
}

// scatter into bucket-partitioned order via LDS cursors (no global atomics).
// payload packs (index<<8 | low-8-bits-of-key) so finals never re-gather keys.
__global__ __launch_bounds__(256) void k_bucketize(
    const int* __restrict__ keys, const int* __restrict__ perm,
    const int* __restrict__ partial, const int* __restrict__ boffs,
    int* __restrict__ ebuck, int nchunk, int E) {
  __shared__ int lcur[256];
  int t = threadIdx.x, chunk = blockIdx.x;
  int idx = t * nchunk + chunk;
  lcur[t] = partial[idx] + boffs[idx >> 8];
  __syncthreads();
  int base = chunk * 2048;
#pragma unroll
  for (int k = 0; k < 8; ++k) {
    int i = base + k * 256 + t;
    if (i < E) {
      int key = perm ? keys[perm[i]] : keys[i];
      int pos = atomicAdd(&lcur[key >> 8], 1);
      ebuck[pos] = (i << 8) | (key & 255);
    }
  }
}

// per-bucket finalize (row): LDS hist + LDS scan -> offs_r and perm_r
__global__ __launch_bounds__(256) void k_final_row(
    const int* __restrict__ ebuck, const int* __restrict__ partial,
    const int* __restrict__ boffs, int* __restrict__ perm_r,
    int* __restrict__ offs_r, int nchunk, int N, int E) {
  __shared__ int lh[256], sm[256], lscan[256];
  int t = threadIdx.x, b = blockIdx.x;
  int i0 = b * nchunk;
  int start = partial[i0] + boffs[i0 >> 8];
  int i1 = i0 + nchunk;
  int end = (b < 255) ? partial[i1] + boffs[i1 >> 8] : E;
  lh[t] = 0;
  __syncthreads();
  for (int p = start + t; p < end; p += 256) atomicAdd(&lh[ebuck[p] & 255], 1);
  __syncthreads();
  int val = lh[t];
  sm[t] = val;
  __syncthreads();
  for (int off = 1; off < 256; off <<= 1) {
    int v = (t >= off) ? sm[t - off] : 0;
    __syncthreads();
    sm[t] += v;
    __syncthreads();
  }
  lscan[t] = sm[t] - val;
  int node = b * 256 + t;
  if (node < N) offs_r[node] = start + lscan[t];
  if (b == 0 && t == 0) offs_r[N] = E;
  lh[t] = 0;
  __syncthreads();
  for (int p = start + t; p < end; p += 256) {
    int v = ebuck[p];
    int low = v & 255;
    int rk = atomicAdd(&lh[low], 1);
    perm_r[start + lscan[low] + rk] = v >> 8;
  }
}

// per-bucket finalize (col): also emits pstat[pc] = (row, rowCSR-slot)
__global__ __launch_bounds__(256) void k_final_col(
    const int* __restrict__ ebuck, const int* __restrict__ perm_r,
    const int* __restrict__ row, const int* __restrict__ partial,
    const int* __restrict__ boffs, int2* __restrict__ pstat,
    int* __restrict__ offs_c, int nchunk, int N, int E) {
  __shared__ int lh[256], sm[256], lscan[256];
  int t = threadIdx.x, b = blockIdx.x;
  int i0 = b * nchunk;
  int start = partial[i0] + boffs[i0 >> 8];
  int i1 = i0 + nchunk;
  int end = (b < 255) ? partial[i1] + boffs[i1 >> 8] : E;
  lh[t] = 0;
  __syncthreads();
  for (int p = start + t; p < end; p += 256) atomicAdd(&lh[ebuck[p] & 255], 1);
  __syncthreads();
  int val = lh[t];
  sm[t] = val;
  __syncthreads();
  for (int off = 1; off < 256; off <<= 1) {
    int v = (t >= off) ? sm[t - off] : 0;
    __syncthreads();
    sm[t] += v;
    __syncthreads();
  }
  lscan[t] = sm[t] - val;
  int node = b * 256 + t;
  if (node < N) offs_c[node] = start + lscan[t];
  if (b == 0 && t == 0) offs_c[N] = E;
  lh[t] = 0;
  __syncthreads();
  for (int p = start + t; p < end; p += 256) {
    int v = ebuck[p];
    int low = v & 255;
    int rp = v >> 8;                      // rowCSR slot (~ascending -> L2 locality)
    int e = perm_r[rp];
    int rk = atomicAdd(&lh[low], 1);
    int2 rec; rec.x = row[e]; rec.y = rp;
    pstat[start + lscan[low] + rk] = rec;
  }
}

// ------- fused per-row sims + weights, MFMA edition. One wave per row. ------
__global__ __launch_bounds__(256) void k_simw(
    const float* __restrict__ xn, const __hip_bfloat16* __restrict__ xnb,
    const int* __restrict__ colof_r, const int* __restrict__ offs_r,
    float* __restrict__ adjr, float* __restrict__ wgr, float* __restrict__ colw,
    const float* __restrict__ gate, int layer, int N) {
  int w = threadIdx.x >> 6;   // wave 0..3, one row each
  int l = threadIdx.x & 63;
  int r = blockIdx.x * 4 + w;
  __shared__ float sims[4][320];
  __shared__ int scol[4][320];
  if (r >= N) return;
  int p0 = offs_r[r], p1 = offs_r[r + 1];
  int ne = p1 - p0;                     // ~17 (Poisson(16) + self loop), <320
  int quad = l >> 4;
  int m = l & 15;
  int qoff = quad * 8;
  const __hip_bfloat16* xr = xnb + (size_t)r * F;
  bf16x8 b0 = *(const bf16x8*)(xr + 0 * 32 + qoff);   // 16-lane broadcast loads
  bf16x8 b1 = *(const bf16x8*)(xr + 1 * 32 + qoff);
  bf16x8 b2 = *(const bf16x8*)(xr + 2 * 32 + qoff);
  bf16x8 b3 = *(const bf16x8*)(xr + 3 * 32 + qoff);
  for (int tb = 0; tb < ne; tb += 16) {
    int ii = tb + m; if (ii > ne - 1) ii = ne - 1;     // clamp (extra rows ignored)
    int cm = colof_r[p0 + ii];
    if (quad == 0 && tb + m < ne) scol[w][tb + m] = cm;
    const __hip_bfloat16* xc = xnb + (size_t)cm * F;
    bf16x8 a0 = *(const bf16x8*)(xc + 0 * 32 + qoff);  // 4 independent 16B gathers
    bf16x8 a1 = *(const bf16x8*)(xc + 1 * 32 + qoff);
    bf16x8 a2 = *(const bf16x8*)(xc + 2 * 32 + qoff);
    bf16x8 a3 = *(const bf16x8*)(xc + 3 * 32 + qoff);
    f32x4 acc = {0.f, 0.f, 0.f, 0.f};
    acc = __builtin_amdgcn_mfma_f32_16x16x32_bf16(a0, b0, acc, 0, 0, 0);
    acc = __builtin_amdgcn_mfma_f32_16x16x32_bf16(a1, b1, acc, 0, 0, 0);
    acc = __builtin_amdgcn_mfma_f32_16x16x32_bf16(a2, b2, acc, 0, 0, 0);
    acc = __builtin_amdgcn_mfma_f32_16x16x32_bf16(a3, b3, acc, 0, 0, 0);
    if (m == 0) {                       // lanes 0,16,32,48 hold rows quad*4+reg
#pragma unroll
      for (int reg = 0; reg < 4; ++reg) {
        int i = tb + quad * 4 + reg;
        if (i < ne) sims[w][i] = acc[reg];
      }
    }
  }
  // pass 2: guard-band fp32 recompute + threshold + rowsum/deg (one wave)
  float vsum = 0.f; int cn = 0;
  for (int base = 0; base < ne; base += 64) {
    int i = base + l;
    bool have = i < ne;
    float s = have ? sims[w][i] : 0.f;
    int c = have ? scol[w][i] : r;
    bool self = (c == r);
    bool flag = have && !self && fabsf(s - 0.1f) < 0.03f;
    unsigned long long mask = __ballot(flag);
    while (mask) {                      // ~1 flagged edge/row: wave-coop fp32 dot
      int src = __ffsll(mask) - 1;
      mask &= mask - 1;
      int cc = __shfl(c, src);
      float2 ar = ((const float2*)(xn + (size_t)r * F))[l];
      float2 bc = ((const float2*)(xn + (size_t)cc * F))[l];
      float d = ar.x * bc.x + ar.y * bc.y;
#pragma unroll
      for (int mm = 32; mm >= 1; mm >>= 1) d += __shfl_xor(d, mm);
      if (l == src) s = d;
    }
    if (self || s < 0.1f) s = 0.f;
    if (have) sims[w][i] = s;
    vsum += s;
    cn += (s > 0.f) ? 1 : 0;
  }
#pragma unroll
  for (int mm = 32; mm >= 1; mm >>= 1) {
    vsum += __shfl_xor(vsum, mm);
    cn += __shfl_xor(cn, mm);
  }
  float rs = vsum;
  float lam = 1.0f / (float)(cn + 1);
  float gg = (layer > 0) ? gate[layer - 1] : 0.f;
  for (int i = l; i < ne; i += 64) {
    int c = scol[w][i];
    float s = sims[w][i];
    float sn = (rs > 0.f) ? s / rs : 0.f;
    float wv = (c == r) ? lam : sn;
    wv = expf(wv);                      // thresholded edges get exp(0)=1
    float wc;
    if (layer == 0) { adjr[p0 + i] = wv; wc = wv; }
    else { wc = gg * adjr[p0 + i] + (1.f - gg) * wv; }
    wgr[p0 + i] = wc;                   // sequential write
    atomicAdd(colw + c, wc);            // 200KB table, L2-resident
  }
}

// ------ GEMM: out_bf16[M,128] = A[M,128] @ W[128,128], register-tiled -------
__global__ __launch_bounds__(256) void k_gemm128(const float* __restrict__ A,
                                                 const float* __restrict__ W,
                                                 __hip_bfloat16* __restrict__ out, int M) {
  __shared__ float As[128][36];
  int t = threadIdx.x;
  int n0 = blockIdx.x * 32;
  for (int i = t; i < 32 * 128; i += 256) {
    int nn = i >> 7, kk = i & 127;
    int gn = n0 + nn;
    As[kk][nn] = (gn < M) ? A[(size_t)gn * 128 + kk] : 0.f;
  }
  __syncthreads();
  int nb = (t >> 6) * 8;
  int j2 = (t & 63) * 2;
  float acc[8][2] = {};
  for (int k = 0; k < 128; ++k) {
    float4 a01 = *(const float4*)&As[k][nb];
    float4 a23 = *(const float4*)&As[k][nb + 4];
    float2 wv = *(const float2*)&W[k * 128 + j2];
    acc[0][0] += a01.x * wv.x; acc[0][1] += a01.x * wv.y;
    acc[1][0] += a01.y * wv.x; acc[1][1] += a01.y * wv.y;
    acc[2][0] += a01.z * wv.x; acc[2][1] += a01.z * wv.y;
    acc[3][0] += a01.w * wv.x; acc[3][1] += a01.w * wv.y;
    acc[4][0] += a23.x * wv.x; acc[4][1] += a23.x * wv.y;
    acc[5][0] += a23.y * wv.x; acc[5][1] += a23.y * wv.y;
    acc[6][0] += a23.z * wv.x; acc[6][1] += a23.z * wv.y;
    acc[7][0] += a23.w * wv.x; acc[7][1] += a23.w * wv.y;
  }
  __hip_bfloat162* o2 = (__hip_bfloat162*)out;
#pragma unroll
  for (int i = 0; i < 8; ++i) {
    int gn = n0 + nb + i;
    if (gn < M) {
      __hip_bfloat162 o;
      o.x = __float2bfloat16(acc[i][0]); o.y = __float2bfloat16(acc[i][1]);
      o2[(size_t)gn * 64 + (j2 >> 1)] = o;
    }
  }
}

// ------ GEMM: out_bf16[M,40] = A[M,128] @ W[128,40], register-tiled ---------
__global__ __launch_bounds__(320) void k_gemm40(const float* __restrict__ A,
                                                const float* __restrict__ W,
                                                __hip_bfloat16* __restrict__ out,
                                                int M, int C) {
  __shared__ float As[128][68];
  int t = threadIdx.x;
  int n0 = blockIdx.x * 64;
  for (int i = t; i < 64 * 128; i += 320) {
    int nn = i >> 7, kk = i & 127;
    int gn = n0 + nn;
    As[kk][nn] = (gn < M) ? A[(size_t)gn * 128 + kk] : 0.f;
  }
  __syncthreads();
  int gq = t / 40;
  int jc = t - gq * 40;
  int nb = gq * 8;
  float acc[8] = {};
  for (int k = 0; k < 128; ++k) {
    float4 a01 = *(const float4*)&As[k][nb];
    float4 a23 = *(const float4*)&As[k][nb + 4];
    float wv = W[k * C + jc];
    acc[0] += a01.x * wv; acc[1] += a01.y * wv; acc[2] += a01.z * wv; acc[3] += a01.w * wv;
    acc[4] += a23.x * wv; acc[5] += a23.y * wv; acc[6] += a23.z * wv; acc[7] += a23.w * wv;
  }
#pragma unroll
  for (int i = 0; i < 8; ++i) {
    int gn = n0 + nb + i;
    if (gn < M) out[(size_t)gn * C + jc] = __float2bfloat16(acc[i]);
  }
}

// ---- fused: per-edge norm + aggregation + bias + relu + row-normalize ------
__global__ __launch_bounds__(256) void k_agg_norm(
    const __hip_bfloat162* __restrict__ hWb, const int2* __restrict__ pstat,
    const float* __restrict__ wgr, const float* __restrict__ colw,
    const int* __restrict__ offs_c, const float* __restrict__ bias,
    float* __restrict__ out, float* __restrict__ xn, __hip_bfloat16* __restrict__ xnb,
    int N) {
  int w = threadIdx.x >> 6;
  int t = threadIdx.x & 63;
  int c = blockIdx.x * 4 + w;
  if (c >= N) return;
  int p0 = offs_c[c], p1 = offs_c[c + 1];
  float dcv = colw[c];
  float dic = (dcv > 0.f) ? rsqrtf(dcv) : 0.f;
  float acc0 = bias[2 * t], acc1 = bias[2 * t + 1];
  int p = p0;
  for (; p + 4 <= p1; p += 4) {   // 4 row-gathers in flight
    int2 s0 = pstat[p], s1 = pstat[p + 1], s2 = pstat[p + 2], s3 = pstat[p + 3];
    float w0 = wgr[s0.y], w1 = wgr[s1.y], w2 = wgr[s2.y], w3 = wgr[s3.y];
    float d0 = colw[s0.x], d1 = colw[s1.x], d2 = colw[s2.x], d3 = colw[s3.x];
    __hip_bfloat162 h0 = hWb[(size_t)s0.x * 64 + t];
    __hip_bfloat162 h1 = hWb[(size_t)s1.x * 64 + t];
    __hip_bfloat162 h2 = hWb[(size_t)s2.x * 64 + t];
    __hip_bfloat162 h3 = hWb[(size_t)s3.x * 64 + t];
    float n0 = ((d0 > 0.f) ? rsqrtf(d0) : 0.f) * w0 * dic;
    float n1 = ((d1 > 0.f) ? rsqrtf(d1) : 0.f) * w1 * dic;
    float n2 = ((d2 > 0.f) ? rsqrtf(d2) : 0.f) * w2 * dic;
    float n3 = ((d3 > 0.f) ? rsqrtf(d3) : 0.f) * w3 * dic;
    acc0 += n0 * __bfloat162float(h0.x) + n1 * __bfloat162float(h1.x)
          + n2 * __bfloat162float(h2.x) + n3 * __bfloat162float(h3.x);
    acc1 += n0 * __bfloat162float(h0.y) + n1 * __bfloat162float(h1.y)
          + n2 * __bfloat162float(h2.y) + n3 * __bfloat162float(h3.y);
  }
  for (; p < p1; ++p) {
    int2 s0 = pstat[p];
    float w0 = wgr[s0.y];
    float d0 = colw[s0.x];
    __hip_bfloat162 h0 = hWb[(size_t)s0.x * 64 + t];
    float n0 = ((d0 > 0.f) ? rsqrtf(d0) : 0.f) * w0 * dic;
    acc0 += n0 * __bfloat162float(h0.x);
    acc1 += n0 * __bfloat162float(h0.y);
  }
  acc0 = fmaxf(acc0, 0.f); acc1 = fmaxf(acc1, 0.f);
  float2 o; o.x = acc0; o.y = acc1;
  ((float2*)out)[(size_t)c * 64 + t] = o;
  float ss = acc0 * acc0 + acc1 * acc1;
#pragma unroll
  for (int m = 32; m >= 1; m >>= 1) ss += __shfl_xor(ss, m);
  float inv = 1.0f / fmaxf(sqrtf(ss), 1e-12f);
  float2 on; on.x = acc0 * inv; on.y = acc1 * inv;
  ((float2*)xn)[(size_t)c * 64 + t] = on;
  __hip_bfloat162 ob;
  ob.x = __float2bfloat16(on.x); ob.y = __float2bfloat16(on.y);
  ((__hip_bfloat162*)xnb)[(size_t)c * 64 + t] = ob;
}

// ------- fused final aggregation + bias + log_softmax; wave per node --------
__global__ __launch_bounds__(256) void k_agg40_lsm(
    const __hip_bfloat16* __restrict__ hW, const int2* __restrict__ pstat,
    const float* __restrict__ wgr, const float* __restrict__ colw,
    const int* __restrict__ offs_c, const float* __restrict__ bias,
    float* __restrict__ out, int C, int N) {
  int w = threadIdx.x >> 6;
  int j = threadIdx.x & 63;
  int c = blockIdx.x * 4 + w;
  if (c >= N) return;
  int p0 = offs_c[c], p1 = offs_c[c + 1];
  float dcv = colw[c];
  float dic = (dcv > 0.f) ? rsqrtf(dcv) : 0.f;
  bool act = j < C;
  int jj = act ? j : 0;
  float acc = act ? bias[jj] : 0.f;
  int p = p0;
  for (; p + 4 <= p1; p += 4) {
    int2 s0 = pstat[p], s1 = pstat[p + 1], s2 = pstat[p + 2], s3 = pstat[p + 3];
    float w0 = wgr[s0.y], w1 = wgr[s1.y], w2 = wgr[s2.y], w3 = wgr[s3.y];
    float d0 = colw[s0.x], d1 = colw[s1.x], d2 = colw[s2.x], d3 = colw[s3.x];
    float h0 = __bfloat162float(hW[(size_t)s0.x * C + jj]);
    float h1 = __bfloat162float(hW[(size_t)s1.x * C + jj]);
    float h2 = __bfloat162float(hW[(size_t)s2.x * C + jj]);
    float h3 = __bfloat162float(hW[(size_t)s3.x * C + jj]);
    acc += ((d0 > 0.f) ? rsqrtf(d0) : 0.f) * w0 * dic * h0
         + ((d1 > 0.f) ? rsqrtf(d1) : 0.f) * w1 * dic * h1
         + ((d2 > 0.f) ? rsqrtf(d2) : 0.f) * w2 * dic * h2
         + ((d3 > 0.f) ? rsqrtf(d3) : 0.f) * w3 * dic * h3;
  }
  for (; p < p1; ++p) {
    int2 s0 = pstat[p];
    float w0 = wgr[s0.y];
    float d0 = colw[s0.x];
    acc += ((d0 > 0.f) ? rsqrtf(d0) : 0.f) * w0 * dic
         * __bfloat162float(hW[(size_t)s0.x * C + jj]);
  }
  if (!act) acc = 0.f;
  float v = act ? acc : -3.0e38f;
#pragma unroll
  for (int m = 32; m >= 1; m >>= 1) v = fmaxf(v, __shfl_xor(v, m));
  float ex = act ? expf(acc - v) : 0.f;
#pragma unroll
  for (int m = 32; m >= 1; m >>= 1) ex += __shfl_xor(ex, m);
  if (act) out[(size_t)c * C + j] = acc - v - logf(ex);
}

extern "C" void kernel_launch(void* const* d_in, const int* in_sizes, int n_in,
                              void* d_out, int out_size, void* d_ws, size_t ws_size,
                              hipStream_t stream) {
  const float* x    = (const float*)d_in[0];
  const float* gate = (const float*)d_in[1];
  const float* W0   = (const float*)d_in[2];
  const float* b0   = (const float*)d_in[3];
  const float* W1   = (const float*)d_in[4];
  const float* b1   = (const float*)d_in[5];
  const float* W2   = (const float*)d_in[6];
  const float* b2   = (const float*)d_in[7];
  const int* eidx   = (const int*)d_in[8];
  int N = in_sizes[0] / 128;
  int E = in_sizes[8] / 2;
  int C = in_sizes[7];  // 40
  const int* row = eidx;
  const int* col = eidx + E;

  char* ws = (char*)d_ws;
  size_t off = 0;
  auto alloc = [&](size_t bytes) {
    char* p = ws + off;
    off += (bytes + 255) & ~(size_t)255;
    return p;
  };
  float* xn     = (float*)alloc((size_t)N * 128 * 4);
  __hip_bfloat16* xnb = (__hip_bfloat16*)alloc((size_t)N * 128 * 2);
  float* bufC   = (float*)alloc((size_t)N * 128 * 4);
  __hip_bfloat16* hWb = (__hip_bfloat16*)alloc((size_t)N * 128 * 2);
  float* adjr   = (float*)alloc((size_t)E * 4);    // layer-0 weights, row-CSR order
  float* wgr    = (float*)alloc((size_t)E * 4);    // gated weight, row-CSR order
  int*   perm_r = (int*)alloc((size_t)E * 4);
  int2*  pstat  = (int2*)alloc((size_t)E * 8);     // (row, rowCSR-slot) per col slot
  int*   colof_r= (int*)alloc((size_t)E * 4);
  int*   ebuck  = (int*)alloc((size_t)E * 4);      // bucket-partitioned packed ids
  int*   offs_c = (int*)alloc((size_t)(N + 1) * 4);
  int*   offs_r = (int*)alloc((size_t)(N + 1) * 4);
  float* colw   = (float*)alloc((size_t)N * 4);

  int NCHUNK = (E + 2047) / 2048;
  int M      = 256 * NCHUNK;
  int*   ghist  = (int*)alloc((size_t)M * 4);
  int*   partial= (int*)alloc((size_t)M * 4);
  int*   bsum   = (int*)alloc((size_t)NCHUNK * 4);
  int*   boffs  = (int*)alloc((size_t)NCHUNK * 4);

  int NBUK = (N + 255) / 256;
  int nw4  = (N + 3) / 4;

  // ---- CSR build: atomic-free two-level counting sort (row, then col) ----
  k_lhist<<<NCHUNK, 256, 0, stream>>>(row, nullptr, ghist, nullptr, NCHUNK, E);
  k_scan1<<<NCHUNK, 256, 0, stream>>>(ghist, partial, bsum, M);
  k_scan2<<<1, 256, 0, stream>>>(bsum, boffs, NCHUNK);
  k_bucketize<<<NCHUNK, 256, 0, stream>>>(row, nullptr, partial, boffs, ebuck, NCHUNK, E);
  k_final_row<<<NBUK, 256, 0, stream>>>(ebuck, partial, boffs, perm_r, offs_r,
                                        NCHUNK, N, E);
  k_lhist<<<NCHUNK, 256, 0, stream>>>(col, perm_r, ghist, colof_r, NCHUNK, E);
  k_scan1<<<NCHUNK, 256, 0, stream>>>(ghist, partial, bsum, M);
  k_scan2<<<1, 256, 0, stream>>>(bsum, boffs, NCHUNK);
  k_bucketize<<<NCHUNK, 256, 0, stream>>>(col, perm_r, partial, boffs, ebuck, NCHUNK, E);
  k_final_col<<<NBUK, 256, 0, stream>>>(ebuck, perm_r, row, partial, boffs, pstat,
                                        offs_c, NCHUNK, N, E);

  for (int layer = 0; layer < 3; ++layer) {
    hipMemsetAsync(colw, 0, (size_t)N * 4, stream);
    if (layer == 0) k_normalize<<<(N + 3) / 4, 256, 0, stream>>>(x, xn, xnb, N);
    k_simw<<<nw4, 256, 0, stream>>>(xn, xnb, colof_r, offs_r, adjr, wgr, colw,
                                    gate, layer, N);
    const float* hin = (layer == 0) ? x : bufC;
    if (layer < 2) {
      const float* W = (layer == 0) ? W0 : W1;
      const float* b = (layer == 0) ? b0 : b1;
      k_gemm128<<<(N + 31) / 32, 256, 0, stream>>>(hin, W, hWb, N);
      k_agg_norm<<<nw4, 256, 0, stream>>>((const __hip_bfloat162*)hWb, pstat, wgr, colw,
                                          offs_c, b, bufC, xn, xnb, N);
    } else {
      k_gemm40<<<(N + 63) / 64, 320, 0, stream>>>(hin, W2, hWb, N, C);
      k_agg40_lsm<<<nw4, 256, 0, stream>>>(hWb, pstat, wgr, colw, offs_c, b2,
                                           (float*)d_out, C, N);
    }
  }
}

// Round 11
// 622.549 us; speedup vs baseline: 1.6052x; 1.0099x over previous
//
#include <hip/hip_runtime.h>
#include <hip/hip_bf16.h>
#include <math.h>

#define F 128

typedef __attribute__((ext_vector_type(8))) short bf16x8;
typedef __attribute__((ext_vector_type(4))) float f32x4;

// ------- row-normalize: xn = x/max(||x||,eps) (fp32 + bf16 copies) ----------
__global__ void k_normalize(const float* __restrict__ x, float* __restrict__ xn,
                            __hip_bfloat16* __restrict__ xnb, int N) {
  int wid = (blockIdx.x * blockDim.x + threadIdx.x) >> 6;  // one wave per node
  int lane = threadIdx.x & 63;
  if (wid >= N) return;
  const float2* src = (const float2*)(x + (size_t)wid * F);
  float2 v = src[lane];
  float ss = v.x * v.x + v.y * v.y;
#pragma unroll
  for (int m = 32; m >= 1; m >>= 1) ss += __shfl_xor(ss, m);
  float inv = 1.0f / fmaxf(sqrtf(ss), 1e-12f);
  float2 o; o.x = v.x * inv; o.y = v.y * inv;
  ((float2*)(xn + (size_t)wid * F))[lane] = o;
  __hip_bfloat162 ob;
  ob.x = __float2bfloat16(o.x); ob.y = __float2bfloat16(o.y);
  ((__hip_bfloat162*)(xnb + (size_t)wid * F))[lane] = ob;
}

// ============ CSR build: atomic-free two-level LDS counting sort ============
// bucket = node >> 8 (<=256 buckets for N<=65536); 2048-edge chunks.

__global__ __launch_bounds__(256) void k_lhist(
    const int* __restrict__ keys, const int* __restrict__ perm,
    int* __restrict__ ghist, int* __restrict__ keyout, int nchunk, int E) {
  __shared__ int lh[256];
  int t = threadIdx.x, chunk = blockIdx.x;
  lh[t] = 0;
  __syncthreads();
  int base = chunk * 2048;
#pragma unroll
  for (int k = 0; k < 8; ++k) {
    int i = base + k * 256 + t;
    if (i < E) {
      int key = perm ? keys[perm[i]] : keys[i];
      if (keyout) keyout[i] = key;
      atomicAdd(&lh[key >> 8], 1);
    }
  }
  __syncthreads();
  ghist[t * nchunk + chunk] = lh[t];
}

__global__ void k_scan1(const int* __restrict__ cnt, int* __restrict__ partial,
                        int* __restrict__ bsum, int M) {
  __shared__ int sm[256];
  int t = threadIdx.x;
  int i = blockIdx.x * 256 + t;
  int val = (i < M) ? cnt[i] : 0;
  sm[t] = val;
  __syncthreads();
  for (int off = 1; off < 256; off <<= 1) {
    int v = (t >= off) ? sm[t - off] : 0;
    __syncthreads();
    sm[t] += v;
    __syncthreads();
  }
  if (i < M) partial[i] = sm[t] - val;  // exclusive
  if (t == 255) bsum[blockIdx.x] = sm[255];
}

// looped single-block scan (handles nb > 256)
__global__ void k_scan2(const int* __restrict__ bsum, int* __restrict__ boffs, int nb) {
  __shared__ int sm[256];
  int t = threadIdx.x;
  int carry = 0;
  for (int base = 0; base < nb; base += 256) {
    int idx = base + t;
    int val = (idx < nb) ? bsum[idx] : 0;
    sm[t] = val;
    __syncthreads();
    for (int off = 1; off < 256; off <<= 1) {
      int v = (t >= off) ? sm[t - off] : 0;
      __syncthreads();
      sm[t] += v;
      __syncthreads();
    }
    if (idx < nb) boffs[idx] = sm[t] - val + carry;
    carry += sm[255];
    __syncthreads();
  }
}

__global__ __launch_bounds__(256) void k_bucketize(
    const int* __restrict__ keys, const int* __restrict__ perm,
    const int* __restrict__ partial, const int* __restrict__ boffs,
    int* __restrict__ ebuck, int nchunk, int E) {
  __shared__ int lcur[256];
  int t = threadIdx.x, chunk = blockIdx.x;
  int idx = t * nchunk + chunk;
  lcur[t] = partial[idx] + boffs[idx >> 8];
  __syncthreads();
  int base = chunk * 2048;
#pragma unroll
  for (int k = 0; k < 8; ++k) {
    int i = base + k * 256 + t;
    if (i < E) {
      int key = perm ? keys[perm[i]] : keys[i];
      int pos = atomicAdd(&lcur[key >> 8], 1);
      ebuck[pos] = (i << 8) | (key & 255);
    }
  }
}

__global__ __launch_bounds__(256) void k_final_row(
    const int* __restrict__ ebuck, const int* __restrict__ partial,
    const int* __restrict__ boffs, int* __restrict__ perm_r,
    int* __restrict__ offs_r, int nchunk, int N, int E) {
  __shared__ int lh[256], sm[256], lscan[256];
  int t = threadIdx.x, b = blockIdx.x;
  int i0 = b * nchunk;
  int start = partial[i0] + boffs[i0 >> 8];
  int i1 = i0 + nchunk;
  int end = (b < 255) ? partial[i1] + boffs[i1 >> 8] : E;
  lh[t] = 0;
  __syncthreads();
  for (int p = start + t; p < end; p += 256) atomicAdd(&lh[ebuck[p] & 255], 1);
  __syncthreads();
  int val = lh[t];
  sm[t] = val;
  __syncthreads();
  for (int off = 1; off < 256; off <<= 1) {
    int v = (t >= off) ? sm[t - off] : 0;
    __syncthreads();
    sm[t] += v;
    __syncthreads();
  }
  lscan[t] = sm[t] - val;
  int node = b * 256 + t;
  if (node < N) offs_r[node] = start + lscan[t];
  if (b == 0 && t == 0) offs_r[N] = E;
  lh[t] = 0;
  __syncthreads();
  for (int p = start + t; p < end; p += 256) {
    int v = ebuck[p];
    int low = v & 255;
    int rk = atomicAdd(&lh[low], 1);
    perm_r[start + lscan[low] + rk] = v >> 8;
  }
}

__global__ __launch_bounds__(256) void k_final_col(
    const int* __restrict__ ebuck, const int* __restrict__ perm_r,
    const int* __restrict__ row, const int* __restrict__ partial,
    const int* __restrict__ boffs, int2* __restrict__ pstat,
    int* __restrict__ offs_c, int nchunk, int N, int E) {
  __shared__ int lh[256], sm[256], lscan[256];
  int t = threadIdx.x, b = blockIdx.x;
  int i0 = b * nchunk;
  int start = partial[i0] + boffs[i0 >> 8];
  int i1 = i0 + nchunk;
  int end = (b < 255) ? partial[i1] + boffs[i1 >> 8] : E;
  lh[t] = 0;
  __syncthreads();
  for (int p = start + t; p < end; p += 256) atomicAdd(&lh[ebuck[p] & 255], 1);
  __syncthreads();
  int val = lh[t];
  sm[t] = val;
  __syncthreads();
  for (int off = 1; off < 256; off <<= 1) {
    int v = (t >= off) ? sm[t - off] : 0;
    __syncthreads();
    sm[t] += v;
    __syncthreads();
  }
  lscan[t] = sm[t] - val;
  int node = b * 256 + t;
  if (node < N) offs_c[node] = start + lscan[t];
  if (b == 0 && t == 0) offs_c[N] = E;
  lh[t] = 0;
  __syncthreads();
  for (int p = start + t; p < end; p += 256) {
    int v = ebuck[p];
    int low = v & 255;
    int rp = v >> 8;                      // rowCSR slot (~ascending -> L2 locality)
    int e = perm_r[rp];
    int rk = atomicAdd(&lh[low], 1);
    int2 rec; rec.x = row[e]; rec.y = rp;
    pstat[start + lscan[low] + rk] = rec;
  }
}

// ------- fused per-row sims + weights, MFMA edition. One wave per row. ------
__global__ __launch_bounds__(256) void k_simw(
    const float* __restrict__ xn, const __hip_bfloat16* __restrict__ xnb,
    const int* __restrict__ colof_r, const int* __restrict__ offs_r,
    float* __restrict__ adjr, float* __restrict__ wgr, float* __restrict__ colw,
    const float* __restrict__ gate, int layer, int N) {
  int w = threadIdx.x >> 6;   // wave 0..3, one row each
  int l = threadIdx.x & 63;
  int r = blockIdx.x * 4 + w;
  __shared__ float sims[4][320];
  __shared__ int scol[4][320];
  if (r >= N) return;
  int p0 = offs_r[r], p1 = offs_r[r + 1];
  int ne = p1 - p0;                     // ~17 (Poisson(16) + self loop), <320
  int quad = l >> 4;
  int m = l & 15;
  int qoff = quad * 8;
  const __hip_bfloat16* xr = xnb + (size_t)r * F;
  bf16x8 b0 = *(const bf16x8*)(xr + 0 * 32 + qoff);   // 16-lane broadcast loads
  bf16x8 b1 = *(const bf16x8*)(xr + 1 * 32 + qoff);
  bf16x8 b2 = *(const bf16x8*)(xr + 2 * 32 + qoff);
  bf16x8 b3 = *(const bf16x8*)(xr + 3 * 32 + qoff);
  for (int tb = 0; tb < ne; tb += 16) {
    int ii = tb + m; if (ii > ne - 1) ii = ne - 1;     // clamp (extra rows ignored)
    int cm = colof_r[p0 + ii];
    if (quad == 0 && tb + m < ne) scol[w][tb + m] = cm;
    const __hip_bfloat16* xc = xnb + (size_t)cm * F;
    bf16x8 a0 = *(const bf16x8*)(xc + 0 * 32 + qoff);  // 4 independent 16B gathers
    bf16x8 a1 = *(const bf16x8*)(xc + 1 * 32 + qoff);
    bf16x8 a2 = *(const bf16x8*)(xc + 2 * 32 + qoff);
    bf16x8 a3 = *(const bf16x8*)(xc + 3 * 32 + qoff);
    f32x4 acc = {0.f, 0.f, 0.f, 0.f};
    acc = __builtin_amdgcn_mfma_f32_16x16x32_bf16(a0, b0, acc, 0, 0, 0);
    acc = __builtin_amdgcn_mfma_f32_16x16x32_bf16(a1, b1, acc, 0, 0, 0);
    acc = __builtin_amdgcn_mfma_f32_16x16x32_bf16(a2, b2, acc, 0, 0, 0);
    acc = __builtin_amdgcn_mfma_f32_16x16x32_bf16(a3, b3, acc, 0, 0, 0);
    if (m == 0) {                       // lanes 0,16,32,48 hold rows quad*4+reg
#pragma unroll
      for (int reg = 0; reg < 4; ++reg) {
        int i = tb + quad * 4 + reg;
        if (i < ne) sims[w][i] = acc[reg];
      }
    }
  }
  // pass 2: guard-band fp32 recompute + threshold + rowsum/deg (one wave).
  // Band: bf16 rounding is 2^-8/operand -> dot err <= 2^-7 * sum|a_i b_i|
  // <= 2^-7 = 0.0078 (Cauchy-Schwarz, unit vectors); fp32 MFMA accum adds
  // ~1e-6. Band +-0.01 covers the deterministic worst case with margin.
  float vsum = 0.f; int cn = 0;
  for (int base = 0; base < ne; base += 64) {
    int i = base + l;
    bool have = i < ne;
    float s = have ? sims[w][i] : 0.f;
    int c = have ? scol[w][i] : r;
    bool self = (c == r);
    bool flag = have && !self && fabsf(s - 0.1f) < 0.01f;
    unsigned long long mask = __ballot(flag);
    while (mask) {                      // ~0.8 flagged edge/row: wave-coop fp32 dot
      int src = __ffsll(mask) - 1;
      mask &= mask - 1;
      int cc = __shfl(c, src);
      float2 ar = ((const float2*)(xn + (size_t)r * F))[l];
      float2 bc = ((const float2*)(xn + (size_t)cc * F))[l];
      float d = ar.x * bc.x + ar.y * bc.y;
#pragma unroll
      for (int mm = 32; mm >= 1; mm >>= 1) d += __shfl_xor(d, mm);
      if (l == src) s = d;
    }
    if (self || s < 0.1f) s = 0.f;
    if (have) sims[w][i] = s;
    vsum += s;
    cn += (s > 0.f) ? 1 : 0;
  }
#pragma unroll
  for (int mm = 32; mm >= 1; mm >>= 1) {
    vsum += __shfl_xor(vsum, mm);
    cn += __shfl_xor(cn, mm);
  }
  float rs = vsum;
  float lam = 1.0f / (float)(cn + 1);
  float gg = (layer > 0) ? gate[layer - 1] : 0.f;
  for (int i = l; i < ne; i += 64) {
    int c = scol[w][i];
    float s = sims[w][i];
    float sn = (rs > 0.f) ? s / rs : 0.f;
    float wv = (c == r) ? lam : sn;
    wv = expf(wv);                      // thresholded edges get exp(0)=1
    float wc;
    if (layer == 0) { adjr[p0 + i] = wv; wc = wv; }
    else { wc = gg * adjr[p0 + i] + (1.f - gg) * wv; }
    wgr[p0 + i] = wc;                   // sequential write
    atomicAdd(colw + c, wc);            // 200KB table, L2-resident
  }
}

// ------ GEMM: out_bf16[M,128] = A[M,128] @ W[128,128], register-tiled -------
__global__ __launch_bounds__(256) void k_gemm128(const float* __restrict__ A,
                                                 const float* __restrict__ W,
                                                 __hip_bfloat16* __restrict__ out, int M) {
  __shared__ float As[128][36];
  int t = threadIdx.x;
  int n0 = blockIdx.x * 32;
  for (int i = t; i < 32 * 128; i += 256) {
    int nn = i >> 7, kk = i & 127;
    int gn = n0 + nn;
    As[kk][nn] = (gn < M) ? A[(size_t)gn * 128 + kk] : 0.f;
  }
  __syncthreads();
  int nb = (t >> 6) * 8;
  int j2 = (t & 63) * 2;
  float acc[8][2] = {};
  for (int k = 0; k < 128; ++k) {
    float4 a01 = *(const float4*)&As[k][nb];
    float4 a23 = *(const float4*)&As[k][nb + 4];
    float2 wv = *(const float2*)&W[k * 128 + j2];
    acc[0][0] += a01.x * wv.x; acc[0][1] += a01.x * wv.y;
    acc[1][0] += a01.y * wv.x; acc[1][1] += a01.y * wv.y;
    acc[2][0] += a01.z * wv.x; acc[2][1] += a01.z * wv.y;
    acc[3][0] += a01.w * wv.x; acc[3][1] += a01.w * wv.y;
    acc[4][0] += a23.x * wv.x; acc[4][1] += a23.x * wv.y;
    acc[5][0] += a23.y * wv.x; acc[5][1] += a23.y * wv.y;
    acc[6][0] += a23.z * wv.x; acc[6][1] += a23.z * wv.y;
    acc[7][0] += a23.w * wv.x; acc[7][1] += a23.w * wv.y;
  }
  __hip_bfloat162* o2 = (__hip_bfloat162*)out;
#pragma unroll
  for (int i = 0; i < 8; ++i) {
    int gn = n0 + nb + i;
    if (gn < M) {
      __hip_bfloat162 o;
      o.x = __float2bfloat16(acc[i][0]); o.y = __float2bfloat16(acc[i][1]);
      o2[(size_t)gn * 64 + (j2 >> 1)] = o;
    }
  }
}

// ------ GEMM: out_bf16[M,40] = A[M,128] @ W[128,40], register-tiled ---------
__global__ __launch_bounds__(320) void k_gemm40(const float* __restrict__ A,
                                                const float* __restrict__ W,
                                                __hip_bfloat16* __restrict__ out,
                                                int M, int C) {
  __shared__ float As[128][68];
  int t = threadIdx.x;
  int n0 = blockIdx.x * 64;
  for (int i = t; i < 64 * 128; i += 320) {
    int nn = i >> 7, kk = i & 127;
    int gn = n0 + nn;
    As[kk][nn] = (gn < M) ? A[(size_t)gn * 128 + kk] : 0.f;
  }
  __syncthreads();
  int gq = t / 40;
  int jc = t - gq * 40;
  int nb = gq * 8;
  float acc[8] = {};
  for (int k = 0; k < 128; ++k) {
    float4 a01 = *(const float4*)&As[k][nb];
    float4 a23 = *(const float4*)&As[k][nb + 4];
    float wv = W[k * C + jc];
    acc[0] += a01.x * wv; acc[1] += a01.y * wv; acc[2] += a01.z * wv; acc[3] += a01.w * wv;
    acc[4] += a23.x * wv; acc[5] += a23.y * wv; acc[6] += a23.z * wv; acc[7] += a23.w * wv;
  }
#pragma unroll
  for (int i = 0; i < 8; ++i) {
    int gn = n0 + nb + i;
    if (gn < M) out[(size_t)gn * C + jc] = __float2bfloat16(acc[i]);
  }
}

// ---- fused: per-edge norm + aggregation + bias + relu + row-normalize ------
__global__ __launch_bounds__(256) void k_agg_norm(
    const __hip_bfloat162* __restrict__ hWb, const int2* __restrict__ pstat,
    const float* __restrict__ wgr, const float* __restrict__ colw,
    const int* __restrict__ offs_c, const float* __restrict__ bias,
    float* __restrict__ out, float* __restrict__ xn, __hip_bfloat16* __restrict__ xnb,
    int N) {
  int w = threadIdx.x >> 6;
  int t = threadIdx.x & 63;
  int c = blockIdx.x * 4 + w;
  if (c >= N) return;
  int p0 = offs_c[c], p1 = offs_c[c + 1];
  float dcv = colw[c];
  float dic = (dcv > 0.f) ? rsqrtf(dcv) : 0.f;
  float acc0 = bias[2 * t], acc1 = bias[2 * t + 1];
  int p = p0;
  for (; p + 8 <= p1; p += 8) {   // 8 row-gathers in flight
    int2 s[8];
    __hip_bfloat162 h[8];
    float wv[8], dv[8];
#pragma unroll
    for (int k = 0; k < 8; ++k) s[k] = pstat[p + k];
#pragma unroll
    for (int k = 0; k < 8; ++k) h[k] = hWb[(size_t)s[k].x * 64 + t];
#pragma unroll
    for (int k = 0; k < 8; ++k) { wv[k] = wgr[s[k].y]; dv[k] = colw[s[k].x]; }
#pragma unroll
    for (int k = 0; k < 8; ++k) {
      float n = ((dv[k] > 0.f) ? rsqrtf(dv[k]) : 0.f) * wv[k] * dic;
      acc0 += n * __bfloat162float(h[k].x);
      acc1 += n * __bfloat162float(h[k].y);
    }
  }
  for (; p + 4 <= p1; p += 4) {
    int2 s0 = pstat[p], s1 = pstat[p + 1], s2 = pstat[p + 2], s3 = pstat[p + 3];
    float w0 = wgr[s0.y], w1 = wgr[s1.y], w2 = wgr[s2.y], w3 = wgr[s3.y];
    float d0 = colw[s0.x], d1 = colw[s1.x], d2 = colw[s2.x], d3 = colw[s3.x];
    __hip_bfloat162 h0 = hWb[(size_t)s0.x * 64 + t];
    __hip_bfloat162 h1 = hWb[(size_t)s1.x * 64 + t];
    __hip_bfloat162 h2 = hWb[(size_t)s2.x * 64 + t];
    __hip_bfloat162 h3 = hWb[(size_t)s3.x * 64 + t];
    float n0 = ((d0 > 0.f) ? rsqrtf(d0) : 0.f) * w0 * dic;
    float n1 = ((d1 > 0.f) ? rsqrtf(d1) : 0.f) * w1 * dic;
    float n2 = ((d2 > 0.f) ? rsqrtf(d2) : 0.f) * w2 * dic;
    float n3 = ((d3 > 0.f) ? rsqrtf(d3) : 0.f) * w3 * dic;
    acc0 += n0 * __bfloat162float(h0.x) + n1 * __bfloat162float(h1.x)
          + n2 * __bfloat162float(h2.x) + n3 * __bfloat162float(h3.x);
    acc1 += n0 * __bfloat162float(h0.y) + n1 * __bfloat162float(h1.y)
          + n2 * __bfloat162float(h2.y) + n3 * __bfloat162float(h3.y);
  }
  for (; p < p1; ++p) {
    int2 s0 = pstat[p];
    float w0 = wgr[s0.y];
    float d0 = colw[s0.x];
    __hip_bfloat162 h0 = hWb[(size_t)s0.x * 64 + t];
    float n0 = ((d0 > 0.f) ? rsqrtf(d0) : 0.f) * w0 * dic;
    acc0 += n0 * __bfloat162float(h0.x);
    acc1 += n0 * __bfloat162float(h0.y);
  }
  acc0 = fmaxf(acc0, 0.f); acc1 = fmaxf(acc1, 0.f);
  float2 o; o.x = acc0; o.y = acc1;
  ((float2*)out)[(size_t)c * 64 + t] = o;
  float ss = acc0 * acc0 + acc1 * acc1;
#pragma unroll
  for (int m = 32; m >= 1; m >>= 1) ss += __shfl_xor(ss, m);
  float inv = 1.0f / fmaxf(sqrtf(ss), 1e-12f);
  float2 on; on.x = acc0 * inv; on.y = acc1 * inv;
  ((float2*)xn)[(size_t)c * 64 + t] = on;
  __hip_bfloat162 ob;
  ob.x = __float2bfloat16(on.x); ob.y = __float2bfloat16(on.y);
  ((__hip_bfloat162*)xnb)[(size_t)c * 64 + t] = ob;
}

// ------- fused final aggregation + bias + log_softmax; wave per node --------
__global__ __launch_bounds__(256) void k_agg40_lsm(
    const __hip_bfloat16* __restrict__ hW, const int2* __restrict__ pstat,
    const float* __restrict__ wgr, const float* __restrict__ colw,
    const int* __restrict__ offs_c, const float* __restrict__ bias,
    float* __restrict__ out, int C, int N) {
  int w = threadIdx.x >> 6;
  int j = threadIdx.x & 63;
  int c = blockIdx.x * 4 + w;
  if (c >= N) return;
  int p0 = offs_c[c], p1 = offs_c[c + 1];
  float dcv = colw[c];
  float dic = (dcv > 0.f) ? rsqrtf(dcv) : 0.f;
  bool act = j < C;
  int jj = act ? j : 0;
  float acc = act ? bias[jj] : 0.f;
  int p = p0;
  for (; p + 4 <= p1; p += 4) {
    int2 s0 = pstat[p], s1 = pstat[p + 1], s2 = pstat[p + 2], s3 = pstat[p + 3];
    float w0 = wgr[s0.y], w1 = wgr[s1.y], w2 = wgr[s2.y], w3 = wgr[s3.y];
    float d0 = colw[s0.x], d1 = colw[s1.x], d2 = colw[s2.x], d3 = colw[s3.x];
    float h0 = __bfloat162float(hW[(size_t)s0.x * C + jj]);
    float h1 = __bfloat162float(hW[(size_t)s1.x * C + jj]);
    float h2 = __bfloat162float(hW[(size_t)s2.x * C + jj]);
    float h3 = __bfloat162float(hW[(size_t)s3.x * C + jj]);
    acc += ((d0 > 0.f) ? rsqrtf(d0) : 0.f) * w0 * dic * h0
         + ((d1 > 0.f) ? rsqrtf(d1) : 0.f) * w1 * dic * h1
         + ((d2 > 0.f) ? rsqrtf(d2) : 0.f) * w2 * dic * h2
         + ((d3 > 0.f) ? rsqrtf(d3) : 0.f) * w3 * dic * h3;
  }
  for (; p < p1; ++p) {
    int2 s0 = pstat[p];
    float w0 = wgr[s0.y];
    float d0 = colw[s0.x];
    acc += ((d0 > 0.f) ? rsqrtf(d0) : 0.f) * w0 * dic
         * __bfloat162float(hW[(size_t)s0.x * C + jj]);
  }
  if (!act) acc = 0.f;
  float v = act ? acc : -3.0e38f;
#pragma unroll
  for (int m = 32; m >= 1; m >>= 1) v = fmaxf(v, __shfl_xor(v, m));
  float ex = act ? expf(acc - v) : 0.f;
#pragma unroll
  for (int m = 32; m >= 1; m >>= 1) ex += __shfl_xor(ex, m);
  if (act) out[(size_t)c * C + j] = acc - v - logf(ex);
}

extern "C" void kernel_launch(void* const* d_in, const int* in_sizes, int n_in,
                              void* d_out, int out_size, void* d_ws, size_t ws_size,
                              hipStream_t stream) {
  const float* x    = (const float*)d_in[0];
  const float* gate = (const float*)d_in[1];
  const float* W0   = (const float*)d_in[2];
  const float* b0   = (const float*)d_in[3];
  const float* W1   = (const float*)d_in[4];
  const float* b1   = (const float*)d_in[5];
  const float* W2   = (const float*)d_in[6];
  const float* b2   = (const float*)d_in[7];
  const int* eidx   = (const int*)d_in[8];
  int N = in_sizes[0] / 128;
  int E = in_sizes[8] / 2;
  int C = in_sizes[7];  // 40
  const int* row = eidx;
  const int* col = eidx + E;

  char* ws = (char*)d_ws;
  size_t off = 0;
  auto alloc = [&](size_t bytes) {
    char* p = ws + off;
    off += (bytes + 255) & ~(size_t)255;
    return p;
  };
  float* xn     = (float*)alloc((size_t)N * 128 * 4);
  __hip_bfloat16* xnb = (__hip_bfloat16*)alloc((size_t)N * 128 * 2);
  float* bufC   = (float*)alloc((size_t)N * 128 * 4);
  __hip_bfloat16* hWb = (__hip_bfloat16*)alloc((size_t)N * 128 * 2);
  float* adjr   = (float*)alloc((size_t)E * 4);    // layer-0 weights, row-CSR order
  float* wgr    = (float*)alloc((size_t)E * 4);    // gated weight, row-CSR order
  int*   perm_r = (int*)alloc((size_t)E * 4);
  int2*  pstat  = (int2*)alloc((size_t)E * 8);     // (row, rowCSR-slot) per col slot
  int*   colof_r= (int*)alloc((size_t)E * 4);
  int*   ebuck  = (int*)alloc((size_t)E * 4);      // bucket-partitioned packed ids
  int*   offs_c = (int*)alloc((size_t)(N + 1) * 4);
  int*   offs_r = (int*)alloc((size_t)(N + 1) * 4);
  float* colw   = (float*)alloc((size_t)N * 4);

  int NCHUNK = (E + 2047) / 2048;
  int M      = 256 * NCHUNK;
  int*   ghist  = (int*)alloc((size_t)M * 4);
  int*   partial= (int*)alloc((size_t)M * 4);
  int*   bsum   = (int*)alloc((size_t)NCHUNK * 4);
  int*   boffs  = (int*)alloc((size_t)NCHUNK * 4);

  int NBUK = (N + 255) / 256;
  int nw4  = (N + 3) / 4;

  // ---- CSR build: atomic-free two-level counting sort (row, then col) ----
  k_lhist<<<NCHUNK, 256, 0, stream>>>(row, nullptr, ghist, nullptr, NCHUNK, E);
  k_scan1<<<NCHUNK, 256, 0, stream>>>(ghist, partial, bsum, M);
  k_scan2<<<1, 256, 0, stream>>>(bsum, boffs, NCHUNK);
  k_bucketize<<<NCHUNK, 256, 0, stream>>>(row, nullptr, partial, boffs, ebuck, NCHUNK, E);
  k_final_row<<<NBUK, 256, 0, stream>>>(ebuck, partial, boffs, perm_r, offs_r,
                                        NCHUNK, N, E);
  k_lhist<<<NCHUNK, 256, 0, stream>>>(col, perm_r, ghist, colof_r, NCHUNK, E);
  k_scan1<<<NCHUNK, 256, 0, stream>>>(ghist, partial, bsum, M);
  k_scan2<<<1, 256, 0, stream>>>(bsum, boffs, NCHUNK);
  k_bucketize<<<NCHUNK, 256, 0, stream>>>(col, perm_r, partial, boffs, ebuck, NCHUNK, E);
  k_final_col<<<NBUK, 256, 0, stream>>>(ebuck, perm_r, row, partial, boffs, pstat,
                                        offs_c, NCHUNK, N, E);

  for (int layer = 0; layer < 3; ++layer) {
    hipMemsetAsync(colw, 0, (size_t)N * 4, stream);
    if (layer == 0) k_normalize<<<(N + 3) / 4, 256, 0, stream>>>(x, xn, xnb, N);
    k_simw<<<nw4, 256, 0, stream>>>(xn, xnb, colof_r, offs_r, adjr, wgr, colw,
                                    gate, layer, N);
    const float* hin = (layer == 0) ? x : bufC;
    if (layer < 2) {
      const float* W = (layer == 0) ? W0 : W1;
      const float* b = (layer == 0) ? b0 : b1;
      k_gemm128<<<(N + 31) / 32, 256, 0, stream>>>(hin, W, hWb, N);
      k_agg_norm<<<nw4, 256, 0, stream>>>((const __hip_bfloat162*)hWb, pstat, wgr, colw,
                                          offs_c, b, bufC, xn, xnb, N);
    } else {
      k_gemm40<<<(N + 63) / 64, 320, 0, stream>>>(hin, W2, hWb, N, C);
      k_agg40_lsm<<<nw4, 256, 0, stream>>>(hWb, pstat, wgr, colw, offs_c, b2,
                                           (float*)d_out, C, N);
    }
  }
}

// Round 12
// 592.456 us; speedup vs baseline: 1.6867x; 1.0508x over previous
//
#include <hip/hip_runtime.h>
#include <hip/hip_bf16.h>
#include <math.h>

#define F 128

typedef __attribute__((ext_vector_type(8))) short bf16x8;
typedef __attribute__((ext_vector_type(4))) float f32x4;

// ------- row-normalize: xn = x/max(||x||,eps) (fp32 + bf16 copies) ----------
__global__ void k_normalize(const float* __restrict__ x, float* __restrict__ xn,
                            __hip_bfloat16* __restrict__ xnb, int N) {
  int wid = (blockIdx.x * blockDim.x + threadIdx.x) >> 6;  // one wave per node
  int lane = threadIdx.x & 63;
  if (wid >= N) return;
  const float2* src = (const float2*)(x + (size_t)wid * F);
  float2 v = src[lane];
  float ss = v.x * v.x + v.y * v.y;
#pragma unroll
  for (int m = 32; m >= 1; m >>= 1) ss += __shfl_xor(ss, m);
  float inv = 1.0f / fmaxf(sqrtf(ss), 1e-12f);
  float2 o; o.x = v.x * inv; o.y = v.y * inv;
  ((float2*)(xn + (size_t)wid * F))[lane] = o;
  __hip_bfloat162 ob;
  ob.x = __float2bfloat16(o.x); ob.y = __float2bfloat16(o.y);
  ((__hip_bfloat162*)(xnb + (size_t)wid * F))[lane] = ob;
}

// ============ CSR build: atomic-free two-level LDS counting sort ============
// bucket = node >> 8 (<=256 buckets for N<=65536); 2048-edge chunks.

__global__ __launch_bounds__(256) void k_lhist(
    const int* __restrict__ keys, const int* __restrict__ perm,
    int* __restrict__ ghist, int* __restrict__ keyout, int nchunk, int E) {
  __shared__ int lh[256];
  int t = threadIdx.x, chunk = blockIdx.x;
  lh[t] = 0;
  __syncthreads();
  int base = chunk * 2048;
#pragma unroll
  for (int k = 0; k < 8; ++k) {
    int i = base + k * 256 + t;
    if (i < E) {
      int key = perm ? keys[perm[i]] : keys[i];
      if (keyout) keyout[i] = key;
      atomicAdd(&lh[key >> 8], 1);
    }
  }
  __syncthreads();
  ghist[t * nchunk + chunk] = lh[t];
}

__global__ void k_scan1(const int* __restrict__ cnt, int* __restrict__ partial,
                        int* __restrict__ bsum, int M) {
  __shared__ int sm[256];
  int t = threadIdx.x;
  int i = blockIdx.x * 256 + t;
  int val = (i < M) ? cnt[i] : 0;
  sm[t] = val;
  __syncthreads();
  for (int off = 1; off < 256; off <<= 1) {
    int v = (t >= off) ? sm[t - off] : 0;
    __syncthreads();
    sm[t] += v;
    __syncthreads();
  }
  if (i < M) partial[i] = sm[t] - val;  // exclusive
  if (t == 255) bsum[blockIdx.x] = sm[255];
}

// looped single-block scan (handles nb > 256)
__global__ void k_scan2(const int* __restrict__ bsum, int* __restrict__ boffs, int nb) {
  __shared__ int sm[256];
  int t = threadIdx.x;
  int carry = 0;
  for (int base = 0; base < nb; base += 256) {
    int idx = base + t;
    int val = (idx < nb) ? bsum[idx] : 0;
    sm[t] = val;
    __syncthreads();
    for (int off = 1; off < 256; off <<= 1) {
      int v = (t >= off) ? sm[t - off] : 0;
      __syncthreads();
      sm[t] += v;
      __syncthreads();
    }
    if (idx < nb) boffs[idx] = sm[t] - val + carry;
    carry += sm[255];
    __syncthreads();
  }
}

__global__ __launch_bounds__(256) void k_bucketize(
    const int* __restrict__ keys, const int* __restrict__ perm,
    const int* __restrict__ partial, const int* __restrict__ boffs,
    int* __restrict__ ebuck, int nchunk, int E) {
  __shared__ int lcur[256];
  int t = threadIdx.x, chunk = blockIdx.x;
  int idx = t * nchunk + chunk;
  lcur[t] = partial[idx] + boffs[idx >> 8];
  __syncthreads();
  int base = chunk * 2048;
#pragma unroll
  for (int k = 0; k < 8; ++k) {
    int i = base + k * 256 + t;
    if (i < E) {
      int key = perm ? keys[perm[i]] : keys[i];
      int pos = atomicAdd(&lcur[key >> 8], 1);
      ebuck[pos] = (i << 8) | (key & 255);
    }
  }
}

__global__ __launch_bounds__(256) void k_final_row(
    const int* __restrict__ ebuck, const int* __restrict__ partial,
    const int* __restrict__ boffs, int* __restrict__ perm_r,
    int* __restrict__ offs_r, int nchunk, int N, int E) {
  __shared__ int lh[256], sm[256], lscan[256];
  int t = threadIdx.x, b = blockIdx.x;
  int i0 = b * nchunk;
  int start = partial[i0] + boffs[i0 >> 8];
  int i1 = i0 + nchunk;
  int end = (b < 255) ? partial[i1] + boffs[i1 >> 8] : E;
  lh[t] = 0;
  __syncthreads();
  for (int p = start + t; p < end; p += 256) atomicAdd(&lh[ebuck[p] & 255], 1);
  __syncthreads();
  int val = lh[t];
  sm[t] = val;
  __syncthreads();
  for (int off = 1; off < 256; off <<= 1) {
    int v = (t >= off) ? sm[t - off] : 0;
    __syncthreads();
    sm[t] += v;
    __syncthreads();
  }
  lscan[t] = sm[t] - val;
  int node = b * 256 + t;
  if (node < N) offs_r[node] = start + lscan[t];
  if (b == 0 && t == 0) offs_r[N] = E;
  lh[t] = 0;
  __syncthreads();
  for (int p = start + t; p < end; p += 256) {
    int v = ebuck[p];
    int low = v & 255;
    int rk = atomicAdd(&lh[low], 1);
    perm_r[start + lscan[low] + rk] = v >> 8;
  }
}

__global__ __launch_bounds__(256) void k_final_col(
    const int* __restrict__ ebuck, const int* __restrict__ perm_r,
    const int* __restrict__ row, const int* __restrict__ partial,
    const int* __restrict__ boffs, int2* __restrict__ pstat,
    int* __restrict__ offs_c, int nchunk, int N, int E) {
  __shared__ int lh[256], sm[256], lscan[256];
  int t = threadIdx.x, b = blockIdx.x;
  int i0 = b * nchunk;
  int start = partial[i0] + boffs[i0 >> 8];
  int i1 = i0 + nchunk;
  int end = (b < 255) ? partial[i1] + boffs[i1 >> 8] : E;
  lh[t] = 0;
  __syncthreads();
  for (int p = start + t; p < end; p += 256) atomicAdd(&lh[ebuck[p] & 255], 1);
  __syncthreads();
  int val = lh[t];
  sm[t] = val;
  __syncthreads();
  for (int off = 1; off < 256; off <<= 1) {
    int v = (t >= off) ? sm[t - off] : 0;
    __syncthreads();
    sm[t] += v;
    __syncthreads();
  }
  lscan[t] = sm[t] - val;
  int node = b * 256 + t;
  if (node < N) offs_c[node] = start + lscan[t];
  if (b == 0 && t == 0) offs_c[N] = E;
  lh[t] = 0;
  __syncthreads();
  for (int p = start + t; p < end; p += 256) {
    int v = ebuck[p];
    int low = v & 255;
    int rp = v >> 8;                      // rowCSR slot (~ascending -> L2 locality)
    int e = perm_r[rp];
    int rk = atomicAdd(&lh[low], 1);
    int2 rec; rec.x = row[e]; rec.y = rp;
    pstat[start + lscan[low] + rk] = rec;
  }
}

// ------- fused per-row sims + weights, MFMA edition. One wave per row. ------
// No global atomics: colw is computed afterwards by k_colw (segmented sum).
__global__ __launch_bounds__(256) void k_simw(
    const float* __restrict__ xn, const __hip_bfloat16* __restrict__ xnb,
    const int* __restrict__ colof_r, const int* __restrict__ offs_r,
    float* __restrict__ adjr, float* __restrict__ wgr,
    const float* __restrict__ gate, int layer, int N) {
  int w = threadIdx.x >> 6;   // wave 0..3, one row each
  int l = threadIdx.x & 63;
  int r = blockIdx.x * 4 + w;
  __shared__ float sims[4][320];
  __shared__ int scol[4][320];
  if (r >= N) return;
  int p0 = offs_r[r], p1 = offs_r[r + 1];
  int ne = p1 - p0;                     // ~17 (Poisson(16) + self loop), <320
  int quad = l >> 4;
  int m = l & 15;
  int qoff = quad * 8;
  const __hip_bfloat16* xr = xnb + (size_t)r * F;
  bf16x8 b0 = *(const bf16x8*)(xr + 0 * 32 + qoff);   // 16-lane broadcast loads
  bf16x8 b1 = *(const bf16x8*)(xr + 1 * 32 + qoff);
  bf16x8 b2 = *(const bf16x8*)(xr + 2 * 32 + qoff);
  bf16x8 b3 = *(const bf16x8*)(xr + 3 * 32 + qoff);
  for (int tb = 0; tb < ne; tb += 16) {
    int ii = tb + m; if (ii > ne - 1) ii = ne - 1;     // clamp (extra rows ignored)
    int cm = colof_r[p0 + ii];
    if (quad == 0 && tb + m < ne) scol[w][tb + m] = cm;
    const __hip_bfloat16* xc = xnb + (size_t)cm * F;
    bf16x8 a0 = *(const bf16x8*)(xc + 0 * 32 + qoff);  // 4 independent 16B gathers
    bf16x8 a1 = *(const bf16x8*)(xc + 1 * 32 + qoff);
    bf16x8 a2 = *(const bf16x8*)(xc + 2 * 32 + qoff);
    bf16x8 a3 = *(const bf16x8*)(xc + 3 * 32 + qoff);
    f32x4 acc = {0.f, 0.f, 0.f, 0.f};
    acc = __builtin_amdgcn_mfma_f32_16x16x32_bf16(a0, b0, acc, 0, 0, 0);
    acc = __builtin_amdgcn_mfma_f32_16x16x32_bf16(a1, b1, acc, 0, 0, 0);
    acc = __builtin_amdgcn_mfma_f32_16x16x32_bf16(a2, b2, acc, 0, 0, 0);
    acc = __builtin_amdgcn_mfma_f32_16x16x32_bf16(a3, b3, acc, 0, 0, 0);
    if (m == 0) {                       // lanes 0,16,32,48 hold rows quad*4+reg
#pragma unroll
      for (int reg = 0; reg < 4; ++reg) {
        int i = tb + quad * 4 + reg;
        if (i < ne) sims[w][i] = acc[reg];
      }
    }
  }
  // pass 2: guard-band fp32 recompute + threshold + rowsum/deg (one wave).
  // Band: bf16 rounding 2^-8/operand -> dot err <= 2^-7 = 0.0078 worst case
  // (Cauchy-Schwarz, unit vectors); +-0.01 covers it deterministically.
  float vsum = 0.f; int cn = 0;
  for (int base = 0; base < ne; base += 64) {
    int i = base + l;
    bool have = i < ne;
    float s = have ? sims[w][i] : 0.f;
    int c = have ? scol[w][i] : r;
    bool self = (c == r);
    bool flag = have && !self && fabsf(s - 0.1f) < 0.01f;
    unsigned long long mask = __ballot(flag);
    while (mask) {                      // ~0.8 flagged edge/row: wave-coop fp32 dot
      int src = __ffsll(mask) - 1;
      mask &= mask - 1;
      int cc = __shfl(c, src);
      float2 ar = ((const float2*)(xn + (size_t)r * F))[l];
      float2 bc = ((const float2*)(xn + (size_t)cc * F))[l];
      float d = ar.x * bc.x + ar.y * bc.y;
#pragma unroll
      for (int mm = 32; mm >= 1; mm >>= 1) d += __shfl_xor(d, mm);
      if (l == src) s = d;
    }
    if (self || s < 0.1f) s = 0.f;
    if (have) sims[w][i] = s;
    vsum += s;
    cn += (s > 0.f) ? 1 : 0;
  }
#pragma unroll
  for (int mm = 32; mm >= 1; mm >>= 1) {
    vsum += __shfl_xor(vsum, mm);
    cn += __shfl_xor(cn, mm);
  }
  float rs = vsum;
  float lam = 1.0f / (float)(cn + 1);
  float gg = (layer > 0) ? gate[layer - 1] : 0.f;
  for (int i = l; i < ne; i += 64) {
    int c = scol[w][i];
    float s = sims[w][i];
    float sn = (rs > 0.f) ? s / rs : 0.f;
    float wv = (c == r) ? lam : sn;
    wv = expf(wv);                      // thresholded edges get exp(0)=1
    float wc;
    if (layer == 0) { adjr[p0 + i] = wv; wc = wv; }
    else { wc = gg * adjr[p0 + i] + (1.f - gg) * wv; }
    wgr[p0 + i] = wc;                   // sequential write; NO atomics
  }
}

// ---- colw[c] = sum of wc over col-CSR segment (replaces scattered atomics) -
__global__ __launch_bounds__(256) void k_colw(
    const int2* __restrict__ pstat, const float* __restrict__ wgr,
    const int* __restrict__ offs_c, float* __restrict__ colw, int N) {
  int c = blockIdx.x * 256 + threadIdx.x;
  if (c >= N) return;
  int p0 = offs_c[c], p1 = offs_c[c + 1];
  float s = 0.f;
  int p = p0;
  for (; p + 4 <= p1; p += 4) {        // 4 random L2 reads in flight
    int2 a = pstat[p], b = pstat[p + 1], d = pstat[p + 2], e = pstat[p + 3];
    s += wgr[a.y] + wgr[b.y] + wgr[d.y] + wgr[e.y];
  }
  for (; p < p1; ++p) s += wgr[pstat[p].y];
  colw[c] = s;
}

// ------ GEMM: out_bf16[M,128] = A[M,128] @ W[128,128], register-tiled -------
__global__ __launch_bounds__(256) void k_gemm128(const float* __restrict__ A,
                                                 const float* __restrict__ W,
                                                 __hip_bfloat16* __restrict__ out, int M) {
  __shared__ float As[128][36];
  int t = threadIdx.x;
  int n0 = blockIdx.x * 32;
  for (int i = t; i < 32 * 128; i += 256) {
    int nn = i >> 7, kk = i & 127;
    int gn = n0 + nn;
    As[kk][nn] = (gn < M) ? A[(size_t)gn * 128 + kk] : 0.f;
  }
  __syncthreads();
  int nb = (t >> 6) * 8;
  int j2 = (t & 63) * 2;
  float acc[8][2] = {};
  for (int k = 0; k < 128; ++k) {
    float4 a01 = *(const float4*)&As[k][nb];
    float4 a23 = *(const float4*)&As[k][nb + 4];
    float2 wv = *(const float2*)&W[k * 128 + j2];
    acc[0][0] += a01.x * wv.x; acc[0][1] += a01.x * wv.y;
    acc[1][0] += a01.y * wv.x; acc[1][1] += a01.y * wv.y;
    acc[2][0] += a01.z * wv.x; acc[2][1] += a01.z * wv.y;
    acc[3][0] += a01.w * wv.x; acc[3][1] += a01.w * wv.y;
    acc[4][0] += a23.x * wv.x; acc[4][1] += a23.x * wv.y;
    acc[5][0] += a23.y * wv.x; acc[5][1] += a23.y * wv.y;
    acc[6][0] += a23.z * wv.x; acc[6][1] += a23.z * wv.y;
    acc[7][0] += a23.w * wv.x; acc[7][1] += a23.w * wv.y;
  }
  __hip_bfloat162* o2 = (__hip_bfloat162*)out;
#pragma unroll
  for (int i = 0; i < 8; ++i) {
    int gn = n0 + nb + i;
    if (gn < M) {
      __hip_bfloat162 o;
      o.x = __float2bfloat16(acc[i][0]); o.y = __float2bfloat16(acc[i][1]);
      o2[(size_t)gn * 64 + (j2 >> 1)] = o;
    }
  }
}

// ------ GEMM: out_bf16[M,40] = A[M,128] @ W[128,40], register-tiled ---------
__global__ __launch_bounds__(320) void k_gemm40(const float* __restrict__ A,
                                                const float* __restrict__ W,
                                                __hip_bfloat16* __restrict__ out,
                                                int M, int C) {
  __shared__ float As[128][68];
  int t = threadIdx.x;
  int n0 = blockIdx.x * 64;
  for (int i = t; i < 64 * 128; i += 320) {
    int nn = i >> 7, kk = i & 127;
    int gn = n0 + nn;
    As[kk][nn] = (gn < M) ? A[(size_t)gn * 128 + kk] : 0.f;
  }
  __syncthreads();
  int gq = t / 40;
  int jc = t - gq * 40;
  int nb = gq * 8;
  float acc[8] = {};
  for (int k = 0; k < 128; ++k) {
    float4 a01 = *(const float4*)&As[k][nb];
    float4 a23 = *(const float4*)&As[k][nb + 4];
    float wv = W[k * C + jc];
    acc[0] += a01.x * wv; acc[1] += a01.y * wv; acc[2] += a01.z * wv; acc[3] += a01.w * wv;
    acc[4] += a23.x * wv; acc[5] += a23.y * wv; acc[6] += a23.z * wv; acc[7] += a23.w * wv;
  }
#pragma unroll
  for (int i = 0; i < 8; ++i) {
    int gn = n0 + nb + i;
    if (gn < M) out[(size_t)gn * C + jc] = __float2bfloat16(acc[i]);
  }
}

// ---- fused: per-edge norm + aggregation + bias + relu + row-normalize ------
__global__ __launch_bounds__(256) void k_agg_norm(
    const __hip_bfloat162* __restrict__ hWb, const int2* __restrict__ pstat,
    const float* __restrict__ wgr, const float* __restrict__ colw,
    const int* __restrict__ offs_c, const float* __restrict__ bias,
    float* __restrict__ out, float* __restrict__ xn, __hip_bfloat16* __restrict__ xnb,
    int N) {
  int w = threadIdx.x >> 6;
  int t = threadIdx.x & 63;
  int c = blockIdx.x * 4 + w;
  if (c >= N) return;
  int p0 = offs_c[c], p1 = offs_c[c + 1];
  float dcv = colw[c];
  float dic = (dcv > 0.f) ? rsqrtf(dcv) : 0.f;
  float acc0 = bias[2 * t], acc1 = bias[2 * t + 1];
  int p = p0;
  for (; p + 8 <= p1; p += 8) {   // 8 row-gathers in flight
    int2 s[8];
    __hip_bfloat162 h[8];
    float wv[8], dv[8];
#pragma unroll
    for (int k = 0; k < 8; ++k) s[k] = pstat[p + k];
#pragma unroll
    for (int k = 0; k < 8; ++k) h[k] = hWb[(size_t)s[k].x * 64 + t];
#pragma unroll
    for (int k = 0; k < 8; ++k) { wv[k] = wgr[s[k].y]; dv[k] = colw[s[k].x]; }
#pragma unroll
    for (int k = 0; k < 8; ++k) {
      float n = ((dv[k] > 0.f) ? rsqrtf(dv[k]) : 0.f) * wv[k] * dic;
      acc0 += n * __bfloat162float(h[k].x);
      acc1 += n * __bfloat162float(h[k].y);
    }
  }
  for (; p + 4 <= p1; p += 4) {
    int2 s0 = pstat[p], s1 = pstat[p + 1], s2 = pstat[p + 2], s3 = pstat[p + 3];
    float w0 = wgr[s0.y], w1 = wgr[s1.y], w2 = wgr[s2.y], w3 = wgr[s3.y];
    float d0 = colw[s0.x], d1 = colw[s1.x], d2 = colw[s2.x], d3 = colw[s3.x];
    __hip_bfloat162 h0 = hWb[(size_t)s0.x * 64 + t];
    __hip_bfloat162 h1 = hWb[(size_t)s1.x * 64 + t];
    __hip_bfloat162 h2 = hWb[(size_t)s2.x * 64 + t];
    __hip_bfloat162 h3 = hWb[(size_t)s3.x * 64 + t];
    float n0 = ((d0 > 0.f) ? rsqrtf(d0) : 0.f) * w0 * dic;
    float n1 = ((d1 > 0.f) ? rsqrtf(d1) : 0.f) * w1 * dic;
    float n2 = ((d2 > 0.f) ? rsqrtf(d2) : 0.f) * w2 * dic;
    float n3 = ((d3 > 0.f) ? rsqrtf(d3) : 0.f) * w3 * dic;
    acc0 += n0 * __bfloat162float(h0.x) + n1 * __bfloat162float(h1.x)
          + n2 * __bfloat162float(h2.x) + n3 * __bfloat162float(h3.x);
    acc1 += n0 * __bfloat162float(h0.y) + n1 * __bfloat162float(h1.y)
          + n2 * __bfloat162float(h2.y) + n3 * __bfloat162float(h3.y);
  }
  for (; p < p1; ++p) {
    int2 s0 = pstat[p];
    float w0 = wgr[s0.y];
    float d0 = colw[s0.x];
    __hip_bfloat162 h0 = hWb[(size_t)s0.x * 64 + t];
    float n0 = ((d0 > 0.f) ? rsqrtf(d0) : 0.f) * w0 * dic;
    acc0 += n0 * __bfloat162float(h0.x);
    acc1 += n0 * __bfloat162float(h0.y);
  }
  acc0 = fmaxf(acc0, 0.f); acc1 = fmaxf(acc1, 0.f);
  float2 o; o.x = acc0; o.y = acc1;
  ((float2*)out)[(size_t)c * 64 + t] = o;
  float ss = acc0 * acc0 + acc1 * acc1;
#pragma unroll
  for (int m = 32; m >= 1; m >>= 1) ss += __shfl_xor(ss, m);
  float inv = 1.0f / fmaxf(sqrtf(ss), 1e-12f);
  float2 on; on.x = acc0 * inv; on.y = acc1 * inv;
  ((float2*)xn)[(size_t)c * 64 + t] = on;
  __hip_bfloat162 ob;
  ob.x = __float2bfloat16(on.x); ob.y = __float2bfloat16(on.y);
  ((__hip_bfloat162*)xnb)[(size_t)c * 64 + t] = ob;
}

// ------- fused final aggregation + bias + log_softmax; wave per node --------
__global__ __launch_bounds__(256) void k_agg40_lsm(
    const __hip_bfloat16* __restrict__ hW, const int2* __restrict__ pstat,
    const float* __restrict__ wgr, const float* __restrict__ colw,
    const int* __restrict__ offs_c, const float* __restrict__ bias,
    float* __restrict__ out, int C, int N) {
  int w = threadIdx.x >> 6;
  int j = threadIdx.x & 63;
  int c = blockIdx.x * 4 + w;
  if (c >= N) return;
  int p0 = offs_c[c], p1 = offs_c[c + 1];
  float dcv = colw[c];
  float dic = (dcv > 0.f) ? rsqrtf(dcv) : 0.f;
  bool act = j < C;
  int jj = act ? j : 0;
  float acc = act ? bias[jj] : 0.f;
  int p = p0;
  for (; p + 4 <= p1; p += 4) {
    int2 s0 = pstat[p], s1 = pstat[p + 1], s2 = pstat[p + 2], s3 = pstat[p + 3];
    float w0 = wgr[s0.y], w1 = wgr[s1.y], w2 = wgr[s2.y], w3 = wgr[s3.y];
    float d0 = colw[s0.x], d1 = colw[s1.x], d2 = colw[s2.x], d3 = colw[s3.x];
    float h0 = __bfloat162float(hW[(size_t)s0.x * C + jj]);
    float h1 = __bfloat162float(hW[(size_t)s1.x * C + jj]);
    float h2 = __bfloat162float(hW[(size_t)s2.x * C + jj]);
    float h3 = __bfloat162float(hW[(size_t)s3.x * C + jj]);
    acc += ((d0 > 0.f) ? rsqrtf(d0) : 0.f) * w0 * dic * h0
         + ((d1 > 0.f) ? rsqrtf(d1) : 0.f) * w1 * dic * h1
         + ((d2 > 0.f) ? rsqrtf(d2) : 0.f) * w2 * dic * h2
         + ((d3 > 0.f) ? rsqrtf(d3) : 0.f) * w3 * dic * h3;
  }
  for (; p < p1; ++p) {
    int2 s0 = pstat[p];
    float w0 = wgr[s0.y];
    float d0 = colw[s0.x];
    acc += ((d0 > 0.f) ? rsqrtf(d0) : 0.f) * w0 * dic
         * __bfloat162float(hW[(size_t)s0.x * C + jj]);
  }
  if (!act) acc = 0.f;
  float v = act ? acc : -3.0e38f;
#pragma unroll
  for (int m = 32; m >= 1; m >>= 1) v = fmaxf(v, __shfl_xor(v, m));
  float ex = act ? expf(acc - v) : 0.f;
#pragma unroll
  for (int m = 32; m >= 1; m >>= 1) ex += __shfl_xor(ex, m);
  if (act) out[(size_t)c * C + j] = acc - v - logf(ex);
}

extern "C" void kernel_launch(void* const* d_in, const int* in_sizes, int n_in,
                              void* d_out, int out_size, void* d_ws, size_t ws_size,
                              hipStream_t stream) {
  const float* x    = (const float*)d_in[0];
  const float* gate = (const float*)d_in[1];
  const float* W0   = (const float*)d_in[2];
  const float* b0   = (const float*)d_in[3];
  const float* W1   = (const float*)d_in[4];
  const float* b1   = (const float*)d_in[5];
  const float* W2   = (const float*)d_in[6];
  const float* b2   = (const float*)d_in[7];
  const int* eidx   = (const int*)d_in[8];
  int N = in_sizes[0] / 128;
  int E = in_sizes[8] / 2;
  int C = in_sizes[7];  // 40
  const int* row = eidx;
  const int* col = eidx + E;

  char* ws = (char*)d_ws;
  size_t off = 0;
  auto alloc = [&](size_t bytes) {
    char* p = ws + off;
    off += (bytes + 255) & ~(size_t)255;
    return p;
  };
  float* xn     = (float*)alloc((size_t)N * 128 * 4);
  __hip_bfloat16* xnb = (__hip_bfloat16*)alloc((size_t)N * 128 * 2);
  float* bufC   = (float*)alloc((size_t)N * 128 * 4);
  __hip_bfloat16* hWb = (__hip_bfloat16*)alloc((size_t)N * 128 * 2);
  float* adjr   = (float*)alloc((size_t)E * 4);    // layer-0 weights, row-CSR order
  float* wgr    = (float*)alloc((size_t)E * 4);    // gated weight, row-CSR order
  int*   perm_r = (int*)alloc((size_t)E * 4);
  int2*  pstat  = (int2*)alloc((size_t)E * 8);     // (row, rowCSR-slot) per col slot
  int*   colof_r= (int*)alloc((size_t)E * 4);
  int*   ebuck  = (int*)alloc((size_t)E * 4);      // bucket-partitioned packed ids
  int*   offs_c = (int*)alloc((size_t)(N + 1) * 4);
  int*   offs_r = (int*)alloc((size_t)(N + 1) * 4);
  float* colw   = (float*)alloc((size_t)N * 4);

  int NCHUNK = (E + 2047) / 2048;
  int M      = 256 * NCHUNK;
  int*   ghist  = (int*)alloc((size_t)M * 4);
  int*   partial= (int*)alloc((size_t)M * 4);
  int*   bsum   = (int*)alloc((size_t)NCHUNK * 4);
  int*   boffs  = (int*)alloc((size_t)NCHUNK * 4);

  int NBUK = (N + 255) / 256;
  int nb1  = (N + 255) / 256;
  int nw4  = (N + 3) / 4;

  // ---- CSR build: atomic-free two-level counting sort (row, then col) ----
  k_lhist<<<NCHUNK, 256, 0, stream>>>(row, nullptr, ghist, nullptr, NCHUNK, E);
  k_scan1<<<NCHUNK, 256, 0, stream>>>(ghist, partial, bsum, M);
  k_scan2<<<1, 256, 0, stream>>>(bsum, boffs, NCHUNK);
  k_bucketize<<<NCHUNK, 256, 0, stream>>>(row, nullptr, partial, boffs, ebuck, NCHUNK, E);
  k_final_row<<<NBUK, 256, 0, stream>>>(ebuck, partial, boffs, perm_r, offs_r,
                                        NCHUNK, N, E);
  k_lhist<<<NCHUNK, 256, 0, stream>>>(col, perm_r, ghist, colof_r, NCHUNK, E);
  k_scan1<<<NCHUNK, 256, 0, stream>>>(ghist, partial, bsum, M);
  k_scan2<<<1, 256, 0, stream>>>(bsum, boffs, NCHUNK);
  k_bucketize<<<NCHUNK, 256, 0, stream>>>(col, perm_r, partial, boffs, ebuck, NCHUNK, E);
  k_final_col<<<NBUK, 256, 0, stream>>>(ebuck, perm_r, row, partial, boffs, pstat,
                                        offs_c, NCHUNK, N, E);

  for (int layer = 0; layer < 3; ++layer) {
    if (layer == 0) k_normalize<<<(N + 3) / 4, 256, 0, stream>>>(x, xn, xnb, N);
    k_simw<<<nw4, 256, 0, stream>>>(xn, xnb, colof_r, offs_r, adjr, wgr,
                                    gate, layer, N);
    k_colw<<<nb1, 256, 0, stream>>>(pstat, wgr, offs_c, colw, N);
    const float* hin = (layer == 0) ? x : bufC;
    if (layer < 2) {
      const float* W = (layer == 0) ? W0 : W1;
      const float* b = (layer == 0) ? b0 : b1;
      k_gemm128<<<(N + 31) / 32, 256, 0, stream>>>(hin, W, hWb, N);
      k_agg_norm<<<nw4, 256, 0, stream>>>((const __hip_bfloat162*)hWb, pstat, wgr, colw,
                                          offs_c, b, bufC, xn, xnb, N);
    } else {
      k_gemm40<<<(N + 63) / 64, 320, 0, stream>>>(hin, W2, hWb, N, C);
      k_agg40_lsm<<<nw4, 256, 0, stream>>>(hWb, pstat, wgr, colw, offs_c, b2,
                                           (float*)d_out, C, N);
    }
  }
}